// Round 1
// baseline (579.825 us; speedup 1.0000x reference)
//
#include <hip/hip_runtime.h>
#include <math.h>

#define DI __device__ __forceinline__

constexpr int B_ = 16, CLS_ = 20, C_ = 512, H_ = 4, HD_ = 128, N_ = 1024, G_ = 80, G2_ = 160, K_ = 9;
constexpr float EPS_ = 1e-5f;
constexpr float BNS_ = 0.9999950000374997f;     // 1/sqrt(1+1e-5)
constexpr float SCALE_ = 0.08838834764831845f;  // 128^-0.5
constexpr float INVSQRT2_ = 0.7071067811865475f;

// ---- workspace layout (float offsets) ----
constexpr long OFF_PART  = 0;                       // 1024*2
constexpr long OFF_STATS = 2048;                    // 16*2
constexpr long OFF_XN    = 4096;                    // 16*512*1024  (reused later for attn-out)
constexpr long OFF_Q     = OFF_XN    + 8388608;     // 16*512*1024
constexpr long OFF_KV    = OFF_Q     + 8388608;     // 16*20*1024
constexpr long OFF_AMAPT = OFF_KV    + 327680;      // 16*1024*80
constexpr long OFF_XF    = OFF_AMAPT + 1310720;     // 16*1024*80
constexpr long OFF_XU    = OFF_XF    + 1310720;     // 16*1024*80
constexpr long OFF_SQ    = OFF_XU    + 1310720;     // 16*1024
constexpr long OFF_NEGD  = OFF_SQ    + 16384;       // 16*1024*1024
constexpr long OFF_IDX   = OFF_NEGD  + 16777216;    // 16*1024*9 (int)
constexpr long OFF_GOUTT = OFF_IDX   + 147456;      // 16*1024*80

DI float wsum(float v){
#pragma unroll
  for(int d=1; d<64; d<<=1) v += __shfl_xor(v, d);
  return v;
}
DI float wfmax(float v){
#pragma unroll
  for(int d=1; d<64; d<<=1) v = fmaxf(v, __shfl_xor(v, d));
  return v;
}

// K1a: per-segment partial sums of x_patch (for per-batch global LN)
__global__ __launch_bounds__(256) void k_stats_partial(const float* __restrict__ x, float* __restrict__ part){
  int blk = blockIdx.x;                 // b*64+seg
  const float4* xp = (const float4*)x;
  long base4 = (long)blk * 2048;
  int t = threadIdx.x;
  float s = 0.f, ss = 0.f;
#pragma unroll
  for(int j=0;j<8;++j){
    float4 v = xp[base4 + t + 256*j];
    s  += v.x + v.y + v.z + v.w;
    ss += v.x*v.x + v.y*v.y + v.z*v.z + v.w*v.w;
  }
  s = wsum(s); ss = wsum(ss);
  __shared__ float rs[4], rss[4];
  int wv = t >> 6;
  if((t & 63) == 0){ rs[wv] = s; rss[wv] = ss; }
  __syncthreads();
  if(t == 0){
    part[blk*2]   = rs[0]+rs[1]+rs[2]+rs[3];
    part[blk*2+1] = rss[0]+rss[1]+rss[2]+rss[3];
  }
}

// K1b: finalize mean / inv-std per batch
__global__ __launch_bounds__(64) void k_stats_final(const float* __restrict__ part, float* __restrict__ stats){
  int b = blockIdx.x, t = threadIdx.x;
  float s  = part[(b*64+t)*2];
  float ss = part[(b*64+t)*2+1];
  s = wsum(s); ss = wsum(ss);
  if(t == 0){
    const float cnt = (float)(C_ * N_);
    float m = s / cnt;
    float var = ss / cnt - m*m;
    stats[b*2]   = m;
    stats[b*2+1] = 1.0f / sqrtf(var + EPS_);
  }
}

// K2: xn = (x - m) * inv * nw[c] + nb[c]
__global__ __launch_bounds__(256) void k_xn(const float* __restrict__ x, const float* __restrict__ stats,
                                            const float* __restrict__ nw, const float* __restrict__ nb,
                                            float* __restrict__ xn){
  long i4 = (long)blockIdx.x * 256 + threadIdx.x;   // float4 index, 2097152 total
  int c = (int)((i4 >> 8) & 511);
  int b = (int)(i4 >> 17);
  float m = stats[b*2], inv = stats[b*2+1];
  float a = inv * nw[c];
  float bb = nb[c] - m * a;
  float4 v = ((const float4*)x)[i4];
  float4 o;
  o.x = v.x*a + bb; o.y = v.y*a + bb; o.z = v.z*a + bb; o.w = v.w*a + bb;
  ((float4*)xn)[i4] = o;
}

// K3/K13: Out[b][o][n] = sum_c W[o][c]*Bm[b][c][n] + bias[o] (+ Res)
template<bool RES>
__global__ __launch_bounds__(256) void k_gemm512(const float* __restrict__ W, const float* __restrict__ Bm,
                                                 const float* __restrict__ bias, const float* __restrict__ Res,
                                                 float* __restrict__ Out){
  __shared__ float As[16][64];
  __shared__ float Bs[16][64];
  int b  = blockIdx.z;
  int o0 = blockIdx.y * 64, n0 = blockIdx.x * 64;
  int t  = threadIdx.x;
  int tx = t & 15, ty = t >> 4;
  float acc[4][4] = {};
  const float* Bbase = Bm + (long)b * C_ * N_;
  for(int k0 = 0; k0 < C_; k0 += 16){
    {
      int r = t >> 2, kq = (t & 3) * 4;
      float4 a4 = *(const float4*)&W[(long)(o0 + r) * C_ + k0 + kq];
      As[kq][r] = a4.x; As[kq+1][r] = a4.y; As[kq+2][r] = a4.z; As[kq+3][r] = a4.w;
    }
    {
      int kk = t >> 4, c4 = (t & 15) * 4;
      float4 b4 = *(const float4*)&Bbase[(long)(k0 + kk) * N_ + n0 + c4];
      *(float4*)&Bs[kk][c4] = b4;
    }
    __syncthreads();
#pragma unroll
    for(int kk = 0; kk < 16; ++kk){
      float4 a  = *(const float4*)&As[kk][ty*4];
      float4 b4 = *(const float4*)&Bs[kk][tx*4];
      acc[0][0] += a.x*b4.x; acc[0][1] += a.x*b4.y; acc[0][2] += a.x*b4.z; acc[0][3] += a.x*b4.w;
      acc[1][0] += a.y*b4.x; acc[1][1] += a.y*b4.y; acc[1][2] += a.y*b4.z; acc[1][3] += a.y*b4.w;
      acc[2][0] += a.z*b4.x; acc[2][1] += a.z*b4.y; acc[2][2] += a.z*b4.z; acc[2][3] += a.z*b4.w;
      acc[3][0] += a.w*b4.x; acc[3][1] += a.w*b4.y; acc[3][2] += a.w*b4.z; acc[3][3] += a.w*b4.w;
    }
    __syncthreads();
  }
#pragma unroll
  for(int i = 0; i < 4; ++i){
    int o = o0 + ty*4 + i;
    long oidx = ((long)b * C_ + o) * N_ + n0 + tx*4;
    float bi = bias[o];
    float4 r;
    r.x = acc[i][0] + bi; r.y = acc[i][1] + bi; r.z = acc[i][2] + bi; r.w = acc[i][3] + bi;
    if(RES){
      float4 rv = *(const float4*)&Res[oidx];
      r.x += rv.x; r.y += rv.y; r.z += rv.z; r.w += rv.w;
    }
    *(float4*)&Out[oidx] = r;
  }
}

// K4: cls layernorm + kv projection. grid (B, 8) ; block handles 128 outputs x 20 cls
__global__ __launch_bounds__(256) void k_cls_kv(const float* __restrict__ xcls,
                                                const float* __restrict__ ncw, const float* __restrict__ ncb,
                                                const float* __restrict__ pkvw, const float* __restrict__ pkvb,
                                                float* __restrict__ kv){
  int b = blockIdx.x;
  int ochunk = blockIdx.y;
  __shared__ float xc[CLS_][C_];
  int t = threadIdx.x, wv = t >> 6, l = t & 63;
  for(int cls = wv; cls < CLS_; cls += 4){
    const float* xr = xcls + ((long)b*CLS_ + cls) * C_;
    float vals[8];
    float s = 0.f, ss = 0.f;
#pragma unroll
    for(int j=0;j<8;++j){ float v = xr[l + 64*j]; vals[j] = v; s += v; ss += v*v; }
    s = wsum(s); ss = wsum(ss);
    float m = s / (float)C_;
    float var = ss / (float)C_ - m*m;
    float inv = 1.0f / sqrtf(var + EPS_);
#pragma unroll
    for(int j=0;j<8;++j){
      int c = l + 64*j;
      xc[cls][c] = (vals[j]-m)*inv*ncw[c] + ncb[c];
    }
  }
  __syncthreads();
  int o = ochunk*128 + (t & 127);
  int cls0 = (t >> 7) * 10;
  float acc[10] = {};
  const float* wrow = pkvw + (long)o * C_;
  for(int k4 = 0; k4 < C_; k4 += 4){
    float4 w4 = *(const float4*)&wrow[k4];
#pragma unroll
    for(int i=0;i<10;++i){
      acc[i] += w4.x*xc[cls0+i][k4] + w4.y*xc[cls0+i][k4+1] + w4.z*xc[cls0+i][k4+2] + w4.w*xc[cls0+i][k4+3];
    }
  }
  float bo = pkvb[o];
#pragma unroll
  for(int i=0;i<10;++i) kv[((long)b*CLS_ + cls0+i)*1024 + o] = acc[i] + bo;
}

// K5: attn = q . key * scale -> amapT[b][n][h*20+cls]. grid (B*H, 16)
__global__ __launch_bounds__(256) void k_attn_amap(const float* __restrict__ q, const float* __restrict__ kv,
                                                   float* __restrict__ amapT){
  int bh = blockIdx.x; int b = bh >> 2, h = bh & 3;
  int n0 = blockIdx.y * 64;
  __shared__ float qs[HD_][65];
  __shared__ float ks[CLS_][HD_];
  int t = threadIdx.x, wv = t >> 6, l = t & 63;
  const float* qb = q + ((long)b*C_ + h*HD_) * N_ + n0;
#pragma unroll
  for(int j=0;j<8;++j){
    int idx = t + 256*j;            // 2048 float4
    int d = idx >> 4;
    int c4 = (idx & 15) * 4;
    float4 v = *(const float4*)&qb[(long)d * N_ + c4];
    qs[d][c4] = v.x; qs[d][c4+1] = v.y; qs[d][c4+2] = v.z; qs[d][c4+3] = v.w;
  }
  const float* kvb = kv + (long)b*CLS_*1024 + h*HD_;
  for(int idx = t; idx < CLS_*32; idx += 256){
    int cls = idx >> 5;
    int c4 = (idx & 31) * 4;
    float4 v = *(const float4*)&kvb[(long)cls*1024 + c4];
    ks[cls][c4] = v.x; ks[cls][c4+1] = v.y; ks[cls][c4+2] = v.z; ks[cls][c4+3] = v.w;
  }
  __syncthreads();
  // wave wv handles cls in [wv*5, wv*5+5), lane l handles n0+l
#pragma unroll
  for(int ci=0; ci<5; ++ci){
    int cls = wv*5 + ci;
    float acc = 0.f;
#pragma unroll 8
    for(int d=0; d<HD_; ++d) acc += qs[d][l] * ks[cls][d];
    amapT[((long)b*N_ + n0 + l)*G_ + h*CLS_ + cls] = acc * SCALE_;
  }
}

// K6: per-row fc1+bn1 -> xf row; fused row-normalization -> xu, sq. one wave per row
__global__ __launch_bounds__(256) void k_fc1(const float* __restrict__ amapT, const float* __restrict__ w,
                                             const float* __restrict__ bias, const float* __restrict__ g1,
                                             const float* __restrict__ b1,
                                             float* __restrict__ xf, float* __restrict__ xu, float* __restrict__ sq){
  int t = threadIdx.x, wv = t >> 6, l = t & 63;
  long r = (long)blockIdx.x*4 + wv;
  __shared__ float arow[4][G_];
  const float* ap = amapT + r*G_;
  arow[wv][l] = ap[l];
  if(l < 16) arow[wv][64+l] = ap[64+l];
  __syncthreads();
  int o2 = (l < 16) ? (64 + l) : 0;
  float acc0 = 0.f, acc1 = 0.f;
  const float* w0 = w + (long)l*G_;
  const float* w1 = w + (long)o2*G_;
#pragma unroll 8
  for(int g=0; g<G_; ++g){
    float a = arow[wv][g];
    acc0 += w0[g]*a;
    acc1 += w1[g]*a;
  }
  float v0 = (acc0 + bias[l])  * (g1[l]*BNS_)  + b1[l];
  float v1 = (acc1 + bias[o2]) * (g1[o2]*BNS_) + b1[o2];
  xf[r*G_ + l] = v0;
  if(l < 16) xf[r*G_ + 64 + l] = v1;
  float ssq = v0*v0 + ((l<16) ? v1*v1 : 0.f);
  ssq = wsum(ssq);
  float nrm = sqrtf(ssq);
  float invn = 1.0f / fmaxf(nrm, 1e-12f);
  float u0 = v0*invn, u1 = v1*invn;
  float s2 = u0*u0 + ((l<16) ? u1*u1 : 0.f);
  s2 = wsum(s2);
  xu[r*G_ + l] = u0;
  if(l < 16) xu[r*G_ + 64 + l] = u1;
  if(l == 0) sq[r] = s2;
}

// K8: neg_d = 2*xu.xu^T - sq_n - sq_m  (per batch 1024x1024, K=80)
__global__ __launch_bounds__(256) void k_negd(const float* __restrict__ xu, const float* __restrict__ sq,
                                              float* __restrict__ negd){
  int b = blockIdx.z;
  int n0 = blockIdx.y*64, m0 = blockIdx.x*64;
  __shared__ float As[16][64];
  __shared__ float Bs[16][64];
  const float* xb = xu + (long)b*N_*G_;
  int t = threadIdx.x, tx = t & 15, ty = t >> 4;
  float acc[4][4] = {};
  for(int k0=0; k0<G_; k0+=16){
    int rr = t >> 2, kq = (t & 3)*4;
    float4 a4 = *(const float4*)&xb[(long)(n0+rr)*G_ + k0 + kq];
    As[kq][rr] = a4.x; As[kq+1][rr] = a4.y; As[kq+2][rr] = a4.z; As[kq+3][rr] = a4.w;
    float4 b4 = *(const float4*)&xb[(long)(m0+rr)*G_ + k0 + kq];
    Bs[kq][rr] = b4.x; Bs[kq+1][rr] = b4.y; Bs[kq+2][rr] = b4.z; Bs[kq+3][rr] = b4.w;
    __syncthreads();
#pragma unroll
    for(int kk=0; kk<16; ++kk){
      float4 a  = *(const float4*)&As[kk][ty*4];
      float4 b4 = *(const float4*)&Bs[kk][tx*4];
      acc[0][0] += a.x*b4.x; acc[0][1] += a.x*b4.y; acc[0][2] += a.x*b4.z; acc[0][3] += a.x*b4.w;
      acc[1][0] += a.y*b4.x; acc[1][1] += a.y*b4.y; acc[1][2] += a.y*b4.z; acc[1][3] += a.y*b4.w;
      acc[2][0] += a.z*b4.x; acc[2][1] += a.z*b4.y; acc[2][2] += a.z*b4.z; acc[2][3] += a.z*b4.w;
      acc[3][0] += a.w*b4.x; acc[3][1] += a.w*b4.y; acc[3][2] += a.w*b4.z; acc[3][3] += a.w*b4.w;
    }
    __syncthreads();
  }
  float sn[4], sm[4];
#pragma unroll
  for(int i=0;i<4;++i) sn[i] = sq[(long)b*N_ + n0 + ty*4 + i];
#pragma unroll
  for(int j=0;j<4;++j) sm[j] = sq[(long)b*N_ + m0 + tx*4 + j];
#pragma unroll
  for(int i=0;i<4;++i){
    long row = (long)b*N_ + n0 + ty*4 + i;
    float4 r;
    r.x = 2.f*acc[i][0] - sn[i] - sm[0];
    r.y = 2.f*acc[i][1] - sn[i] - sm[1];
    r.z = 2.f*acc[i][2] - sn[i] - sm[2];
    r.w = 2.f*acc[i][3] - sn[i] - sm[3];
    *(float4*)&negd[row*N_ + m0 + tx*4] = r;
  }
}

// K9: top-9 indices per row (descending, ties -> lower index). one wave per row
__global__ __launch_bounds__(256) void k_topk(const float* __restrict__ negd, int* __restrict__ idx){
  int t = threadIdx.x, wv = t >> 6, l = t & 63;
  long r = (long)blockIdx.x*4 + wv;
  const float* row = negd + r*N_;
  float vals[16];
#pragma unroll
  for(int j=0;j<16;++j) vals[j] = row[l + 64*j];
#pragma unroll
  for(int p=0; p<K_; ++p){
    float bv = vals[0]; int bj = 0;
#pragma unroll
    for(int j=1;j<16;++j) if(vals[j] > bv){ bv = vals[j]; bj = j; }
    int bm = l + 64*bj;
#pragma unroll
    for(int d=1; d<64; d<<=1){
      float ov = __shfl_xor(bv, d);
      int   om = __shfl_xor(bm, d);
      if(ov > bv || (ov == bv && om < bm)){ bv = ov; bm = om; }
    }
#pragma unroll
    for(int j=0;j<16;++j) if(bm == l + 64*j) vals[j] = -INFINITY;
    if(l == 0) idx[r*K_ + p] = bm;
  }
}

// K10: xj (neighbor max) -> y -> per-head 40x40 mixer -> bn2 -> gelu -> fc2 -> bn3 -> +sc -> goutT
__global__ __launch_bounds__(256) void k_graph_mlp(const float* __restrict__ xf, const int* __restrict__ idx,
                                                   const float* __restrict__ mrw, const float* __restrict__ mrb,
                                                   const float* __restrict__ g2, const float* __restrict__ b2,
                                                   const float* __restrict__ fc2w, const float* __restrict__ fc2b,
                                                   const float* __restrict__ g3, const float* __restrict__ b3,
                                                   const float* __restrict__ amapT, float* __restrict__ goutT){
  int t = threadIdx.x, wv = t >> 6, l = t & 63;
  long r = (long)blockIdx.x*4 + wv;
  long b = r >> 10;
  const float* frow = xf + r*G_;
  int o2s = (l < 16) ? (64 + l) : 0;
  float f0 = frow[l];
  float f1 = frow[o2s];
  float m0 = -INFINITY, m1 = -INFINITY;
  const int* ix = idx + r*K_;
#pragma unroll
  for(int k=0;k<K_;++k){
    int nb = ix[k];
    const float* nr = xf + ((long)b*N_ + nb)*G_;
    m0 = fmaxf(m0, nr[l]);
    m1 = fmaxf(m1, nr[o2s]);
  }
  float xj0 = m0 - f0, xj1 = m1 - f1;
  __shared__ float y[4][G2_];
  __shared__ float z[4][G2_];
  y[wv][2*l]   = f0;
  y[wv][2*l+1] = xj0;
  if(l < 16){ y[wv][128+2*l] = f1; y[wv][128+2*l+1] = xj1; }
  __syncthreads();
  auto zcalc = [&](int o)->float{
    int h = o / 40;
    const float* yy = &y[wv][h*40];
    const float* wr = mrw + (long)o*40;
    float a = mrb[o];
#pragma unroll 8
    for(int i=0;i<40;++i) a += yy[i]*wr[i];
    float v = a*(g2[o]*BNS_) + b2[o];
    return v * 0.5f * (1.0f + erff(v * INVSQRT2_));
  };
  float z1v = zcalc(l);
  float z2v = zcalc(64 + l);
  float z3v = (l < 32) ? zcalc(128 + l) : 0.f;
  z[wv][l] = z1v;
  z[wv][64+l] = z2v;
  if(l < 32) z[wv][128+l] = z3v;
  __syncthreads();
  auto z2calc = [&](int o)->float{
    const float* wr = fc2w + (long)o*G2_;
    float a = fc2b[o];
#pragma unroll 8
    for(int j=0;j<G2_;++j) a += z[wv][j]*wr[j];
    return a*(g3[o]*BNS_) + b3[o];
  };
  float r0 = z2calc(l) + amapT[r*G_ + l];
  goutT[r*G_ + l] = r0;
  if(l < 16){
    float r1 = z2calc(64+l) + amapT[r*G_ + 64 + l];
    goutT[r*G_ + 64 + l] = r1;
  }
}

// K12: softmax over cls + PV -> outp[b][h*128+d][n] (LDS transposed write). grid (B*H, 16)
__global__ __launch_bounds__(256) void k_softmax_pv(const float* __restrict__ goutT, const float* __restrict__ kv,
                                                    float* __restrict__ outp){
  int bh = blockIdx.x; int b = bh >> 2, h = bh & 3;
  int n0 = blockIdx.y * 64;
  __shared__ float vs[CLS_][HD_];
  __shared__ float os[HD_][65];
  int t = threadIdx.x, wv = t >> 6, l = t & 63;
  const float* vb = kv + (long)b*CLS_*1024 + C_ + h*HD_;
  for(int i = t; i < CLS_*32; i += 256){
    int cls = i >> 5;
    int c4 = (i & 31)*4;
    float4 v = *(const float4*)&vb[(long)cls*1024 + c4];
    vs[cls][c4] = v.x; vs[cls][c4+1] = v.y; vs[cls][c4+2] = v.z; vs[cls][c4+3] = v.w;
  }
  __syncthreads();
  for(int ni=0; ni<16; ++ni){
    int n = n0 + wv*16 + ni;
    const float* gr = goutT + ((long)b*N_ + n)*G_ + h*CLS_;
    float x = (l < CLS_) ? gr[l] : -INFINITY;
    float mx = wfmax(x);
    float p = (l < CLS_) ? expf(x - mx) : 0.f;
    float s = wsum(p);
    float pn = p / s;
    float a0 = 0.f, a1 = 0.f;
#pragma unroll
    for(int cls=0; cls<CLS_; ++cls){
      float pv = __shfl(pn, cls);
      a0 += pv * vs[cls][l];
      a1 += pv * vs[cls][64+l];
    }
    os[l][wv*16+ni] = a0;
    os[64+l][wv*16+ni] = a1;
  }
  __syncthreads();
  float* ob = outp + ((long)b*C_ + h*HD_)*N_ + n0;
#pragma unroll
  for(int j=0;j<8;++j){
    int i = t + 256*j;              // 2048 float4
    int d = i >> 4;
    int c4 = (i & 15)*4;
    float4 v;
    v.x = os[d][c4]; v.y = os[d][c4+1]; v.z = os[d][c4+2]; v.w = os[d][c4+3];
    *(float4*)&ob[(long)d*N_ + c4] = v;
  }
}

extern "C" void kernel_launch(void* const* d_in, const int* in_sizes, int n_in,
                              void* d_out, int out_size, void* d_ws, size_t ws_size,
                              hipStream_t stream){
  const float* x_cls   = (const float*)d_in[0];
  const float* x_patch = (const float*)d_in[1];
  const float* norm_x_w = (const float*)d_in[2];
  const float* norm_x_b = (const float*)d_in[3];
  const float* pq_w  = (const float*)d_in[4];
  const float* pq_b  = (const float*)d_in[5];
  const float* ncls_w = (const float*)d_in[6];
  const float* ncls_b = (const float*)d_in[7];
  const float* pkv_w = (const float*)d_in[8];
  const float* pkv_b = (const float*)d_in[9];
  const float* fc1_w = (const float*)d_in[10];
  const float* fc1_b = (const float*)d_in[11];
  const float* bn1_g = (const float*)d_in[12];
  const float* bn1_b = (const float*)d_in[13];
  const float* mr_w  = (const float*)d_in[14];
  const float* mr_b  = (const float*)d_in[15];
  const float* bn2_g = (const float*)d_in[16];
  const float* bn2_b = (const float*)d_in[17];
  const float* fc2_w = (const float*)d_in[18];
  const float* fc2_b = (const float*)d_in[19];
  const float* bn3_g = (const float*)d_in[20];
  const float* bn3_b = (const float*)d_in[21];
  const float* proj_w = (const float*)d_in[22];
  const float* proj_b = (const float*)d_in[23];

  float* ws = (float*)d_ws;
  float* part   = ws + OFF_PART;
  float* stats  = ws + OFF_STATS;
  float* xn     = ws + OFF_XN;      // later reused as attn-out (B,C,N)
  float* qbuf   = ws + OFF_Q;
  float* kvbuf  = ws + OFF_KV;
  float* amapT  = ws + OFF_AMAPT;
  float* xf     = ws + OFF_XF;
  float* xubuf  = ws + OFF_XU;
  float* sqbuf  = ws + OFF_SQ;
  float* negd   = ws + OFF_NEGD;
  int*   idxbuf = (int*)(ws + OFF_IDX);
  float* goutT  = ws + OFF_GOUTT;
  float* attn_out = xn;             // xn is dead after the q GEMM
  float* out = (float*)d_out;

  k_stats_partial<<<1024, 256, 0, stream>>>(x_patch, part);
  k_stats_final<<<16, 64, 0, stream>>>(part, stats);
  k_xn<<<8192, 256, 0, stream>>>(x_patch, stats, norm_x_w, norm_x_b, xn);
  k_gemm512<false><<<dim3(16,8,16), 256, 0, stream>>>(pq_w, xn, pq_b, nullptr, qbuf);
  k_cls_kv<<<dim3(16,8), 256, 0, stream>>>(x_cls, ncls_w, ncls_b, pkv_w, pkv_b, kvbuf);
  k_attn_amap<<<dim3(64,16), 256, 0, stream>>>(qbuf, kvbuf, amapT);
  k_fc1<<<4096, 256, 0, stream>>>(amapT, fc1_w, fc1_b, bn1_g, bn1_b, xf, xubuf, sqbuf);
  k_negd<<<dim3(16,16,16), 256, 0, stream>>>(xubuf, sqbuf, negd);
  k_topk<<<4096, 256, 0, stream>>>(negd, idxbuf);
  k_graph_mlp<<<4096, 256, 0, stream>>>(xf, idxbuf, mr_w, mr_b, bn2_g, bn2_b,
                                        fc2_w, fc2_b, bn3_g, bn3_b, amapT, goutT);
  k_softmax_pv<<<dim3(64,16), 256, 0, stream>>>(goutT, kvbuf, attn_out);
  k_gemm512<true><<<dim3(16,8,16), 256, 0, stream>>>(proj_w, attn_out, proj_b, x_patch, out);
}

// Round 2
// 389.146 us; speedup vs baseline: 1.4900x; 1.4900x over previous
//
#include <hip/hip_runtime.h>
#include <math.h>

#define DI __device__ __forceinline__

constexpr int B_ = 16, CLS_ = 20, C_ = 512, H_ = 4, HD_ = 128, N_ = 1024, G_ = 80, G2_ = 160, K_ = 9;
constexpr float EPS_ = 1e-5f;
constexpr float BNS_ = 0.9999950000374997f;     // 1/sqrt(1+1e-5)
constexpr float SCALE_ = 0.08838834764831845f;  // 128^-0.5
constexpr float INVSQRT2_ = 0.7071067811865475f;

typedef __attribute__((ext_vector_type(8))) short bf16x8;
typedef __attribute__((ext_vector_type(4))) float f32x4;

// ---- workspace layout (float slots) ----
constexpr long OFF_PART  = 0;                    // 2048
constexpr long OFF_STATS = 2048;                 // 32
constexpr long OFF_Q     = 4096;                 // 16*512*1024 fp32
constexpr long OFF_KV    = OFF_Q     + 8388608;  // 16*20*1024
constexpr long OFF_AMAPT = OFF_KV    + 327680;   // 16*1024*80
constexpr long OFF_XF    = OFF_AMAPT + 1310720;
constexpr long OFF_XU    = OFF_XF    + 1310720;
constexpr long OFF_SQ    = OFF_XU    + 1310720;  // 16*1024
constexpr long OFF_NEGD  = OFF_SQ    + 16384;    // 16*1024*1024 fp32; ALSO overlays xn_bf16 (early) and attnout_bf16 (late)
constexpr long OFF_IDX   = OFF_NEGD  + 16777216; // 16*1024*9 int
constexpr long OFF_GOUTT = OFF_IDX   + 147456;   // 16*1024*80
constexpr long OFF_WQB   = OFF_GOUTT + 1310720;  // 512*512 bf16 = 131072 float slots
constexpr long OFF_WPB   = OFF_WQB   + 131072;

DI float wsum(float v){
#pragma unroll
  for(int d=1; d<64; d<<=1) v += __shfl_xor(v, d);
  return v;
}
DI float wfmax(float v){
#pragma unroll
  for(int d=1; d<64; d<<=1) v = fmaxf(v, __shfl_xor(v, d));
  return v;
}
DI unsigned short f2b(float f){
  unsigned u = __float_as_uint(f);
  unsigned r = (u + 0x7FFFu + ((u >> 16) & 1u)) >> 16;
  return (unsigned short)r;
}

#define GLOAD16(g, s) __builtin_amdgcn_global_load_lds((const __attribute__((address_space(1))) void*)(g), \
                        (__attribute__((address_space(3))) void*)(s), 16, 0, 0)

// K1a: per-segment partial sums of x_patch
__global__ __launch_bounds__(256) void k_stats_partial(const float* __restrict__ x, float* __restrict__ part){
  int blk = blockIdx.x;                 // b*64+seg
  const float4* xp = (const float4*)x;
  long base4 = (long)blk * 2048;
  int t = threadIdx.x;
  float s = 0.f, ss = 0.f;
#pragma unroll
  for(int j=0;j<8;++j){
    float4 v = xp[base4 + t + 256*j];
    s  += v.x + v.y + v.z + v.w;
    ss += v.x*v.x + v.y*v.y + v.z*v.z + v.w*v.w;
  }
  s = wsum(s); ss = wsum(ss);
  __shared__ float rs[4], rss[4];
  int wv = t >> 6;
  if((t & 63) == 0){ rs[wv] = s; rss[wv] = ss; }
  __syncthreads();
  if(t == 0){
    part[blk*2]   = rs[0]+rs[1]+rs[2]+rs[3];
    part[blk*2+1] = rss[0]+rss[1]+rss[2]+rss[3];
  }
}

__global__ __launch_bounds__(64) void k_stats_final(const float* __restrict__ part, float* __restrict__ stats){
  int b = blockIdx.x, t = threadIdx.x;
  float s  = part[(b*64+t)*2];
  float ss = part[(b*64+t)*2+1];
  s = wsum(s); ss = wsum(ss);
  if(t == 0){
    const float cnt = (float)(C_ * N_);
    float m = s / cnt;
    float var = ss / cnt - m*m;
    stats[b*2]   = m;
    stats[b*2+1] = 1.0f / sqrtf(var + EPS_);
  }
}

// K2: norm + transpose + bf16: xnb[b][n][c] = bf16( (x[b][c][n]-m)*inv*nw[c]+nb[c] )
__global__ __launch_bounds__(256) void k_xn_t(const float* __restrict__ x, const float* __restrict__ stats,
                                              const float* __restrict__ nw, const float* __restrict__ nb,
                                              unsigned short* __restrict__ xnb){
  __shared__ float tile[64][65];
  int b = blockIdx.z, c0 = blockIdx.y*64, n0 = blockIdx.x*64;
  float m = stats[b*2], inv = stats[b*2+1];
  int t = threadIdx.x;
  const float* xb = x + ((long)b*C_ + c0)*N_ + n0;
#pragma unroll
  for(int j=0;j<4;++j){
    int idx = t + 256*j;
    int r = idx >> 4, c4 = (idx & 15)*4;
    float a = inv * nw[c0+r];
    float bb = nb[c0+r] - m*a;
    float4 v = *(const float4*)&xb[(long)r*N_ + c4];
    tile[r][c4]   = v.x*a + bb;
    tile[r][c4+1] = v.y*a + bb;
    tile[r][c4+2] = v.z*a + bb;
    tile[r][c4+3] = v.w*a + bb;
  }
  __syncthreads();
  unsigned short* ob = xnb + ((long)b*N_ + n0)*C_ + c0;
#pragma unroll
  for(int j=0;j<8;++j){
    int idx = t + 256*j;
    int n = idx >> 5, cc = (idx & 31)*2;
    ushort2 u;
    u.x = f2b(tile[cc][n]);
    u.y = f2b(tile[cc+1][n]);
    *(ushort2*)&ob[(long)n*C_ + cc] = u;
  }
}

// weight fp32 -> bf16 (both 512x512 matrices)
__global__ __launch_bounds__(256) void k_wconv(const float* __restrict__ a, const float* __restrict__ b,
                                               unsigned short* __restrict__ oa, unsigned short* __restrict__ ob){
  long i = (long)blockIdx.x*256 + threadIdx.x;   // float4 idx, 65536 per matrix
  const float4* src = (const float4*)(blockIdx.y == 0 ? a : b);
  unsigned short* dst = blockIdx.y == 0 ? oa : ob;
  float4 v = src[i];
  uint2 o;
  o.x = (unsigned)f2b(v.x) | ((unsigned)f2b(v.y) << 16);
  o.y = (unsigned)f2b(v.z) | ((unsigned)f2b(v.w) << 16);
  ((uint2*)dst)[i] = o;
}

// MFMA GEMM: Out[b][o][n] = sum_c Wb[o][c]*Xb[b][n][c] + bias[o] (+Res)
// A = Wb (M=512 x K=512 bf16 row-major), B = Xb (per batch, N=1024 x K=512 bf16 n-major)
template<bool RES>
__global__ __launch_bounds__(256) void k_gemm_mfma(const unsigned short* __restrict__ Wb,
                                                   const unsigned short* __restrict__ Xb,
                                                   const float* __restrict__ bias,
                                                   const float* __restrict__ Res,
                                                   float* __restrict__ Out){
  __shared__ unsigned short Al[4096];   // [128 rows(o)][32 k]
  __shared__ unsigned short Bl[4096];   // [128 rows(n)][32 k]
  int b = blockIdx.z;
  int o0 = blockIdx.y*128, n0 = blockIdx.x*128;
  int t = threadIdx.x, w = t >> 6, l = t & 63;
  int wr = w >> 1, wc = w & 1;
  f32x4 acc[4][4] = {};
  const unsigned short* Wt = Wb + (long)(o0 + w*16 + (l>>2))*512 + (l&3)*8;
  const unsigned short* Xt = Xb + ((long)b*N_ + n0 + w*16 + (l>>2))*512 + (l&3)*8;
  int ra = wr*64 + (l & 15);
  int rb = wc*64 + (l & 15);
  int kq = (l >> 4) * 8;
  for(int k0 = 0; k0 < 512; k0 += 32){
    if(k0) __syncthreads();
    GLOAD16(Wt + k0,            &Al[w*512]);
    GLOAD16(Wt + 64*512 + k0,   &Al[2048 + w*512]);
    GLOAD16(Xt + k0,            &Bl[w*512]);
    GLOAD16(Xt + 64*512 + k0,   &Bl[2048 + w*512]);
    __syncthreads();
    bf16x8 af[4], bfr[4];
#pragma unroll
    for(int i=0;i<4;++i){
      af[i]  = *(const bf16x8*)&Al[(ra + i*16)*32 + kq];
      bfr[i] = *(const bf16x8*)&Bl[(rb + i*16)*32 + kq];
    }
#pragma unroll
    for(int mi=0; mi<4; ++mi)
#pragma unroll
      for(int ni=0; ni<4; ++ni)
        acc[mi][ni] = __builtin_amdgcn_mfma_f32_16x16x32_bf16(af[mi], bfr[ni], acc[mi][ni], 0, 0, 0);
  }
  long obase = ((long)b*C_ + o0 + wr*64)*N_ + n0 + wc*64 + (l & 15);
  int r0 = (l >> 4) * 4;
#pragma unroll
  for(int mi=0; mi<4; ++mi){
#pragma unroll
    for(int r=0; r<4; ++r){
      int row = mi*16 + r0 + r;
      float bi = bias[o0 + wr*64 + row];
#pragma unroll
      for(int ni=0; ni<4; ++ni){
        long oi = obase + (long)row*N_ + ni*16;
        float v = acc[mi][ni][r] + bi;
        if(RES) v += Res[oi];
        Out[oi] = v;
      }
    }
  }
}

// K4: cls layernorm + kv projection
__global__ __launch_bounds__(256) void k_cls_kv(const float* __restrict__ xcls,
                                                const float* __restrict__ ncw, const float* __restrict__ ncb,
                                                const float* __restrict__ pkvw, const float* __restrict__ pkvb,
                                                float* __restrict__ kv){
  int b = blockIdx.x;
  int ochunk = blockIdx.y;
  __shared__ float xc[CLS_][C_];
  int t = threadIdx.x, wv = t >> 6, l = t & 63;
  for(int cls = wv; cls < CLS_; cls += 4){
    const float* xr = xcls + ((long)b*CLS_ + cls) * C_;
    float vals[8];
    float s = 0.f, ss = 0.f;
#pragma unroll
    for(int j=0;j<8;++j){ float v = xr[l + 64*j]; vals[j] = v; s += v; ss += v*v; }
    s = wsum(s); ss = wsum(ss);
    float m = s / (float)C_;
    float var = ss / (float)C_ - m*m;
    float inv = 1.0f / sqrtf(var + EPS_);
#pragma unroll
    for(int j=0;j<8;++j){
      int c = l + 64*j;
      xc[cls][c] = (vals[j]-m)*inv*ncw[c] + ncb[c];
    }
  }
  __syncthreads();
  int o = ochunk*128 + (t & 127);
  int cls0 = (t >> 7) * 10;
  float acc[10] = {};
  const float* wrow = pkvw + (long)o * C_;
  for(int k4 = 0; k4 < C_; k4 += 4){
    float4 w4 = *(const float4*)&wrow[k4];
#pragma unroll
    for(int i=0;i<10;++i){
      acc[i] += w4.x*xc[cls0+i][k4] + w4.y*xc[cls0+i][k4+1] + w4.z*xc[cls0+i][k4+2] + w4.w*xc[cls0+i][k4+3];
    }
  }
  float bo = pkvb[o];
#pragma unroll
  for(int i=0;i<10;++i) kv[((long)b*CLS_ + cls0+i)*1024 + o] = acc[i] + bo;
}

// K5: attn logits -> amapT[b][n][h*20+cls]
__global__ __launch_bounds__(256) void k_attn_amap(const float* __restrict__ q, const float* __restrict__ kv,
                                                   float* __restrict__ amapT){
  int bh = blockIdx.x; int b = bh >> 2, h = bh & 3;
  int n0 = blockIdx.y * 64;
  __shared__ float qs[HD_][65];
  __shared__ float ks[CLS_][HD_];
  int t = threadIdx.x, wv = t >> 6, l = t & 63;
  const float* qb = q + ((long)b*C_ + h*HD_) * N_ + n0;
#pragma unroll
  for(int j=0;j<8;++j){
    int idx = t + 256*j;
    int d = idx >> 4;
    int c4 = (idx & 15) * 4;
    float4 v = *(const float4*)&qb[(long)d * N_ + c4];
    qs[d][c4] = v.x; qs[d][c4+1] = v.y; qs[d][c4+2] = v.z; qs[d][c4+3] = v.w;
  }
  const float* kvb = kv + (long)b*CLS_*1024 + h*HD_;
  for(int idx = t; idx < CLS_*32; idx += 256){
    int cls = idx >> 5;
    int c4 = (idx & 31) * 4;
    float4 v = *(const float4*)&kvb[(long)cls*1024 + c4];
    ks[cls][c4] = v.x; ks[cls][c4+1] = v.y; ks[cls][c4+2] = v.z; ks[cls][c4+3] = v.w;
  }
  __syncthreads();
#pragma unroll
  for(int ci=0; ci<5; ++ci){
    int cls = wv*5 + ci;
    float a0=0.f, a1=0.f, a2=0.f, a3=0.f;
#pragma unroll 8
    for(int d=0; d<HD_; d+=4){
      float4 k4 = *(const float4*)&ks[cls][d];
      a0 += qs[d][l]  *k4.x;
      a1 += qs[d+1][l]*k4.y;
      a2 += qs[d+2][l]*k4.z;
      a3 += qs[d+3][l]*k4.w;
    }
    amapT[((long)b*N_ + n0 + l)*G_ + h*CLS_ + cls] = ((a0+a1)+(a2+a3)) * SCALE_;
  }
}

// K6: fc1+bn1 -> xf ; normalize -> xu, sq. one wave per row
__global__ __launch_bounds__(256) void k_fc1(const float* __restrict__ amapT, const float* __restrict__ w,
                                             const float* __restrict__ bias, const float* __restrict__ g1,
                                             const float* __restrict__ b1,
                                             float* __restrict__ xf, float* __restrict__ xu, float* __restrict__ sq){
  int t = threadIdx.x, wv = t >> 6, l = t & 63;
  long r = (long)blockIdx.x*4 + wv;
  __shared__ float arow[4][G_];
  const float* ap = amapT + r*G_;
  arow[wv][l] = ap[l];
  if(l < 16) arow[wv][64+l] = ap[64+l];
  __syncthreads();
  int o2 = (l < 16) ? (64 + l) : 0;
  const float4* w0 = (const float4*)(w + (long)l*G_);
  const float4* w1 = (const float4*)(w + (long)o2*G_);
  const float4* ar = (const float4*)&arow[wv][0];
  float4 A0 = {0,0,0,0}, A1 = {0,0,0,0};
#pragma unroll
  for(int g=0; g<20; ++g){
    float4 av = ar[g];
    float4 u0 = w0[g], u1 = w1[g];
    A0.x += u0.x*av.x; A0.y += u0.y*av.y; A0.z += u0.z*av.z; A0.w += u0.w*av.w;
    A1.x += u1.x*av.x; A1.y += u1.y*av.y; A1.z += u1.z*av.z; A1.w += u1.w*av.w;
  }
  float acc0 = (A0.x+A0.y)+(A0.z+A0.w);
  float acc1 = (A1.x+A1.y)+(A1.z+A1.w);
  float v0 = (acc0 + bias[l])  * (g1[l]*BNS_)  + b1[l];
  float v1 = (acc1 + bias[o2]) * (g1[o2]*BNS_) + b1[o2];
  xf[r*G_ + l] = v0;
  if(l < 16) xf[r*G_ + 64 + l] = v1;
  float ssq = v0*v0 + ((l<16) ? v1*v1 : 0.f);
  ssq = wsum(ssq);
  float nrm = sqrtf(ssq);
  float invn = 1.0f / fmaxf(nrm, 1e-12f);
  float u0 = v0*invn, u1 = v1*invn;
  float s2 = u0*u0 + ((l<16) ? u1*u1 : 0.f);
  s2 = wsum(s2);
  xu[r*G_ + l] = u0;
  if(l < 16) xu[r*G_ + 64 + l] = u1;
  if(l == 0) sq[r] = s2;
}

// K8: neg_d
__global__ __launch_bounds__(256) void k_negd(const float* __restrict__ xu, const float* __restrict__ sq,
                                              float* __restrict__ negd){
  int b = blockIdx.z;
  int n0 = blockIdx.y*64, m0 = blockIdx.x*64;
  __shared__ float As[16][64];
  __shared__ float Bs[16][64];
  const float* xb = xu + (long)b*N_*G_;
  int t = threadIdx.x, tx = t & 15, ty = t >> 4;
  float acc[4][4] = {};
  for(int k0=0; k0<G_; k0+=16){
    int rr = t >> 2, kq = (t & 3)*4;
    float4 a4 = *(const float4*)&xb[(long)(n0+rr)*G_ + k0 + kq];
    As[kq][rr] = a4.x; As[kq+1][rr] = a4.y; As[kq+2][rr] = a4.z; As[kq+3][rr] = a4.w;
    float4 b4 = *(const float4*)&xb[(long)(m0+rr)*G_ + k0 + kq];
    Bs[kq][rr] = b4.x; Bs[kq+1][rr] = b4.y; Bs[kq+2][rr] = b4.z; Bs[kq+3][rr] = b4.w;
    __syncthreads();
#pragma unroll
    for(int kk=0; kk<16; ++kk){
      float4 a  = *(const float4*)&As[kk][ty*4];
      float4 b4 = *(const float4*)&Bs[kk][tx*4];
      acc[0][0] += a.x*b4.x; acc[0][1] += a.x*b4.y; acc[0][2] += a.x*b4.z; acc[0][3] += a.x*b4.w;
      acc[1][0] += a.y*b4.x; acc[1][1] += a.y*b4.y; acc[1][2] += a.y*b4.z; acc[1][3] += a.y*b4.w;
      acc[2][0] += a.z*b4.x; acc[2][1] += a.z*b4.y; acc[2][2] += a.z*b4.z; acc[2][3] += a.z*b4.w;
      acc[3][0] += a.w*b4.x; acc[3][1] += a.w*b4.y; acc[3][2] += a.w*b4.z; acc[3][3] += a.w*b4.w;
    }
    __syncthreads();
  }
  float sn[4], sm[4];
#pragma unroll
  for(int i=0;i<4;++i) sn[i] = sq[(long)b*N_ + n0 + ty*4 + i];
#pragma unroll
  for(int j=0;j<4;++j) sm[j] = sq[(long)b*N_ + m0 + tx*4 + j];
#pragma unroll
  for(int i=0;i<4;++i){
    long row = (long)b*N_ + n0 + ty*4 + i;
    float4 r;
    r.x = 2.f*acc[i][0] - sn[i] - sm[0];
    r.y = 2.f*acc[i][1] - sn[i] - sm[1];
    r.z = 2.f*acc[i][2] - sn[i] - sm[2];
    r.w = 2.f*acc[i][3] - sn[i] - sm[3];
    *(float4*)&negd[row*N_ + m0 + tx*4] = r;
  }
}

// K9: top-9 per row
__global__ __launch_bounds__(256) void k_topk(const float* __restrict__ negd, int* __restrict__ idx){
  int t = threadIdx.x, wv = t >> 6, l = t & 63;
  long r = (long)blockIdx.x*4 + wv;
  const float* row = negd + r*N_;
  float vals[16];
#pragma unroll
  for(int j=0;j<16;++j) vals[j] = row[l + 64*j];
#pragma unroll
  for(int p=0; p<K_; ++p){
    float bv = vals[0]; int bj = 0;
#pragma unroll
    for(int j=1;j<16;++j) if(vals[j] > bv){ bv = vals[j]; bj = j; }
    int bm = l + 64*bj;
#pragma unroll
    for(int d=1; d<64; d<<=1){
      float ov = __shfl_xor(bv, d);
      int   om = __shfl_xor(bm, d);
      if(ov > bv || (ov == bv && om < bm)){ bv = ov; bm = om; }
    }
#pragma unroll
    for(int j=0;j<16;++j) if(bm == l + 64*j) vals[j] = -INFINITY;
    if(l == 0) idx[r*K_ + p] = bm;
  }
}

// K10: graph MLP (v2: float4 weights + split accumulator chains)
__global__ __launch_bounds__(256) void k_graph_mlp(const float* __restrict__ xf, const int* __restrict__ idx,
                                                   const float* __restrict__ mrw, const float* __restrict__ mrb,
                                                   const float* __restrict__ g2, const float* __restrict__ b2,
                                                   const float* __restrict__ fc2w, const float* __restrict__ fc2b,
                                                   const float* __restrict__ g3, const float* __restrict__ b3,
                                                   const float* __restrict__ amapT, float* __restrict__ goutT){
  int t = threadIdx.x, wv = t >> 6, l = t & 63;
  long r = (long)blockIdx.x*4 + wv;
  long b = r >> 10;
  const float* frow = xf + r*G_;
  int o2s = (l < 16) ? (64 + l) : 0;
  float f0 = frow[l];
  float f1 = frow[o2s];
  const int* ixp = idx + r*K_;
  int nbx[K_];
#pragma unroll
  for(int k=0;k<K_;++k) nbx[k] = ixp[k];
  float m0 = -INFINITY, m1 = -INFINITY;
#pragma unroll
  for(int k=0;k<K_;++k){
    const float* nr = xf + ((long)b*N_ + nbx[k])*G_;
    m0 = fmaxf(m0, nr[l]);
    m1 = fmaxf(m1, nr[o2s]);
  }
  float xj0 = m0 - f0, xj1 = m1 - f1;
  __shared__ float y[4][G2_];
  __shared__ float z[4][G2_];
  y[wv][2*l]   = f0;
  y[wv][2*l+1] = xj0;
  if(l < 16){ y[wv][128+2*l] = f1; y[wv][128+2*l+1] = xj1; }
  __syncthreads();
  auto zcalc = [&](int o)->float{
    int h = o / 40;
    const float4* yy = (const float4*)&y[wv][h*40];
    const float4* wr = (const float4*)(mrw + (long)o*40);
    float4 A = {0,0,0,0};
#pragma unroll
    for(int i=0;i<10;++i){
      float4 w4 = wr[i], y4 = yy[i];
      A.x += w4.x*y4.x; A.y += w4.y*y4.y; A.z += w4.z*y4.z; A.w += w4.w*y4.w;
    }
    float a = (A.x+A.y)+(A.z+A.w) + mrb[o];
    float v = a*(g2[o]*BNS_) + b2[o];
    return v * 0.5f * (1.0f + erff(v * INVSQRT2_));
  };
  float z1v = zcalc(l);
  float z2v = zcalc(64 + l);
  float z3v = (l < 32) ? zcalc(128 + l) : 0.f;
  z[wv][l] = z1v;
  z[wv][64+l] = z2v;
  if(l < 32) z[wv][128+l] = z3v;
  __syncthreads();
  auto z2calc = [&](int o)->float{
    const float4* wr = (const float4*)(fc2w + (long)o*G2_);
    const float4* zz = (const float4*)&z[wv][0];
    float4 A = {0,0,0,0}, Bv = {0,0,0,0};
#pragma unroll
    for(int j=0;j<40;j+=2){
      float4 w4 = wr[j],   z4 = zz[j];
      float4 w5 = wr[j+1], z5 = zz[j+1];
      A.x  += w4.x*z4.x; A.y  += w4.y*z4.y; A.z  += w4.z*z4.z; A.w  += w4.w*z4.w;
      Bv.x += w5.x*z5.x; Bv.y += w5.y*z5.y; Bv.z += w5.z*z5.z; Bv.w += w5.w*z5.w;
    }
    float a = ((A.x+A.y)+(A.z+A.w)) + ((Bv.x+Bv.y)+(Bv.z+Bv.w)) + fc2b[o];
    return a*(g3[o]*BNS_) + b3[o];
  };
  float r0 = z2calc(l) + amapT[r*G_ + l];
  goutT[r*G_ + l] = r0;
  if(l < 16){
    float r1 = z2calc(64+l) + amapT[r*G_ + 64 + l];
    goutT[r*G_ + 64 + l] = r1;
  }
}

// K12: softmax over cls + PV -> bf16 aob[b][n][c]
__global__ __launch_bounds__(256) void k_softmax_pv(const float* __restrict__ goutT, const float* __restrict__ kv,
                                                    unsigned short* __restrict__ aob){
  int bh = blockIdx.x; int b = bh >> 2, h = bh & 3;
  int n0 = blockIdx.y * 64;
  __shared__ float vs[CLS_][HD_];
  __shared__ float os[HD_][65];
  int t = threadIdx.x, wv = t >> 6, l = t & 63;
  const float* vb = kv + (long)b*CLS_*1024 + C_ + h*HD_;
  for(int i = t; i < CLS_*32; i += 256){
    int cls = i >> 5;
    int c4 = (i & 31)*4;
    float4 v = *(const float4*)&vb[(long)cls*1024 + c4];
    vs[cls][c4] = v.x; vs[cls][c4+1] = v.y; vs[cls][c4+2] = v.z; vs[cls][c4+3] = v.w;
  }
  __syncthreads();
  for(int ni=0; ni<16; ++ni){
    int n = n0 + wv*16 + ni;
    const float* gr = goutT + ((long)b*N_ + n)*G_ + h*CLS_;
    float x = (l < CLS_) ? gr[l] : -INFINITY;
    float mx = wfmax(x);
    float p = (l < CLS_) ? expf(x - mx) : 0.f;
    float s = wsum(p);
    float pn = p / s;
    float a0 = 0.f, a1 = 0.f;
#pragma unroll
    for(int cls=0; cls<CLS_; ++cls){
      float pv = __shfl(pn, cls);
      a0 += pv * vs[cls][l];
      a1 += pv * vs[cls][64+l];
    }
    os[l][wv*16+ni] = a0;
    os[64+l][wv*16+ni] = a1;
  }
  __syncthreads();
  unsigned short* ob = aob + ((long)b*N_ + n0)*C_ + h*HD_;
#pragma unroll
  for(int j=0;j<16;++j){
    int idx = t + 256*j;          // 4096 = 64 n x 64 ushort2
    int n = idx >> 6, j2 = idx & 63;
    int d = 2*j2;
    ushort2 u;
    u.x = f2b(os[d][n]);
    u.y = f2b(os[d+1][n]);
    *(ushort2*)&ob[(long)n*C_ + d] = u;
  }
}

extern "C" void kernel_launch(void* const* d_in, const int* in_sizes, int n_in,
                              void* d_out, int out_size, void* d_ws, size_t ws_size,
                              hipStream_t stream){
  const float* x_cls   = (const float*)d_in[0];
  const float* x_patch = (const float*)d_in[1];
  const float* norm_x_w = (const float*)d_in[2];
  const float* norm_x_b = (const float*)d_in[3];
  const float* pq_w  = (const float*)d_in[4];
  const float* pq_b  = (const float*)d_in[5];
  const float* ncls_w = (const float*)d_in[6];
  const float* ncls_b = (const float*)d_in[7];
  const float* pkv_w = (const float*)d_in[8];
  const float* pkv_b = (const float*)d_in[9];
  const float* fc1_w = (const float*)d_in[10];
  const float* fc1_b = (const float*)d_in[11];
  const float* bn1_g = (const float*)d_in[12];
  const float* bn1_b = (const float*)d_in[13];
  const float* mr_w  = (const float*)d_in[14];
  const float* mr_b  = (const float*)d_in[15];
  const float* bn2_g = (const float*)d_in[16];
  const float* bn2_b = (const float*)d_in[17];
  const float* fc2_w = (const float*)d_in[18];
  const float* fc2_b = (const float*)d_in[19];
  const float* bn3_g = (const float*)d_in[20];
  const float* bn3_b = (const float*)d_in[21];
  const float* proj_w = (const float*)d_in[22];
  const float* proj_b = (const float*)d_in[23];

  float* ws = (float*)d_ws;
  float* part   = ws + OFF_PART;
  float* stats  = ws + OFF_STATS;
  float* qbuf   = ws + OFF_Q;
  float* kvbuf  = ws + OFF_KV;
  float* amapT  = ws + OFF_AMAPT;
  float* xf     = ws + OFF_XF;
  float* xubuf  = ws + OFF_XU;
  float* sqbuf  = ws + OFF_SQ;
  float* negd   = ws + OFF_NEGD;
  int*   idxbuf = (int*)(ws + OFF_IDX);
  float* goutT  = ws + OFF_GOUTT;
  unsigned short* xnb = (unsigned short*)(ws + OFF_NEGD);   // overlay: dead before negd is written
  unsigned short* aob = (unsigned short*)(ws + OFF_NEGD);   // overlay: negd dead after topk
  unsigned short* wqb = (unsigned short*)(ws + OFF_WQB);
  unsigned short* wpb = (unsigned short*)(ws + OFF_WPB);
  float* out = (float*)d_out;

  k_stats_partial<<<1024, 256, 0, stream>>>(x_patch, part);
  k_stats_final<<<16, 64, 0, stream>>>(part, stats);
  k_xn_t<<<dim3(16,8,16), 256, 0, stream>>>(x_patch, stats, norm_x_w, norm_x_b, xnb);
  k_wconv<<<dim3(256,2), 256, 0, stream>>>(pq_w, proj_w, wqb, wpb);
  k_gemm_mfma<false><<<dim3(8,4,16), 256, 0, stream>>>(wqb, xnb, pq_b, nullptr, qbuf);
  k_cls_kv<<<dim3(16,8), 256, 0, stream>>>(x_cls, ncls_w, ncls_b, pkv_w, pkv_b, kvbuf);
  k_attn_amap<<<dim3(64,16), 256, 0, stream>>>(qbuf, kvbuf, amapT);
  k_fc1<<<4096, 256, 0, stream>>>(amapT, fc1_w, fc1_b, bn1_g, bn1_b, xf, xubuf, sqbuf);
  k_negd<<<dim3(16,16,16), 256, 0, stream>>>(xubuf, sqbuf, negd);
  k_topk<<<4096, 256, 0, stream>>>(negd, idxbuf);
  k_graph_mlp<<<4096, 256, 0, stream>>>(xf, idxbuf, mr_w, mr_b, bn2_g, bn2_b,
                                        fc2_w, fc2_b, bn3_g, bn3_b, amapT, goutT);
  k_softmax_pv<<<dim3(64,16), 256, 0, stream>>>(goutT, kvbuf, aob);
  k_gemm_mfma<true><<<dim3(8,4,16), 256, 0, stream>>>(wpb, aob, proj_b, x_patch, out);
}

// Round 3
// 262.979 us; speedup vs baseline: 2.2048x; 1.4798x over previous
//
#include <hip/hip_runtime.h>
#include <math.h>

#define DI __device__ __forceinline__

constexpr int B_ = 16, CLS_ = 20, C_ = 512, H_ = 4, HD_ = 128, N_ = 1024, G_ = 80, G2_ = 160, K_ = 9;
constexpr float EPS_ = 1e-5f;
constexpr float BNS_ = 0.9999950000374997f;     // 1/sqrt(1+1e-5)
constexpr float SCALE_ = 0.08838834764831845f;  // 128^-0.5
constexpr float INVSQRT2_ = 0.7071067811865475f;

typedef __attribute__((ext_vector_type(8))) short bf16x8;
typedef __attribute__((ext_vector_type(4))) float f32x4;

// ---- workspace layout (float slots) ----
constexpr long OFF_PART  = 0;                    // 2048
constexpr long OFF_STATS = 2048;                 // 32
constexpr long OFF_Q     = 4096;                 // 16*512*1024 fp32
constexpr long OFF_KV    = OFF_Q     + 8388608;  // 16*20*1024
constexpr long OFF_AMAPT = OFF_KV    + 327680;   // 16*1024*80
constexpr long OFF_XF    = OFF_AMAPT + 1310720;
constexpr long OFF_XUB   = OFF_XF    + 1310720;  // 16*1024*96 bf16 = 786432 float slots
constexpr long OFF_W1BD  = OFF_XUB   + 786432;   // 160*160 bf16 = 12800 -> 16384 slots
constexpr long OFF_FC2B  = OFF_W1BD  + 16384;    // 80*160 bf16 -> 8192 slots
constexpr long OFF_SQ    = OFF_XUB   + 1310720;  // 16*1024  (after old XU block)
constexpr long OFF_NEGD  = OFF_SQ    + 16384;    // 16*1024*1024 fp32; overlays xn_bf16 (early) / attnout_bf16 (late)
constexpr long OFF_IDX   = OFF_NEGD  + 16777216; // 16*1024*9 int
constexpr long OFF_GOUTT = OFF_IDX   + 147456;   // 16*1024*80
constexpr long OFF_WQB   = OFF_GOUTT + 1310720;  // 512*512 bf16 = 131072 float slots
constexpr long OFF_WPB   = OFF_WQB   + 131072;
constexpr long OFF_Y     = OFF_WPB   + 131072;   // 16384*160 bf16 = 1310720 float slots

DI float wsum(float v){
#pragma unroll
  for(int d=1; d<64; d<<=1) v += __shfl_xor(v, d);
  return v;
}
DI float wfmax(float v){
#pragma unroll
  for(int d=1; d<64; d<<=1) v = fmaxf(v, __shfl_xor(v, d));
  return v;
}
DI unsigned short f2b(float f){
  unsigned u = __float_as_uint(f);
  unsigned r = (u + 0x7FFFu + ((u >> 16) & 1u)) >> 16;
  return (unsigned short)r;
}

#define GLOAD16(g, s) __builtin_amdgcn_global_load_lds((const __attribute__((address_space(1))) void*)(g), \
                        (__attribute__((address_space(3))) void*)(s), 16, 0, 0)

// K1a: per-segment partial sums of x_patch
__global__ __launch_bounds__(256) void k_stats_partial(const float* __restrict__ x, float* __restrict__ part){
  int blk = blockIdx.x;                 // b*64+seg
  const float4* xp = (const float4*)x;
  long base4 = (long)blk * 2048;
  int t = threadIdx.x;
  float s = 0.f, ss = 0.f;
#pragma unroll
  for(int j=0;j<8;++j){
    float4 v = xp[base4 + t + 256*j];
    s  += v.x + v.y + v.z + v.w;
    ss += v.x*v.x + v.y*v.y + v.z*v.z + v.w*v.w;
  }
  s = wsum(s); ss = wsum(ss);
  __shared__ float rs[4], rss[4];
  int wv = t >> 6;
  if((t & 63) == 0){ rs[wv] = s; rss[wv] = ss; }
  __syncthreads();
  if(t == 0){
    part[blk*2]   = rs[0]+rs[1]+rs[2]+rs[3];
    part[blk*2+1] = rss[0]+rss[1]+rss[2]+rss[3];
  }
}

__global__ __launch_bounds__(64) void k_stats_final(const float* __restrict__ part, float* __restrict__ stats){
  int b = blockIdx.x, t = threadIdx.x;
  float s  = part[(b*64+t)*2];
  float ss = part[(b*64+t)*2+1];
  s = wsum(s); ss = wsum(ss);
  if(t == 0){
    const float cnt = (float)(C_ * N_);
    float m = s / cnt;
    float var = ss / cnt - m*m;
    stats[b*2]   = m;
    stats[b*2+1] = 1.0f / sqrtf(var + EPS_);
  }
}

// K2: norm + transpose + bf16: xnb[b][n][c]
__global__ __launch_bounds__(256) void k_xn_t(const float* __restrict__ x, const float* __restrict__ stats,
                                              const float* __restrict__ nw, const float* __restrict__ nb,
                                              unsigned short* __restrict__ xnb){
  __shared__ float tile[64][65];
  int b = blockIdx.z, c0 = blockIdx.y*64, n0 = blockIdx.x*64;
  float m = stats[b*2], inv = stats[b*2+1];
  int t = threadIdx.x;
  const float* xb = x + ((long)b*C_ + c0)*N_ + n0;
#pragma unroll
  for(int j=0;j<4;++j){
    int idx = t + 256*j;
    int r = idx >> 4, c4 = (idx & 15)*4;
    float a = inv * nw[c0+r];
    float bb = nb[c0+r] - m*a;
    float4 v = *(const float4*)&xb[(long)r*N_ + c4];
    tile[r][c4]   = v.x*a + bb;
    tile[r][c4+1] = v.y*a + bb;
    tile[r][c4+2] = v.z*a + bb;
    tile[r][c4+3] = v.w*a + bb;
  }
  __syncthreads();
  unsigned short* ob = xnb + ((long)b*N_ + n0)*C_ + c0;
#pragma unroll
  for(int j=0;j<8;++j){
    int idx = t + 256*j;
    int n = idx >> 5, cc = (idx & 31)*2;
    ushort2 u;
    u.x = f2b(tile[cc][n]);
    u.y = f2b(tile[cc+1][n]);
    *(ushort2*)&ob[(long)n*C_ + cc] = u;
  }
}

// weight fp32 -> bf16 (both 512x512 matrices)
__global__ __launch_bounds__(256) void k_wconv(const float* __restrict__ a, const float* __restrict__ b,
                                               unsigned short* __restrict__ oa, unsigned short* __restrict__ ob){
  long i = (long)blockIdx.x*256 + threadIdx.x;
  const float4* src = (const float4*)(blockIdx.y == 0 ? a : b);
  unsigned short* dst = blockIdx.y == 0 ? oa : ob;
  float4 v = src[i];
  uint2 o;
  o.x = (unsigned)f2b(v.x) | ((unsigned)f2b(v.y) << 16);
  o.y = (unsigned)f2b(v.z) | ((unsigned)f2b(v.w) << 16);
  ((uint2*)dst)[i] = o;
}

// small-weight prep: block-diag mixer weight (160x160) + fc2 (80x160) in bf16
__global__ __launch_bounds__(256) void k_wsmall(const float* __restrict__ mrw, const float* __restrict__ fc2w,
                                                unsigned short* __restrict__ w1bd, unsigned short* __restrict__ fc2b16){
  int row = blockIdx.x, t = threadIdx.x;
  if(t >= 160) return;
  if(row < 160){
    unsigned short v = 0;
    if(t/40 == row/40) v = f2b(mrw[row*40 + (t % 40)]);
    w1bd[row*160 + t] = v;
  } else {
    fc2b16[(row-160)*160 + t] = f2b(fc2w[(long)(row-160)*160 + t]);
  }
}

// MFMA GEMM: Out[b][o][n] = sum_c Wb[o][c]*Xb[b][n][c] + bias[o] (+Res)
template<bool RES>
__global__ __launch_bounds__(256) void k_gemm_mfma(const unsigned short* __restrict__ Wb,
                                                   const unsigned short* __restrict__ Xb,
                                                   const float* __restrict__ bias,
                                                   const float* __restrict__ Res,
                                                   float* __restrict__ Out){
  __shared__ unsigned short Al[4096];   // [128 rows(o)][32 k]
  __shared__ unsigned short Bl[4096];   // [128 rows(n)][32 k]
  int b = blockIdx.z;
  int o0 = blockIdx.y*128, n0 = blockIdx.x*128;
  int t = threadIdx.x, w = t >> 6, l = t & 63;
  int wr = w >> 1, wc = w & 1;
  f32x4 acc[4][4] = {};
  const unsigned short* Wt = Wb + (long)(o0 + w*16 + (l>>2))*512 + (l&3)*8;
  const unsigned short* Xt = Xb + ((long)b*N_ + n0 + w*16 + (l>>2))*512 + (l&3)*8;
  int ra = wr*64 + (l & 15);
  int rb = wc*64 + (l & 15);
  int kq = (l >> 4) * 8;
  for(int k0 = 0; k0 < 512; k0 += 32){
    if(k0) __syncthreads();
    GLOAD16(Wt + k0,            &Al[w*512]);
    GLOAD16(Wt + 64*512 + k0,   &Al[2048 + w*512]);
    GLOAD16(Xt + k0,            &Bl[w*512]);
    GLOAD16(Xt + 64*512 + k0,   &Bl[2048 + w*512]);
    __syncthreads();
    bf16x8 af[4], bfr[4];
#pragma unroll
    for(int i=0;i<4;++i){
      af[i]  = *(const bf16x8*)&Al[(ra + i*16)*32 + kq];
      bfr[i] = *(const bf16x8*)&Bl[(rb + i*16)*32 + kq];
    }
#pragma unroll
    for(int mi=0; mi<4; ++mi)
#pragma unroll
      for(int ni=0; ni<4; ++ni)
        acc[mi][ni] = __builtin_amdgcn_mfma_f32_16x16x32_bf16(af[mi], bfr[ni], acc[mi][ni], 0, 0, 0);
  }
  long obase = ((long)b*C_ + o0 + wr*64)*N_ + n0 + wc*64 + (l & 15);
  int r0 = (l >> 4) * 4;
#pragma unroll
  for(int mi=0; mi<4; ++mi){
#pragma unroll
    for(int r=0; r<4; ++r){
      int row = mi*16 + r0 + r;
      float bi = bias[o0 + wr*64 + row];
#pragma unroll
      for(int ni=0; ni<4; ++ni){
        long oi = obase + (long)row*N_ + ni*16;
        float v = acc[mi][ni][r] + bi;
        if(RES) v += Res[oi];
        Out[oi] = v;
      }
    }
  }
}

// K4: cls layernorm + kv projection
__global__ __launch_bounds__(256) void k_cls_kv(const float* __restrict__ xcls,
                                                const float* __restrict__ ncw, const float* __restrict__ ncb,
                                                const float* __restrict__ pkvw, const float* __restrict__ pkvb,
                                                float* __restrict__ kv){
  int b = blockIdx.x;
  int ochunk = blockIdx.y;
  __shared__ float xc[CLS_][C_];
  int t = threadIdx.x, wv = t >> 6, l = t & 63;
  for(int cls = wv; cls < CLS_; cls += 4){
    const float* xr = xcls + ((long)b*CLS_ + cls) * C_;
    float vals[8];
    float s = 0.f, ss = 0.f;
#pragma unroll
    for(int j=0;j<8;++j){ float v = xr[l + 64*j]; vals[j] = v; s += v; ss += v*v; }
    s = wsum(s); ss = wsum(ss);
    float m = s / (float)C_;
    float var = ss / (float)C_ - m*m;
    float inv = 1.0f / sqrtf(var + EPS_);
#pragma unroll
    for(int j=0;j<8;++j){
      int c = l + 64*j;
      xc[cls][c] = (vals[j]-m)*inv*ncw[c] + ncb[c];
    }
  }
  __syncthreads();
  int o = ochunk*128 + (t & 127);
  int cls0 = (t >> 7) * 10;
  float acc[10] = {};
  const float* wrow = pkvw + (long)o * C_;
  for(int k4 = 0; k4 < C_; k4 += 4){
    float4 w4 = *(const float4*)&wrow[k4];
#pragma unroll
    for(int i=0;i<10;++i){
      acc[i] += w4.x*xc[cls0+i][k4] + w4.y*xc[cls0+i][k4+1] + w4.z*xc[cls0+i][k4+2] + w4.w*xc[cls0+i][k4+3];
    }
  }
  float bo = pkvb[o];
#pragma unroll
  for(int i=0;i<10;++i) kv[((long)b*CLS_ + cls0+i)*1024 + o] = acc[i] + bo;
}

// K5: attn logits -> amapT[b][n][h*20+cls]
__global__ __launch_bounds__(256) void k_attn_amap(const float* __restrict__ q, const float* __restrict__ kv,
                                                   float* __restrict__ amapT){
  int bh = blockIdx.x; int b = bh >> 2, h = bh & 3;
  int n0 = blockIdx.y * 64;
  __shared__ float qs[HD_][65];
  __shared__ float ks[CLS_][HD_];
  int t = threadIdx.x, wv = t >> 6, l = t & 63;
  const float* qb = q + ((long)b*C_ + h*HD_) * N_ + n0;
#pragma unroll
  for(int j=0;j<8;++j){
    int idx = t + 256*j;
    int d = idx >> 4;
    int c4 = (idx & 15) * 4;
    float4 v = *(const float4*)&qb[(long)d * N_ + c4];
    qs[d][c4] = v.x; qs[d][c4+1] = v.y; qs[d][c4+2] = v.z; qs[d][c4+3] = v.w;
  }
  const float* kvb = kv + (long)b*CLS_*1024 + h*HD_;
  for(int idx = t; idx < CLS_*32; idx += 256){
    int cls = idx >> 5;
    int c4 = (idx & 31) * 4;
    float4 v = *(const float4*)&kvb[(long)cls*1024 + c4];
    ks[cls][c4] = v.x; ks[cls][c4+1] = v.y; ks[cls][c4+2] = v.z; ks[cls][c4+3] = v.w;
  }
  __syncthreads();
#pragma unroll
  for(int ci=0; ci<5; ++ci){
    int cls = wv*5 + ci;
    float a0=0.f, a1=0.f, a2=0.f, a3=0.f;
#pragma unroll 8
    for(int d=0; d<HD_; d+=4){
      float4 k4 = *(const float4*)&ks[cls][d];
      a0 += qs[d][l]  *k4.x;
      a1 += qs[d+1][l]*k4.y;
      a2 += qs[d+2][l]*k4.z;
      a3 += qs[d+3][l]*k4.w;
    }
    amapT[((long)b*N_ + n0 + l)*G_ + h*CLS_ + cls] = ((a0+a1)+(a2+a3)) * SCALE_;
  }
}

// K6: fc1+bn1 -> xf ; normalize -> xub(bf16, K-padded 96), sq. one wave per row
__global__ __launch_bounds__(256) void k_fc1(const float* __restrict__ amapT, const float* __restrict__ w,
                                             const float* __restrict__ bias, const float* __restrict__ g1,
                                             const float* __restrict__ b1,
                                             float* __restrict__ xf, unsigned short* __restrict__ xub,
                                             float* __restrict__ sq){
  int t = threadIdx.x, wv = t >> 6, l = t & 63;
  long r = (long)blockIdx.x*4 + wv;
  __shared__ float arow[4][G_];
  const float* ap = amapT + r*G_;
  arow[wv][l] = ap[l];
  if(l < 16) arow[wv][64+l] = ap[64+l];
  __syncthreads();
  int o2 = (l < 16) ? (64 + l) : 0;
  const float* w0 = w + (long)l*G_;
  const float* w1 = w + (long)o2*G_;
  float acc0 = 0.f, acc1 = 0.f;
#pragma unroll 8
  for(int g=0; g<G_; ++g){
    float a = arow[wv][g];
    acc0 += w0[g]*a;
    acc1 += w1[g]*a;
  }
  float v0 = (acc0 + bias[l])  * (g1[l]*BNS_)  + b1[l];
  float v1 = (acc1 + bias[o2]) * (g1[o2]*BNS_) + b1[o2];
  xf[r*G_ + l] = v0;
  if(l < 16) xf[r*G_ + 64 + l] = v1;
  float ssq = v0*v0 + ((l<16) ? v1*v1 : 0.f);
  ssq = wsum(ssq);
  float nrm = sqrtf(ssq);
  float invn = 1.0f / fmaxf(nrm, 1e-12f);
  float u0 = v0*invn, u1 = v1*invn;
  float s2 = u0*u0 + ((l<16) ? u1*u1 : 0.f);
  s2 = wsum(s2);
  xub[r*96 + l] = f2b(u0);
  if(l < 16) xub[r*96 + 64 + l] = f2b(u1);
  else if(l < 32) xub[r*96 + 64 + l] = 0;    // zero K-pad cols 80..95
  if(l == 0) sq[r] = s2;
}

// K8: neg_d via bf16 MFMA: 128x128 tile, K=96 (padded)
__global__ __launch_bounds__(256) void k_negd_mfma(const unsigned short* __restrict__ xub,
                                                   const float* __restrict__ sq,
                                                   float* __restrict__ negd){
  __shared__ unsigned short Al[128*96];
  __shared__ unsigned short Bl[128*96];
  int b = blockIdx.z;
  int n0 = blockIdx.y*128, m0 = blockIdx.x*128;
  int t = threadIdx.x, w = t >> 6, l = t & 63;
  int wr = w >> 1, wc = w & 1;
  const unsigned short* gA = xub + ((long)b*N_ + n0)*96;
  const unsigned short* gB = xub + ((long)b*N_ + m0)*96;
#pragma unroll
  for(int rd=0; rd<6; ++rd){
    int chunk = rd*4 + w;
    GLOAD16(gA + chunk*512 + l*8, &Al[chunk*512]);
    GLOAD16(gB + chunk*512 + l*8, &Bl[chunk*512]);
  }
  __syncthreads();
  f32x4 acc[4][4] = {};
  int ra = wr*64 + (l & 15);
  int rb = wc*64 + (l & 15);
#pragma unroll
  for(int ks=0; ks<3; ++ks){
    int kq = ks*32 + (l >> 4)*8;
    bf16x8 af[4], bfr[4];
#pragma unroll
    for(int i=0;i<4;++i){
      af[i]  = *(const bf16x8*)&Al[(ra + i*16)*96 + kq];
      bfr[i] = *(const bf16x8*)&Bl[(rb + i*16)*96 + kq];
    }
#pragma unroll
    for(int mi=0; mi<4; ++mi)
#pragma unroll
      for(int ni=0; ni<4; ++ni)
        acc[mi][ni] = __builtin_amdgcn_mfma_f32_16x16x32_bf16(af[mi], bfr[ni], acc[mi][ni], 0, 0, 0);
  }
  int r0 = (l >> 4)*4;
  const float* sqb = sq + (long)b*N_;
#pragma unroll
  for(int mi=0; mi<4; ++mi){
#pragma unroll
    for(int r=0; r<4; ++r){
      int n = n0 + wr*64 + mi*16 + r0 + r;
      float sn = sqb[n];
      long row = ((long)b*N_ + n)*N_;
#pragma unroll
      for(int ni=0; ni<4; ++ni){
        int m = m0 + wc*64 + ni*16 + (l & 15);
        negd[row + m] = 2.f*acc[mi][ni][r] - sn - sqb[m];
      }
    }
  }
}

// K9: top-9 per row
__global__ __launch_bounds__(256) void k_topk(const float* __restrict__ negd, int* __restrict__ idx){
  int t = threadIdx.x, wv = t >> 6, l = t & 63;
  long r = (long)blockIdx.x*4 + wv;
  const float* row = negd + r*N_;
  float vals[16];
#pragma unroll
  for(int j=0;j<16;++j) vals[j] = row[l + 64*j];
#pragma unroll
  for(int p=0; p<K_; ++p){
    float bv = vals[0]; int bj = 0;
#pragma unroll
    for(int j=1;j<16;++j) if(vals[j] > bv){ bv = vals[j]; bj = j; }
    int bm = l + 64*bj;
#pragma unroll
    for(int d=1; d<64; d<<=1){
      float ov = __shfl_xor(bv, d);
      int   om = __shfl_xor(bm, d);
      if(ov > bv || (ov == bv && om < bm)){ bv = ov; bm = om; }
    }
#pragma unroll
    for(int j=0;j<16;++j) if(bm == l + 64*j) vals[j] = -INFINITY;
    if(l == 0) idx[r*K_ + p] = bm;
  }
}

// K10a: gather -> y[b][n][160] bf16 (even=xf, odd=neighbor-max - xf). one wave/row
__global__ __launch_bounds__(256) void k_y(const float* __restrict__ xf, const int* __restrict__ idx,
                                           unsigned short* __restrict__ y){
  int t = threadIdx.x, wv = t >> 6, l = t & 63;
  long r = (long)blockIdx.x*4 + wv;
  long b = r >> 10;
  const float* frow = xf + r*G_;
  int o2s = (l < 16) ? (64 + l) : 0;
  float f0 = frow[l];
  float f1 = frow[o2s];
  const int* ixp = idx + r*K_;
  float m0 = -INFINITY, m1 = -INFINITY;
#pragma unroll
  for(int k=0;k<K_;++k){
    const float* nr = xf + ((long)b*N_ + ixp[k])*G_;
    m0 = fmaxf(m0, nr[l]);
    m1 = fmaxf(m1, nr[o2s]);
  }
  unsigned short* yr = y + r*G2_;
  ushort2 u0; u0.x = f2b(f0); u0.y = f2b(m0 - f0);
  *(ushort2*)&yr[2*l] = u0;
  if(l < 16){
    ushort2 u1; u1.x = f2b(f1); u1.y = f2b(m1 - f1);
    *(ushort2*)&yr[128 + 2*l] = u1;
  }
}

// K10b: MFMA mixer (block-diag 160x160) + bn2 + gelu + fc2 + bn3 + amap -> goutT
// one wave per 16 rows; 4 waves/block; grid 256
__global__ __launch_bounds__(256) void k_mixer_mfma(const unsigned short* __restrict__ y,
                                                    const unsigned short* __restrict__ w1bd,
                                                    const float* __restrict__ mrb,
                                                    const float* __restrict__ g2, const float* __restrict__ b2,
                                                    const unsigned short* __restrict__ fc2b16,
                                                    const float* __restrict__ fc2bias,
                                                    const float* __restrict__ g3, const float* __restrict__ b3,
                                                    const float* __restrict__ amapT, float* __restrict__ goutT){
  __shared__ unsigned short zl[4][16][G2_];   // per-wave private z tiles
  int t = threadIdx.x, w = t >> 6, l = t & 63;
  long row0 = ((long)blockIdx.x*4 + w)*16;
  int lr = l & 15, lk = l >> 4;
  // preload A fragments (y rows) from global (L2/L3 resident)
  bf16x8 ay[5];
  const unsigned short* yrow = y + (row0 + lr)*G2_ + lk*8;
#pragma unroll
  for(int ks=0; ks<5; ++ks) ay[ks] = *(const bf16x8*)&yrow[ks*32];
  // mixer GEMM: z[16 rows][160]
  f32x4 accz[10] = {};
  const unsigned short* wb = w1bd + (long)lr*G2_ + lk*8;
#pragma unroll
  for(int ks=0; ks<5; ++ks){
#pragma unroll
    for(int ct=0; ct<10; ++ct){
      bf16x8 bw = *(const bf16x8*)&wb[ct*16*G2_ + ks*32];
      accz[ct] = __builtin_amdgcn_mfma_f32_16x16x32_bf16(ay[ks], bw, accz[ct], 0, 0, 0);
    }
  }
  // bias + bn2 + gelu -> bf16 z tile in LDS (C layout: col=l&15 -> out, row=(l>>4)*4+i)
#pragma unroll
  for(int ct=0; ct<10; ++ct){
    int o = ct*16 + lr;
    float bi = mrb[o], ga = g2[o]*BNS_, bb = b2[o];
#pragma unroll
    for(int i=0;i<4;++i){
      float v = (accz[ct][i] + bi)*ga + bb;
      float zz = v * 0.5f * (1.0f + erff(v * INVSQRT2_));
      zl[w][lk*4 + i][o] = f2b(zz);
    }
  }
  __syncthreads();
  // fc2: A = z rows, B = fc2 weights (80x160)
  bf16x8 az[5];
#pragma unroll
  for(int ks=0; ks<5; ++ks) az[ks] = *(const bf16x8*)&zl[w][lr][ks*32 + lk*8];
  f32x4 acc2[5] = {};
  const unsigned short* fb = fc2b16 + (long)lr*G2_ + lk*8;
#pragma unroll
  for(int ks=0; ks<5; ++ks){
#pragma unroll
    for(int ct=0; ct<5; ++ct){
      bf16x8 bw = *(const bf16x8*)&fb[ct*16*G2_ + ks*32];
      acc2[ct] = __builtin_amdgcn_mfma_f32_16x16x32_bf16(az[ks], bw, acc2[ct], 0, 0, 0);
    }
  }
  // bn3 + residual(amapT) -> goutT
#pragma unroll
  for(int ct=0; ct<5; ++ct){
    int o = ct*16 + lr;
    float bi = fc2bias[o], ga = g3[o]*BNS_, bb = b3[o];
#pragma unroll
    for(int i=0;i<4;++i){
      long row = row0 + lk*4 + i;
      float v = (acc2[ct][i] + bi)*ga + bb + amapT[row*G_ + o];
      goutT[row*G_ + o] = v;
    }
  }
}

// K12: softmax over cls + PV -> bf16 aob[b][n][c]
__global__ __launch_bounds__(256) void k_softmax_pv(const float* __restrict__ goutT, const float* __restrict__ kv,
                                                    unsigned short* __restrict__ aob){
  int bh = blockIdx.x; int b = bh >> 2, h = bh & 3;
  int n0 = blockIdx.y * 64;
  __shared__ float vs[CLS_][HD_];
  __shared__ float os[HD_][65];
  int t = threadIdx.x, wv = t >> 6, l = t & 63;
  const float* vb = kv + (long)b*CLS_*1024 + C_ + h*HD_;
  for(int i = t; i < CLS_*32; i += 256){
    int cls = i >> 5;
    int c4 = (i & 31)*4;
    float4 v = *(const float4*)&vb[(long)cls*1024 + c4];
    vs[cls][c4] = v.x; vs[cls][c4+1] = v.y; vs[cls][c4+2] = v.z; vs[cls][c4+3] = v.w;
  }
  __syncthreads();
  for(int ni=0; ni<16; ++ni){
    int n = n0 + wv*16 + ni;
    const float* gr = goutT + ((long)b*N_ + n)*G_ + h*CLS_;
    float x = (l < CLS_) ? gr[l] : -INFINITY;
    float mx = wfmax(x);
    float p = (l < CLS_) ? expf(x - mx) : 0.f;
    float s = wsum(p);
    float pn = p / s;
    float a0 = 0.f, a1 = 0.f;
#pragma unroll
    for(int cls=0; cls<CLS_; ++cls){
      float pv = __shfl(pn, cls);
      a0 += pv * vs[cls][l];
      a1 += pv * vs[cls][64+l];
    }
    os[l][wv*16+ni] = a0;
    os[64+l][wv*16+ni] = a1;
  }
  __syncthreads();
  unsigned short* ob = aob + ((long)b*N_ + n0)*C_ + h*HD_;
#pragma unroll
  for(int j=0;j<16;++j){
    int idx = t + 256*j;
    int n = idx >> 6, j2 = idx & 63;
    int d = 2*j2;
    ushort2 u;
    u.x = f2b(os[d][n]);
    u.y = f2b(os[d+1][n]);
    *(ushort2*)&ob[(long)n*C_ + d] = u;
  }
}

extern "C" void kernel_launch(void* const* d_in, const int* in_sizes, int n_in,
                              void* d_out, int out_size, void* d_ws, size_t ws_size,
                              hipStream_t stream){
  const float* x_cls   = (const float*)d_in[0];
  const float* x_patch = (const float*)d_in[1];
  const float* norm_x_w = (const float*)d_in[2];
  const float* norm_x_b = (const float*)d_in[3];
  const float* pq_w  = (const float*)d_in[4];
  const float* pq_b  = (const float*)d_in[5];
  const float* ncls_w = (const float*)d_in[6];
  const float* ncls_b = (const float*)d_in[7];
  const float* pkv_w = (const float*)d_in[8];
  const float* pkv_b = (const float*)d_in[9];
  const float* fc1_w = (const float*)d_in[10];
  const float* fc1_b = (const float*)d_in[11];
  const float* bn1_g = (const float*)d_in[12];
  const float* bn1_b = (const float*)d_in[13];
  const float* mr_w  = (const float*)d_in[14];
  const float* mr_b  = (const float*)d_in[15];
  const float* bn2_g = (const float*)d_in[16];
  const float* bn2_b = (const float*)d_in[17];
  const float* fc2_w = (const float*)d_in[18];
  const float* fc2_b = (const float*)d_in[19];
  const float* bn3_g = (const float*)d_in[20];
  const float* bn3_b = (const float*)d_in[21];
  const float* proj_w = (const float*)d_in[22];
  const float* proj_b = (const float*)d_in[23];

  float* ws = (float*)d_ws;
  float* part   = ws + OFF_PART;
  float* stats  = ws + OFF_STATS;
  float* qbuf   = ws + OFF_Q;
  float* kvbuf  = ws + OFF_KV;
  float* amapT  = ws + OFF_AMAPT;
  float* xf     = ws + OFF_XF;
  float* sqbuf  = ws + OFF_SQ;
  float* negd   = ws + OFF_NEGD;
  int*   idxbuf = (int*)(ws + OFF_IDX);
  float* goutT  = ws + OFF_GOUTT;
  unsigned short* xub    = (unsigned short*)(ws + OFF_XUB);
  unsigned short* w1bd   = (unsigned short*)(ws + OFF_W1BD);
  unsigned short* fc2b16 = (unsigned short*)(ws + OFF_FC2B);
  unsigned short* ybuf   = (unsigned short*)(ws + OFF_Y);
  unsigned short* xnb = (unsigned short*)(ws + OFF_NEGD);   // overlay: dead before negd written
  unsigned short* aob = (unsigned short*)(ws + OFF_NEGD);   // overlay: negd dead after topk
  unsigned short* wqb = (unsigned short*)(ws + OFF_WQB);
  unsigned short* wpb = (unsigned short*)(ws + OFF_WPB);
  float* out = (float*)d_out;

  k_stats_partial<<<1024, 256, 0, stream>>>(x_patch, part);
  k_stats_final<<<16, 64, 0, stream>>>(part, stats);
  k_xn_t<<<dim3(16,8,16), 256, 0, stream>>>(x_patch, stats, norm_x_w, norm_x_b, xnb);
  k_wconv<<<dim3(256,2), 256, 0, stream>>>(pq_w, proj_w, wqb, wpb);
  k_wsmall<<<240, 256, 0, stream>>>(mr_w, fc2_w, w1bd, fc2b16);
  k_gemm_mfma<false><<<dim3(8,4,16), 256, 0, stream>>>(wqb, xnb, pq_b, nullptr, qbuf);
  k_cls_kv<<<dim3(16,8), 256, 0, stream>>>(x_cls, ncls_w, ncls_b, pkv_w, pkv_b, kvbuf);
  k_attn_amap<<<dim3(64,16), 256, 0, stream>>>(qbuf, kvbuf, amapT);
  k_fc1<<<4096, 256, 0, stream>>>(amapT, fc1_w, fc1_b, bn1_g, bn1_b, xf, xub, sqbuf);
  k_negd_mfma<<<dim3(8,8,16), 256, 0, stream>>>(xub, sqbuf, negd);
  k_topk<<<4096, 256, 0, stream>>>(negd, idxbuf);
  k_y<<<4096, 256, 0, stream>>>(xf, idxbuf, ybuf);
  k_mixer_mfma<<<256, 256, 0, stream>>>(ybuf, w1bd, mr_b, bn2_g, bn2_b,
                                        fc2b16, fc2_b, bn3_g, bn3_b, amapT, goutT);
  k_softmax_pv<<<dim3(64,16), 256, 0, stream>>>(goutT, kvbuf, aob);
  k_gemm_mfma<true><<<dim3(8,4,16), 256, 0, stream>>>(wpb, aob, proj_b, x_patch, out);
}

// Round 5
// 248.549 us; speedup vs baseline: 2.3328x; 1.0581x over previous
//
#include <hip/hip_runtime.h>
#include <math.h>

#define DI __device__ __forceinline__

constexpr int B_ = 16, CLS_ = 20, C_ = 512, H_ = 4, HD_ = 128, N_ = 1024, G_ = 80, G2_ = 160, K_ = 9;
constexpr float EPS_ = 1e-5f;
constexpr float BNS_ = 0.9999950000374997f;     // 1/sqrt(1+1e-5)
constexpr float SCALE_ = 0.08838834764831845f;  // 128^-0.5
constexpr float INVSQRT2_ = 0.7071067811865475f;

typedef __attribute__((ext_vector_type(8))) short bf16x8;
typedef __attribute__((ext_vector_type(4))) float f32x4;

// ---- workspace layout (float slots) ----
constexpr long OFF_PART  = 0;                      // 2048
constexpr long OFF_STATS = 2048;                   // 32
constexpr long OFF_EB    = 4096;                   // E bf16 [16][128][512] = 524288 slots
constexpr long OFF_EBB   = OFF_EB    + 524288;     // 1280 fp32
constexpr long OFF_KV    = OFF_EBB   + 2048;       // 16*20*1024
constexpr long OFF_AMAPT = OFF_KV    + 327680;     // 16*1024*80
constexpr long OFF_XF    = OFF_AMAPT + 1310720;
constexpr long OFF_XUB   = OFF_XF    + 1310720;    // bf16 16*1024*96 = 786432 slots
constexpr long OFF_W1BD  = OFF_XUB   + 786432;     // 16384
constexpr long OFF_FC2B  = OFF_W1BD  + 16384;      // 8192
constexpr long OFF_SQ    = OFF_FC2B  + 8192;       // 16384
constexpr long OFF_NEGD  = OFF_SQ    + 16384;      // 16*1024*1024 fp32; overlays xnb (early) / aob (late)
constexpr long OFF_IDX   = OFF_NEGD  + 16777216;   // 147456 ints
constexpr long OFF_GOUTT = OFF_IDX   + 147456;     // 1310720
constexpr long OFF_WPB   = OFF_GOUTT + 1310720;    // 131072 (proj_w bf16)
constexpr long OFF_Y     = OFF_WPB   + 131072;     // 1310720

DI float wsum(float v){
#pragma unroll
  for(int d=1; d<64; d<<=1) v += __shfl_xor(v, d);
  return v;
}
DI unsigned short f2b(float f){
  unsigned u = __float_as_uint(f);
  unsigned r = (u + 0x7FFFu + ((u >> 16) & 1u)) >> 16;
  return (unsigned short)r;
}

#define GLOAD16(g, s) __builtin_amdgcn_global_load_lds((const __attribute__((address_space(1))) void*)(g), \
                        (__attribute__((address_space(3))) void*)(s), 16, 0, 0)

// K1a: per-segment partial sums of x_patch
__global__ __launch_bounds__(256) void k_stats_partial(const float* __restrict__ x, float* __restrict__ part){
  int blk = blockIdx.x;                 // b*64+seg
  const float4* xp = (const float4*)x;
  long base4 = (long)blk * 2048;
  int t = threadIdx.x;
  float s = 0.f, ss = 0.f;
#pragma unroll
  for(int j=0;j<8;++j){
    float4 v = xp[base4 + t + 256*j];
    s  += v.x + v.y + v.z + v.w;
    ss += v.x*v.x + v.y*v.y + v.z*v.z + v.w*v.w;
  }
  s = wsum(s); ss = wsum(ss);
  __shared__ float rs[4], rss[4];
  int wv = t >> 6;
  if((t & 63) == 0){ rs[wv] = s; rss[wv] = ss; }
  __syncthreads();
  if(t == 0){
    part[blk*2]   = rs[0]+rs[1]+rs[2]+rs[3];
    part[blk*2+1] = rss[0]+rss[1]+rss[2]+rss[3];
  }
}

__global__ __launch_bounds__(64) void k_stats_final(const float* __restrict__ part, float* __restrict__ stats){
  int b = blockIdx.x, t = threadIdx.x;
  float s  = part[(b*64+t)*2];
  float ss = part[(b*64+t)*2+1];
  s = wsum(s); ss = wsum(ss);
  if(t == 0){
    const float cnt = (float)(C_ * N_);
    float m = s / cnt;
    float var = ss / cnt - m*m;
    stats[b*2]   = m;
    stats[b*2+1] = 1.0f / sqrtf(var + EPS_);
  }
}

// K2: norm + transpose + bf16: xnb[b][n][c]
__global__ __launch_bounds__(256) void k_xn_t(const float* __restrict__ x, const float* __restrict__ stats,
                                              const float* __restrict__ nw, const float* __restrict__ nb,
                                              unsigned short* __restrict__ xnb){
  __shared__ float tile[64][65];
  int b = blockIdx.z, c0 = blockIdx.y*64, n0 = blockIdx.x*64;
  float m = stats[b*2], inv = stats[b*2+1];
  int t = threadIdx.x;
  const float* xb = x + ((long)b*C_ + c0)*N_ + n0;
#pragma unroll
  for(int j=0;j<4;++j){
    int idx = t + 256*j;
    int r = idx >> 4, c4 = (idx & 15)*4;
    float a = inv * nw[c0+r];
    float bb = nb[c0+r] - m*a;
    float4 v = *(const float4*)&xb[(long)r*N_ + c4];
    tile[r][c4]   = v.x*a + bb;
    tile[r][c4+1] = v.y*a + bb;
    tile[r][c4+2] = v.z*a + bb;
    tile[r][c4+3] = v.w*a + bb;
  }
  __syncthreads();
  unsigned short* ob = xnb + ((long)b*N_ + n0)*C_ + c0;
#pragma unroll
  for(int j=0;j<8;++j){
    int idx = t + 256*j;
    int n = idx >> 5, cc = (idx & 31)*2;
    ushort2 u;
    u.x = f2b(tile[cc][n]);
    u.y = f2b(tile[cc+1][n]);
    *(ushort2*)&ob[(long)n*C_ + cc] = u;
  }
}

// proj weight fp32 -> bf16
__global__ __launch_bounds__(256) void k_wconv(const float* __restrict__ a, unsigned short* __restrict__ oa){
  long i = (long)blockIdx.x*256 + threadIdx.x;
  float4 v = ((const float4*)a)[i];
  uint2 o;
  o.x = (unsigned)f2b(v.x) | ((unsigned)f2b(v.y) << 16);
  o.y = (unsigned)f2b(v.z) | ((unsigned)f2b(v.w) << 16);
  ((uint2*)oa)[i] = o;
}

// small-weight prep: block-diag mixer weight (160x160) + fc2 (80x160) in bf16
__global__ __launch_bounds__(256) void k_wsmall(const float* __restrict__ mrw, const float* __restrict__ fc2w,
                                                unsigned short* __restrict__ w1bd, unsigned short* __restrict__ fc2b16){
  int row = blockIdx.x, t = threadIdx.x;
  if(t >= 160) return;
  if(row < 160){
    unsigned short v = 0;
    if(t/40 == row/40) v = f2b(mrw[row*40 + (t % 40)]);
    w1bd[row*160 + t] = v;
  } else {
    fc2b16[(row-160)*160 + t] = f2b(fc2w[(long)(row-160)*160 + t]);
  }
}

// E prep: E[b][g=h*20+cls][c] = SCALE * sum_d k_[b,cls,h*128+d] * pq_w[h*128+d][c]  (bf16, rows 80..127 zero)
//         ebb[b][g] = SCALE * sum_d k_ * pq_b
__global__ __launch_bounds__(256) void k_eprep(const float* __restrict__ kv, const float* __restrict__ pqw,
                                               const float* __restrict__ pqb,
                                               unsigned short* __restrict__ Eb, float* __restrict__ ebb){
  int b = blockIdx.x, hh = blockIdx.y, t = threadIdx.x;
  if(hh == 4){                       // zero-pad rows 80..127
    unsigned* z = (unsigned*)(Eb + ((long)b*128 + 80)*512);
    for(int i=t; i<12288; i+=256) z[i] = 0;
    return;
  }
  int h = hh;
  __shared__ float key[CLS_][HD_];
  for(int i=t; i<CLS_*HD_; i+=256){
    int cls = i >> 7, d = i & 127;
    key[cls][d] = kv[((long)b*CLS_+cls)*1024 + h*HD_ + d];
  }
  __syncthreads();
  float acc[CLS_][2] = {};
  const float* wbase = pqw + (long)h*HD_*C_ + 2*t;
  for(int d=0; d<HD_; ++d){
    float2 w2 = *(const float2*)&wbase[(long)d*C_];
#pragma unroll
    for(int cls=0; cls<CLS_; ++cls){
      float kk = key[cls][d];
      acc[cls][0] += kk*w2.x;
      acc[cls][1] += kk*w2.y;
    }
  }
  unsigned short* erow = Eb + ((long)b*128 + h*CLS_)*512 + 2*t;
#pragma unroll
  for(int cls=0; cls<CLS_; ++cls){
    ushort2 u;
    u.x = f2b(acc[cls][0]*SCALE_);
    u.y = f2b(acc[cls][1]*SCALE_);
    *(ushort2*)&erow[(long)cls*512] = u;
  }
  if(t < CLS_){
    float bacc = 0.f;
    for(int d=0; d<HD_; ++d) bacc += key[t][d]*pqb[h*HD_+d];
    ebb[b*G_ + h*CLS_ + t] = bacc*SCALE_;
  }
}

// amap GEMM: amapT[b][n][g] = sum_c E[b][g][c]*xnb[b][n][c] + ebb[b][g]
__global__ __launch_bounds__(256) void k_amap_gemm(const unsigned short* __restrict__ Eb,
                                                   const unsigned short* __restrict__ Xb,
                                                   const float* __restrict__ ebb,
                                                   float* __restrict__ amapT){
  __shared__ unsigned short Anl[2048];   // 64 n rows x 32 k
  __shared__ unsigned short Bgl[4096];   // 128 g rows x 32 k
  int b = blockIdx.y, n0 = blockIdx.x*64;
  int t = threadIdx.x, w = t >> 6, l = t & 63;
  int wr = w >> 1, wc = w & 1;
  f32x4 acc[2][4] = {};
  const unsigned short* At = Xb + ((long)b*N_ + n0 + w*16 + (l>>2))*512 + (l&3)*8;
  const unsigned short* Bt = Eb + ((long)b*128 + w*16 + (l>>2))*512 + (l&3)*8;
  int ra = wr*32 + (l & 15);
  int rb = wc*64 + (l & 15);
  int kq = (l >> 4) * 8;
  for(int k0 = 0; k0 < 512; k0 += 32){
    if(k0) __syncthreads();
    GLOAD16(At + k0,          &Anl[w*512]);
    GLOAD16(Bt + k0,          &Bgl[w*512]);
    GLOAD16(Bt + 64*512 + k0, &Bgl[2048 + w*512]);
    __syncthreads();
    bf16x8 af[2], bfr[4];
#pragma unroll
    for(int rt=0; rt<2; ++rt) af[rt]  = *(const bf16x8*)&Anl[(ra + rt*16)*32 + kq];
#pragma unroll
    for(int ct=0; ct<4; ++ct) bfr[ct] = *(const bf16x8*)&Bgl[(rb + ct*16)*32 + kq];
#pragma unroll
    for(int rt=0; rt<2; ++rt)
#pragma unroll
      for(int ct=0; ct<4; ++ct)
        acc[rt][ct] = __builtin_amdgcn_mfma_f32_16x16x32_bf16(af[rt], bfr[ct], acc[rt][ct], 0, 0, 0);
  }
  int r0 = (l >> 4)*4;
#pragma unroll
  for(int rt=0; rt<2; ++rt){
#pragma unroll
    for(int r=0; r<4; ++r){
      int n = n0 + wr*32 + rt*16 + r0 + r;
      long rowb = ((long)b*N_ + n)*G_;
#pragma unroll
      for(int ct=0; ct<4; ++ct){
        int g = wc*64 + ct*16 + (l & 15);
        if(g < G_) amapT[rowb + g] = acc[rt][ct][r] + ebb[b*G_ + g];
      }
    }
  }
}

// MFMA GEMM: Out[b][o][n] = sum_c Wb[o][c]*Xb[b][n][c] + bias[o] (+Res)
template<bool RES>
__global__ __launch_bounds__(256) void k_gemm_mfma(const unsigned short* __restrict__ Wb,
                                                   const unsigned short* __restrict__ Xb,
                                                   const float* __restrict__ bias,
                                                   const float* __restrict__ Res,
                                                   float* __restrict__ Out){
  __shared__ unsigned short Al[4096];   // [128 rows(o)][32 k]
  __shared__ unsigned short Bl[4096];   // [128 rows(n)][32 k]
  int b = blockIdx.z;
  int o0 = blockIdx.y*128, n0 = blockIdx.x*128;
  int t = threadIdx.x, w = t >> 6, l = t & 63;
  int wr = w >> 1, wc = w & 1;
  f32x4 acc[4][4] = {};
  const unsigned short* Wt = Wb + (long)(o0 + w*16 + (l>>2))*512 + (l&3)*8;
  const unsigned short* Xt = Xb + ((long)b*N_ + n0 + w*16 + (l>>2))*512 + (l&3)*8;
  int ra = wr*64 + (l & 15);
  int rb = wc*64 + (l & 15);
  int kq = (l >> 4) * 8;
  for(int k0 = 0; k0 < 512; k0 += 32){
    if(k0) __syncthreads();
    GLOAD16(Wt + k0,            &Al[w*512]);
    GLOAD16(Wt + 64*512 + k0,   &Al[2048 + w*512]);
    GLOAD16(Xt + k0,            &Bl[w*512]);
    GLOAD16(Xt + 64*512 + k0,   &Bl[2048 + w*512]);
    __syncthreads();
    bf16x8 af[4], bfr[4];
#pragma unroll
    for(int i=0;i<4;++i){
      af[i]  = *(const bf16x8*)&Al[(ra + i*16)*32 + kq];
      bfr[i] = *(const bf16x8*)&Bl[(rb + i*16)*32 + kq];
    }
#pragma unroll
    for(int mi=0; mi<4; ++mi)
#pragma unroll
      for(int ni=0; ni<4; ++ni)
        acc[mi][ni] = __builtin_amdgcn_mfma_f32_16x16x32_bf16(af[mi], bfr[ni], acc[mi][ni], 0, 0, 0);
  }
  long obase = ((long)b*C_ + o0 + wr*64)*N_ + n0 + wc*64 + (l & 15);
  int r0 = (l >> 4) * 4;
#pragma unroll
  for(int mi=0; mi<4; ++mi){
#pragma unroll
    for(int r=0; r<4; ++r){
      int row = mi*16 + r0 + r;
      float bi = bias[o0 + wr*64 + row];
#pragma unroll
      for(int ni=0; ni<4; ++ni){
        long oi = obase + (long)row*N_ + ni*16;
        float v = acc[mi][ni][r] + bi;
        if(RES) v += Res[oi];
        Out[oi] = v;
      }
    }
  }
}

// K4: cls layernorm + kv projection
__global__ __launch_bounds__(256) void k_cls_kv(const float* __restrict__ xcls,
                                                const float* __restrict__ ncw, const float* __restrict__ ncb,
                                                const float* __restrict__ pkvw, const float* __restrict__ pkvb,
                                                float* __restrict__ kv){
  int b = blockIdx.x;
  int ochunk = blockIdx.y;
  __shared__ float xc[CLS_][C_];
  int t = threadIdx.x, wv = t >> 6, l = t & 63;
  for(int cls = wv; cls < CLS_; cls += 4){
    const float* xr = xcls + ((long)b*CLS_ + cls) * C_;
    float vals[8];
    float s = 0.f, ss = 0.f;
#pragma unroll
    for(int j=0;j<8;++j){ float v = xr[l + 64*j]; vals[j] = v; s += v; ss += v*v; }
    s = wsum(s); ss = wsum(ss);
    float m = s / (float)C_;
    float var = ss / (float)C_ - m*m;
    float inv = 1.0f / sqrtf(var + EPS_);
#pragma unroll
    for(int j=0;j<8;++j){
      int c = l + 64*j;
      xc[cls][c] = (vals[j]-m)*inv*ncw[c] + ncb[c];
    }
  }
  __syncthreads();
  int o = ochunk*128 + (t & 127);
  int cls0 = (t >> 7) * 10;
  float acc[10] = {};
  const float* wrow = pkvw + (long)o * C_;
  for(int k4 = 0; k4 < C_; k4 += 4){
    float4 w4 = *(const float4*)&wrow[k4];
#pragma unroll
    for(int i=0;i<10;++i){
      acc[i] += w4.x*xc[cls0+i][k4] + w4.y*xc[cls0+i][k4+1] + w4.z*xc[cls0+i][k4+2] + w4.w*xc[cls0+i][k4+3];
    }
  }
  float bo = pkvb[o];
#pragma unroll
  for(int i=0;i<10;++i) kv[((long)b*CLS_ + cls0+i)*1024 + o] = acc[i] + bo;
}

// K6: fc1+bn1 -> xf ; normalize -> xub(bf16, K-padded 96), sq. one wave per row
__global__ __launch_bounds__(256) void k_fc1(const float* __restrict__ amapT, const float* __restrict__ w,
                                             const float* __restrict__ bias, const float* __restrict__ g1,
                                             const float* __restrict__ b1,
                                             float* __restrict__ xf, unsigned short* __restrict__ xub,
                                             float* __restrict__ sq){
  int t = threadIdx.x, wv = t >> 6, l = t & 63;
  long r = (long)blockIdx.x*4 + wv;
  __shared__ float arow[4][G_];
  const float* ap = amapT + r*G_;
  arow[wv][l] = ap[l];
  if(l < 16) arow[wv][64+l] = ap[64+l];
  __syncthreads();
  int o2 = (l < 16) ? (64 + l) : 0;
  const float* w0 = w + (long)l*G_;
  const float* w1 = w + (long)o2*G_;
  float acc0 = 0.f, acc1 = 0.f;
#pragma unroll 8
  for(int g=0; g<G_; ++g){
    float a = arow[wv][g];
    acc0 += w0[g]*a;
    acc1 += w1[g]*a;
  }
  float v0 = (acc0 + bias[l])  * (g1[l]*BNS_)  + b1[l];
  float v1 = (acc1 + bias[o2]) * (g1[o2]*BNS_) + b1[o2];
  xf[r*G_ + l] = v0;
  if(l < 16) xf[r*G_ + 64 + l] = v1;
  float ssq = v0*v0 + ((l<16) ? v1*v1 : 0.f);
  ssq = wsum(ssq);
  float nrm = sqrtf(ssq);
  float invn = 1.0f / fmaxf(nrm, 1e-12f);
  float u0 = v0*invn, u1 = v1*invn;
  float s2 = u0*u0 + ((l<16) ? u1*u1 : 0.f);
  s2 = wsum(s2);
  xub[r*96 + l] = f2b(u0);
  if(l < 16) xub[r*96 + 64 + l] = f2b(u1);
  else if(l < 32) xub[r*96 + 64 + l] = 0;    // zero K-pad cols 80..95
  if(l == 0) sq[r] = s2;
}

// K8: neg_d via bf16 MFMA: 128x128 tile, K=96 (padded)
__global__ __launch_bounds__(256) void k_negd_mfma(const unsigned short* __restrict__ xub,
                                                   const float* __restrict__ sq,
                                                   float* __restrict__ negd){
  __shared__ unsigned short Al[128*96];
  __shared__ unsigned short Bl[128*96];
  int b = blockIdx.z;
  int n0 = blockIdx.y*128, m0 = blockIdx.x*128;
  int t = threadIdx.x, w = t >> 6, l = t & 63;
  int wr = w >> 1, wc = w & 1;
  const unsigned short* gA = xub + ((long)b*N_ + n0)*96;
  const unsigned short* gB = xub + ((long)b*N_ + m0)*96;
#pragma unroll
  for(int rd=0; rd<6; ++rd){
    int chunk = rd*4 + w;
    GLOAD16(gA + chunk*512 + l*8, &Al[chunk*512]);
    GLOAD16(gB + chunk*512 + l*8, &Bl[chunk*512]);
  }
  __syncthreads();
  f32x4 acc[4][4] = {};
  int ra = wr*64 + (l & 15);
  int rb = wc*64 + (l & 15);
#pragma unroll
  for(int ks=0; ks<3; ++ks){
    int kq = ks*32 + (l >> 4)*8;
    bf16x8 af[4], bfr[4];
#pragma unroll
    for(int i=0;i<4;++i){
      af[i]  = *(const bf16x8*)&Al[(ra + i*16)*96 + kq];
      bfr[i] = *(const bf16x8*)&Bl[(rb + i*16)*96 + kq];
    }
#pragma unroll
    for(int mi=0; mi<4; ++mi)
#pragma unroll
      for(int ni=0; ni<4; ++ni)
        acc[mi][ni] = __builtin_amdgcn_mfma_f32_16x16x32_bf16(af[mi], bfr[ni], acc[mi][ni], 0, 0, 0);
  }
  int r0 = (l >> 4)*4;
  const float* sqb = sq + (long)b*N_;
#pragma unroll
  for(int mi=0; mi<4; ++mi){
#pragma unroll
    for(int r=0; r<4; ++r){
      int n = n0 + wr*64 + mi*16 + r0 + r;
      float sn = sqb[n];
      long row = ((long)b*N_ + n)*N_;
#pragma unroll
      for(int ni=0; ni<4; ++ni){
        int m = m0 + wc*64 + ni*16 + (l & 15);
        negd[row + m] = 2.f*acc[mi][ni][r] - sn - sqb[m];
      }
    }
  }
}

// K9: top-9 per row
__global__ __launch_bounds__(256) void k_topk(const float* __restrict__ negd, int* __restrict__ idx){
  int t = threadIdx.x, wv = t >> 6, l = t & 63;
  long r = (long)blockIdx.x*4 + wv;
  const float* row = negd + r*N_;
  float vals[16];
#pragma unroll
  for(int j=0;j<16;++j) vals[j] = row[l + 64*j];
#pragma unroll
  for(int p=0; p<K_; ++p){
    float bv = vals[0]; int bj = 0;
#pragma unroll
    for(int j=1;j<16;++j) if(vals[j] > bv){ bv = vals[j]; bj = j; }
    int bm = l + 64*bj;
#pragma unroll
    for(int d=1; d<64; d<<=1){
      float ov = __shfl_xor(bv, d);
      int   om = __shfl_xor(bm, d);
      if(ov > bv || (ov == bv && om < bm)){ bv = ov; bm = om; }
    }
#pragma unroll
    for(int j=0;j<16;++j) if(bm == l + 64*j) vals[j] = -INFINITY;
    if(l == 0) idx[r*K_ + p] = bm;
  }
}

// K10a: gather -> y[b][n][160] bf16. one wave/row
__global__ __launch_bounds__(256) void k_y(const float* __restrict__ xf, const int* __restrict__ idx,
                                           unsigned short* __restrict__ y){
  int t = threadIdx.x, wv = t >> 6, l = t & 63;
  long r = (long)blockIdx.x*4 + wv;
  long b = r >> 10;
  const float* frow = xf + r*G_;
  int o2s = (l < 16) ? (64 + l) : 0;
  float f0 = frow[l];
  float f1 = frow[o2s];
  const int* ixp = idx + r*K_;
  float m0 = -INFINITY, m1 = -INFINITY;
#pragma unroll
  for(int k=0;k<K_;++k){
    const float* nr = xf + ((long)b*N_ + ixp[k])*G_;
    m0 = fmaxf(m0, nr[l]);
    m1 = fmaxf(m1, nr[o2s]);
  }
  unsigned short* yr = y + r*G2_;
  ushort2 u0; u0.x = f2b(f0); u0.y = f2b(m0 - f0);
  *(ushort2*)&yr[2*l] = u0;
  if(l < 16){
    ushort2 u1; u1.x = f2b(f1); u1.y = f2b(m1 - f1);
    *(ushort2*)&yr[128 + 2*l] = u1;
  }
}

// K10b: MFMA mixer + bn2 + gelu + fc2 + bn3 + amap -> goutT
__global__ __launch_bounds__(256) void k_mixer_mfma(const unsigned short* __restrict__ y,
                                                    const unsigned short* __restrict__ w1bd,
                                                    const float* __restrict__ mrb,
                                                    const float* __restrict__ g2, const float* __restrict__ b2,
                                                    const unsigned short* __restrict__ fc2b16,
                                                    const float* __restrict__ fc2bias,
                                                    const float* __restrict__ g3, const float* __restrict__ b3,
                                                    const float* __restrict__ amapT, float* __restrict__ goutT){
  __shared__ unsigned short zl[4][16][G2_];
  int t = threadIdx.x, w = t >> 6, l = t & 63;
  long row0 = ((long)blockIdx.x*4 + w)*16;
  int lr = l & 15, lk = l >> 4;
  bf16x8 ay[5];
  const unsigned short* yrow = y + (row0 + lr)*G2_ + lk*8;
#pragma unroll
  for(int ks=0; ks<5; ++ks) ay[ks] = *(const bf16x8*)&yrow[ks*32];
  f32x4 accz[10] = {};
  const unsigned short* wb = w1bd + (long)lr*G2_ + lk*8;
#pragma unroll
  for(int ks=0; ks<5; ++ks){
#pragma unroll
    for(int ct=0; ct<10; ++ct){
      bf16x8 bw = *(const bf16x8*)&wb[ct*16*G2_ + ks*32];
      accz[ct] = __builtin_amdgcn_mfma_f32_16x16x32_bf16(ay[ks], bw, accz[ct], 0, 0, 0);
    }
  }
#pragma unroll
  for(int ct=0; ct<10; ++ct){
    int o = ct*16 + lr;
    float bi = mrb[o], ga = g2[o]*BNS_, bb = b2[o];
#pragma unroll
    for(int i=0;i<4;++i){
      float v = (accz[ct][i] + bi)*ga + bb;
      float zz = v * 0.5f * (1.0f + erff(v * INVSQRT2_));
      zl[w][lk*4 + i][o] = f2b(zz);
    }
  }
  __syncthreads();
  bf16x8 az[5];
#pragma unroll
  for(int ks=0; ks<5; ++ks) az[ks] = *(const bf16x8*)&zl[w][lr][ks*32 + lk*8];
  f32x4 acc2[5] = {};
  const unsigned short* fb = fc2b16 + (long)lr*G2_ + lk*8;
#pragma unroll
  for(int ks=0; ks<5; ++ks){
#pragma unroll
    for(int ct=0; ct<5; ++ct){
      bf16x8 bw = *(const bf16x8*)&fb[ct*16*G2_ + ks*32];
      acc2[ct] = __builtin_amdgcn_mfma_f32_16x16x32_bf16(az[ks], bw, acc2[ct], 0, 0, 0);
    }
  }
#pragma unroll
  for(int ct=0; ct<5; ++ct){
    int o = ct*16 + lr;
    float bi = fc2bias[o], ga = g3[o]*BNS_, bb = b3[o];
#pragma unroll
    for(int i=0;i<4;++i){
      long row = row0 + lk*4 + i;
      float v = (acc2[ct][i] + bi)*ga + bb + amapT[row*G_ + o];
      goutT[row*G_ + o] = v;
    }
  }
}

// K12 v2: per-thread softmax + MFMA PV -> bf16 aob[b][n][c]
__global__ __launch_bounds__(256) void k_softmax_pv(const float* __restrict__ goutT, const float* __restrict__ kv,
                                                    unsigned short* __restrict__ aob){
  int bh = blockIdx.x; int b = bh >> 2, h = bh & 3;
  int n0 = blockIdx.y * 64;
  __shared__ unsigned short Vt[128*32];   // [d][cls-pad32]
  __shared__ unsigned short Pl[64*40];    // [n][cls-pad32, stride 40]
  __shared__ unsigned short Os[64*132];   // [n][d, stride 132]
  int t = threadIdx.x, w = t >> 6, l = t & 63;
  if(t < 128){
    int d = t;
    const float* vb = kv + ((long)b*CLS_)*1024 + C_ + h*HD_ + d;
#pragma unroll
    for(int cls=0; cls<CLS_; ++cls) Vt[d*32+cls] = f2b(vb[(long)cls*1024]);
#pragma unroll
    for(int cls=CLS_; cls<32; ++cls) Vt[d*32+cls] = 0;
  }
  if(t < 64){
    int n = n0 + t;
    const float* gr = goutT + ((long)b*N_ + n)*G_ + h*CLS_;
    float x[CLS_];
    float mx = -INFINITY;
#pragma unroll
    for(int cls=0; cls<CLS_; ++cls){ x[cls] = gr[cls]; mx = fmaxf(mx, x[cls]); }
    float s = 0.f;
#pragma unroll
    for(int cls=0; cls<CLS_; ++cls){ x[cls] = expf(x[cls]-mx); s += x[cls]; }
    float inv = 1.0f / s;
#pragma unroll
    for(int cls=0; cls<CLS_; ++cls) Pl[t*40+cls] = f2b(x[cls]*inv);
#pragma unroll
    for(int cls=CLS_; cls<32; ++cls) Pl[t*40+cls] = 0;
  }
  __syncthreads();
  int lr = l & 15, kq = (l >> 4)*8;
  f32x4 acc[4][2] = {};
  bf16x8 af[4], bf2[2];
#pragma unroll
  for(int rt=0; rt<4; ++rt) af[rt] = *(const bf16x8*)&Pl[(rt*16+lr)*40 + kq];
#pragma unroll
  for(int ci=0; ci<2; ++ci) bf2[ci] = *(const bf16x8*)&Vt[((2*w+ci)*16+lr)*32 + kq];
#pragma unroll
  for(int rt=0; rt<4; ++rt)
#pragma unroll
    for(int ci=0; ci<2; ++ci)
      acc[rt][ci] = __builtin_amdgcn_mfma_f32_16x16x32_bf16(af[rt], bf2[ci], acc[rt][ci], 0, 0, 0);
  int r0 = (l >> 4)*4;
#pragma unroll
  for(int rt=0; rt<4; ++rt)
#pragma unroll
    for(int ci=0; ci<2; ++ci)
#pragma unroll
      for(int i=0; i<4; ++i)
        Os[(rt*16 + r0 + i)*132 + (2*w+ci)*16 + lr] = f2b(acc[rt][ci][i]);
  __syncthreads();
  unsigned short* ob = aob + ((long)b*N_ + n0)*C_ + h*HD_;
#pragma unroll
  for(int j=0; j<8; ++j){
    int idx = t + 256*j;            // 2048 chunks of 4 shorts -> full 64x128 tile
    int row = idx >> 5, ch = idx & 31;
    *(ushort4*)&ob[(long)row*C_ + ch*4] =
        *(const ushort4*)&Os[row*132 + ch*4];
  }
}

extern "C" void kernel_launch(void* const* d_in, const int* in_sizes, int n_in,
                              void* d_out, int out_size, void* d_ws, size_t ws_size,
                              hipStream_t stream){
  const float* x_cls   = (const float*)d_in[0];
  const float* x_patch = (const float*)d_in[1];
  const float* norm_x_w = (const float*)d_in[2];
  const float* norm_x_b = (const float*)d_in[3];
  const float* pq_w  = (const float*)d_in[4];
  const float* pq_b  = (const float*)d_in[5];
  const float* ncls_w = (const float*)d_in[6];
  const float* ncls_b = (const float*)d_in[7];
  const float* pkv_w = (const float*)d_in[8];
  const float* pkv_b = (const float*)d_in[9];
  const float* fc1_w = (const float*)d_in[10];
  const float* fc1_b = (const float*)d_in[11];
  const float* bn1_g = (const float*)d_in[12];
  const float* bn1_b = (const float*)d_in[13];
  const float* mr_w  = (const float*)d_in[14];
  const float* mr_b  = (const float*)d_in[15];
  const float* bn2_g = (const float*)d_in[16];
  const float* bn2_b = (const float*)d_in[17];
  const float* fc2_w = (const float*)d_in[18];
  const float* fc2_b = (const float*)d_in[19];
  const float* bn3_g = (const float*)d_in[20];
  const float* bn3_b = (const float*)d_in[21];
  const float* proj_w = (const float*)d_in[22];
  const float* proj_b = (const float*)d_in[23];

  float* ws = (float*)d_ws;
  float* part   = ws + OFF_PART;
  float* stats  = ws + OFF_STATS;
  float* ebb    = ws + OFF_EBB;
  float* kvbuf  = ws + OFF_KV;
  float* amapT  = ws + OFF_AMAPT;
  float* xf     = ws + OFF_XF;
  float* sqbuf  = ws + OFF_SQ;
  float* negd   = ws + OFF_NEGD;
  int*   idxbuf = (int*)(ws + OFF_IDX);
  float* goutT  = ws + OFF_GOUTT;
  unsigned short* Eb     = (unsigned short*)(ws + OFF_EB);
  unsigned short* xub    = (unsigned short*)(ws + OFF_XUB);
  unsigned short* w1bd   = (unsigned short*)(ws + OFF_W1BD);
  unsigned short* fc2b16 = (unsigned short*)(ws + OFF_FC2B);
  unsigned short* ybuf   = (unsigned short*)(ws + OFF_Y);
  unsigned short* xnb = (unsigned short*)(ws + OFF_NEGD);   // overlay: dead before negd written
  unsigned short* aob = (unsigned short*)(ws + OFF_NEGD);   // overlay: negd dead after topk
  unsigned short* wpb = (unsigned short*)(ws + OFF_WPB);
  float* out = (float*)d_out;

  k_stats_partial<<<1024, 256, 0, stream>>>(x_patch, part);
  k_stats_final<<<16, 64, 0, stream>>>(part, stats);
  k_xn_t<<<dim3(16,8,16), 256, 0, stream>>>(x_patch, stats, norm_x_w, norm_x_b, xnb);
  k_cls_kv<<<dim3(16,8), 256, 0, stream>>>(x_cls, ncls_w, ncls_b, pkv_w, pkv_b, kvbuf);
  k_eprep<<<dim3(16,5), 256, 0, stream>>>(kvbuf, pq_w, pq_b, Eb, ebb);
  k_wconv<<<256, 256, 0, stream>>>(proj_w, wpb);
  k_wsmall<<<240, 256, 0, stream>>>(mr_w, fc2_w, w1bd, fc2b16);
  k_amap_gemm<<<dim3(16,16), 256, 0, stream>>>(Eb, xnb, ebb, amapT);
  k_fc1<<<4096, 256, 0, stream>>>(amapT, fc1_w, fc1_b, bn1_g, bn1_b, xf, xub, sqbuf);
  k_negd_mfma<<<dim3(8,8,16), 256, 0, stream>>>(xub, sqbuf, negd);
  k_topk<<<4096, 256, 0, stream>>>(negd, idxbuf);
  k_y<<<4096, 256, 0, stream>>>(xf, idxbuf, ybuf);
  k_mixer_mfma<<<256, 256, 0, stream>>>(ybuf, w1bd, mr_b, bn2_g, bn2_b,
                                        fc2b16, fc2_b, bn3_g, bn3_b, amapT, goutT);
  k_softmax_pv<<<dim3(64,16), 256, 0, stream>>>(goutT, kvbuf, aob);
  k_gemm_mfma<true><<<dim3(8,4,16), 256, 0, stream>>>(wpb, aob, proj_b, x_patch, out);
}

// Round 6
// 222.524 us; speedup vs baseline: 2.6057x; 1.1170x over previous
//
#include <hip/hip_runtime.h>
#include <math.h>

#define DI __device__ __forceinline__

constexpr int B_ = 16, CLS_ = 20, C_ = 512, H_ = 4, HD_ = 128, N_ = 1024, G_ = 80, G2_ = 160, K_ = 9;
constexpr float EPS_ = 1e-5f;
constexpr float BNS_ = 0.9999950000374997f;     // 1/sqrt(1+1e-5)
constexpr float SCALE_ = 0.08838834764831845f;  // 128^-0.5
constexpr float INVSQRT2_ = 0.7071067811865475f;

typedef __attribute__((ext_vector_type(8))) short bf16x8;
typedef __attribute__((ext_vector_type(4))) float f32x4;

// ---- workspace layout (float slots) ----
constexpr long OFF_PART  = 0;                      // 2048
constexpr long OFF_STATS = 2048;                   // 32
constexpr long OFF_EB    = 4096;                   // E bf16 [16][128][512] = 524288 slots
constexpr long OFF_EBB   = OFF_EB    + 524288;     // 1280 fp32
constexpr long OFF_KV    = OFF_EBB   + 2048;       // 16*20*1024
constexpr long OFF_AMAPT = OFF_KV    + 327680;     // 16*1024*80
constexpr long OFF_XF    = OFF_AMAPT + 1310720;
constexpr long OFF_XUB   = OFF_XF    + 1310720;    // bf16 16*1024*96 = 786432 slots
constexpr long OFF_W1BD  = OFF_XUB   + 786432;     // 16384
constexpr long OFF_FC2B  = OFF_W1BD  + 16384;      // 8192
constexpr long OFF_SQ    = OFF_FC2B  + 8192;       // 16384
constexpr long OFF_NEGD  = OFF_SQ    + 16384;      // 16*1024*1024 fp32; overlays xnb (early) / aob (late)
constexpr long OFF_IDX   = OFF_NEGD  + 16777216;   // 147456 ints
constexpr long OFF_GOUTT = OFF_IDX   + 147456;     // 1310720
constexpr long OFF_WPB   = OFF_GOUTT + 1310720;    // 131072 (proj_w bf16)
constexpr long OFF_Y     = OFF_WPB   + 131072;     // 1310720

DI float wsum(float v){
#pragma unroll
  for(int d=1; d<64; d<<=1) v += __shfl_xor(v, d);
  return v;
}
DI unsigned short f2b(float f){
  unsigned u = __float_as_uint(f);
  unsigned r = (u + 0x7FFFu + ((u >> 16) & 1u)) >> 16;
  return (unsigned short)r;
}

#define GLOAD16(g, s) __builtin_amdgcn_global_load_lds((const __attribute__((address_space(1))) void*)(g), \
                        (__attribute__((address_space(3))) void*)(s), 16, 0, 0)

// K1a: per-segment partial sums of x_patch
__global__ __launch_bounds__(256) void k_stats_partial(const float* __restrict__ x, float* __restrict__ part){
  int blk = blockIdx.x;                 // b*64+seg
  const float4* xp = (const float4*)x;
  long base4 = (long)blk * 2048;
  int t = threadIdx.x;
  float s = 0.f, ss = 0.f;
#pragma unroll
  for(int j=0;j<8;++j){
    float4 v = xp[base4 + t + 256*j];
    s  += v.x + v.y + v.z + v.w;
    ss += v.x*v.x + v.y*v.y + v.z*v.z + v.w*v.w;
  }
  s = wsum(s); ss = wsum(ss);
  __shared__ float rs[4], rss[4];
  int wv = t >> 6;
  if((t & 63) == 0){ rs[wv] = s; rss[wv] = ss; }
  __syncthreads();
  if(t == 0){
    part[blk*2]   = rs[0]+rs[1]+rs[2]+rs[3];
    part[blk*2+1] = rss[0]+rss[1]+rss[2]+rss[3];
  }
}

__global__ __launch_bounds__(64) void k_stats_final(const float* __restrict__ part, float* __restrict__ stats){
  int b = blockIdx.x, t = threadIdx.x;
  float s  = part[(b*64+t)*2];
  float ss = part[(b*64+t)*2+1];
  s = wsum(s); ss = wsum(ss);
  if(t == 0){
    const float cnt = (float)(C_ * N_);
    float m = s / cnt;
    float var = ss / cnt - m*m;
    stats[b*2]   = m;
    stats[b*2+1] = 1.0f / sqrtf(var + EPS_);
  }
}

// K2: norm + transpose + bf16: xnb[b][n][c]
__global__ __launch_bounds__(256) void k_xn_t(const float* __restrict__ x, const float* __restrict__ stats,
                                              const float* __restrict__ nw, const float* __restrict__ nb,
                                              unsigned short* __restrict__ xnb){
  __shared__ float tile[64][65];
  int b = blockIdx.z, c0 = blockIdx.y*64, n0 = blockIdx.x*64;
  float m = stats[b*2], inv = stats[b*2+1];
  int t = threadIdx.x;
  const float* xb = x + ((long)b*C_ + c0)*N_ + n0;
#pragma unroll
  for(int j=0;j<4;++j){
    int idx = t + 256*j;
    int r = idx >> 4, c4 = (idx & 15)*4;
    float a = inv * nw[c0+r];
    float bb = nb[c0+r] - m*a;
    float4 v = *(const float4*)&xb[(long)r*N_ + c4];
    tile[r][c4]   = v.x*a + bb;
    tile[r][c4+1] = v.y*a + bb;
    tile[r][c4+2] = v.z*a + bb;
    tile[r][c4+3] = v.w*a + bb;
  }
  __syncthreads();
  unsigned short* ob = xnb + ((long)b*N_ + n0)*C_ + c0;
#pragma unroll
  for(int j=0;j<8;++j){
    int idx = t + 256*j;
    int n = idx >> 5, cc = (idx & 31)*2;
    ushort2 u;
    u.x = f2b(tile[cc][n]);
    u.y = f2b(tile[cc+1][n]);
    *(ushort2*)&ob[(long)n*C_ + cc] = u;
  }
}

// proj weight fp32 -> bf16
__global__ __launch_bounds__(256) void k_wconv(const float* __restrict__ a, unsigned short* __restrict__ oa){
  long i = (long)blockIdx.x*256 + threadIdx.x;
  float4 v = ((const float4*)a)[i];
  uint2 o;
  o.x = (unsigned)f2b(v.x) | ((unsigned)f2b(v.y) << 16);
  o.y = (unsigned)f2b(v.z) | ((unsigned)f2b(v.w) << 16);
  ((uint2*)oa)[i] = o;
}

// small-weight prep: block-diag mixer weight (160x160) + fc2 (80x160) in bf16
__global__ __launch_bounds__(256) void k_wsmall(const float* __restrict__ mrw, const float* __restrict__ fc2w,
                                                unsigned short* __restrict__ w1bd, unsigned short* __restrict__ fc2b16){
  int row = blockIdx.x, t = threadIdx.x;
  if(t >= 160) return;
  if(row < 160){
    unsigned short v = 0;
    if(t/40 == row/40) v = f2b(mrw[row*40 + (t % 40)]);
    w1bd[row*160 + t] = v;
  } else {
    fc2b16[(row-160)*160 + t] = f2b(fc2w[(long)(row-160)*160 + t]);
  }
}

// E prep v2: grid (B, 5, 8). blockIdx.y==h (0..3): E[b][h*20+cls][c0..c0+64) ; ==4: zero-pad rows 80..127
__global__ __launch_bounds__(256) void k_eprep(const float* __restrict__ kv, const float* __restrict__ pqw,
                                               const float* __restrict__ pqb,
                                               unsigned short* __restrict__ Eb, float* __restrict__ ebb){
  int b = blockIdx.x, hh = blockIdx.y, cch = blockIdx.z, t = threadIdx.x;
  if(hh == 4){
    if(cch == 0){
      unsigned* z = (unsigned*)(Eb + ((long)b*128 + 80)*512);
      for(int i=t; i<12288; i+=256) z[i] = 0;
    }
    return;
  }
  int h = hh, c0 = cch*64;
  __shared__ float key[CLS_][HD_];      // 10 KB
  __shared__ float part[4][CLS_][64];   // 20 KB
  for(int i=t; i<CLS_*HD_; i+=256){
    int cls = i >> 7, d = i & 127;
    key[cls][d] = kv[((long)b*CLS_+cls)*1024 + h*HD_ + d];
  }
  __syncthreads();
  int c = t & 63, ds = t >> 6;          // ds in [0,4): d-range [ds*32, ds*32+32)
  float acc[CLS_] = {};
  const float* wp = pqw + ((long)(h*HD_ + ds*32))*C_ + c0 + c;
#pragma unroll 8
  for(int di=0; di<32; ++di){
    float wv = wp[(long)di*C_];
#pragma unroll
    for(int cls=0; cls<CLS_; ++cls) acc[cls] += key[cls][ds*32+di]*wv;
  }
#pragma unroll
  for(int cls=0; cls<CLS_; ++cls) part[ds][cls][c] = acc[cls];
  __syncthreads();
  for(int i=t; i<CLS_*64; i+=256){
    int cls = i >> 6, cc = i & 63;
    float v = part[0][cls][cc]+part[1][cls][cc]+part[2][cls][cc]+part[3][cls][cc];
    Eb[((long)b*128 + h*CLS_ + cls)*512 + c0 + cc] = f2b(v*SCALE_);
  }
  if(cch == 0 && t < CLS_){
    float bacc = 0.f;
    for(int d=0; d<HD_; ++d) bacc += key[t][d]*pqb[h*HD_+d];
    ebb[b*G_ + h*CLS_ + t] = bacc*SCALE_;
  }
}

// amap GEMM: amapT[b][n][g] = sum_c E[b][g][c]*xnb[b][n][c] + ebb[b][g]
__global__ __launch_bounds__(256) void k_amap_gemm(const unsigned short* __restrict__ Eb,
                                                   const unsigned short* __restrict__ Xb,
                                                   const float* __restrict__ ebb,
                                                   float* __restrict__ amapT){
  __shared__ unsigned short Anl[2048];   // 64 n rows x 32 k
  __shared__ unsigned short Bgl[4096];   // 128 g rows x 32 k
  int b = blockIdx.y, n0 = blockIdx.x*64;
  int t = threadIdx.x, w = t >> 6, l = t & 63;
  int wr = w >> 1, wc = w & 1;
  f32x4 acc[2][4] = {};
  const unsigned short* At = Xb + ((long)b*N_ + n0 + w*16 + (l>>2))*512 + (l&3)*8;
  const unsigned short* Bt = Eb + ((long)b*128 + w*16 + (l>>2))*512 + (l&3)*8;
  int ra = wr*32 + (l & 15);
  int rb = wc*64 + (l & 15);
  int kq = (l >> 4) * 8;
  for(int k0 = 0; k0 < 512; k0 += 32){
    if(k0) __syncthreads();
    GLOAD16(At + k0,          &Anl[w*512]);
    GLOAD16(Bt + k0,          &Bgl[w*512]);
    GLOAD16(Bt + 64*512 + k0, &Bgl[2048 + w*512]);
    __syncthreads();
    bf16x8 af[2], bfr[4];
#pragma unroll
    for(int rt=0; rt<2; ++rt) af[rt]  = *(const bf16x8*)&Anl[(ra + rt*16)*32 + kq];
#pragma unroll
    for(int ct=0; ct<4; ++ct) bfr[ct] = *(const bf16x8*)&Bgl[(rb + ct*16)*32 + kq];
#pragma unroll
    for(int rt=0; rt<2; ++rt)
#pragma unroll
      for(int ct=0; ct<4; ++ct)
        acc[rt][ct] = __builtin_amdgcn_mfma_f32_16x16x32_bf16(af[rt], bfr[ct], acc[rt][ct], 0, 0, 0);
  }
  int r0 = (l >> 4)*4;
#pragma unroll
  for(int rt=0; rt<2; ++rt){
#pragma unroll
    for(int r=0; r<4; ++r){
      int n = n0 + wr*32 + rt*16 + r0 + r;
      long rowb = ((long)b*N_ + n)*G_;
#pragma unroll
      for(int ct=0; ct<4; ++ct){
        int g = wc*64 + ct*16 + (l & 15);
        if(g < G_) amapT[rowb + g] = acc[rt][ct][r] + ebb[b*G_ + g];
      }
    }
  }
}

// MFMA GEMM: Out[b][o][n] = sum_c Wb[o][c]*Xb[b][n][c] + bias[o] (+Res)
template<bool RES>
__global__ __launch_bounds__(256) void k_gemm_mfma(const unsigned short* __restrict__ Wb,
                                                   const unsigned short* __restrict__ Xb,
                                                   const float* __restrict__ bias,
                                                   const float* __restrict__ Res,
                                                   float* __restrict__ Out){
  __shared__ unsigned short Al[4096];   // [128 rows(o)][32 k]
  __shared__ unsigned short Bl[4096];   // [128 rows(n)][32 k]
  int b = blockIdx.z;
  int o0 = blockIdx.y*128, n0 = blockIdx.x*128;
  int t = threadIdx.x, w = t >> 6, l = t & 63;
  int wr = w >> 1, wc = w & 1;
  f32x4 acc[4][4] = {};
  const unsigned short* Wt = Wb + (long)(o0 + w*16 + (l>>2))*512 + (l&3)*8;
  const unsigned short* Xt = Xb + ((long)b*N_ + n0 + w*16 + (l>>2))*512 + (l&3)*8;
  int ra = wr*64 + (l & 15);
  int rb = wc*64 + (l & 15);
  int kq = (l >> 4) * 8;
  for(int k0 = 0; k0 < 512; k0 += 32){
    if(k0) __syncthreads();
    GLOAD16(Wt + k0,            &Al[w*512]);
    GLOAD16(Wt + 64*512 + k0,   &Al[2048 + w*512]);
    GLOAD16(Xt + k0,            &Bl[w*512]);
    GLOAD16(Xt + 64*512 + k0,   &Bl[2048 + w*512]);
    __syncthreads();
    bf16x8 af[4], bfr[4];
#pragma unroll
    for(int i=0;i<4;++i){
      af[i]  = *(const bf16x8*)&Al[(ra + i*16)*32 + kq];
      bfr[i] = *(const bf16x8*)&Bl[(rb + i*16)*32 + kq];
    }
#pragma unroll
    for(int mi=0; mi<4; ++mi)
#pragma unroll
      for(int ni=0; ni<4; ++ni)
        acc[mi][ni] = __builtin_amdgcn_mfma_f32_16x16x32_bf16(af[mi], bfr[ni], acc[mi][ni], 0, 0, 0);
  }
  long obase = ((long)b*C_ + o0 + wr*64)*N_ + n0 + wc*64 + (l & 15);
  int r0 = (l >> 4) * 4;
#pragma unroll
  for(int mi=0; mi<4; ++mi){
#pragma unroll
    for(int r=0; r<4; ++r){
      int row = mi*16 + r0 + r;
      float bi = bias[o0 + wr*64 + row];
#pragma unroll
      for(int ni=0; ni<4; ++ni){
        long oi = obase + (long)row*N_ + ni*16;
        float v = acc[mi][ni][r] + bi;
        if(RES) v += Res[oi];
        Out[oi] = v;
      }
    }
  }
}

// K4: cls layernorm + kv projection
__global__ __launch_bounds__(256) void k_cls_kv(const float* __restrict__ xcls,
                                                const float* __restrict__ ncw, const float* __restrict__ ncb,
                                                const float* __restrict__ pkvw, const float* __restrict__ pkvb,
                                                float* __restrict__ kv){
  int b = blockIdx.x;
  int ochunk = blockIdx.y;
  __shared__ float xc[CLS_][C_];
  int t = threadIdx.x, wv = t >> 6, l = t & 63;
  for(int cls = wv; cls < CLS_; cls += 4){
    const float* xr = xcls + ((long)b*CLS_ + cls) * C_;
    float vals[8];
    float s = 0.f, ss = 0.f;
#pragma unroll
    for(int j=0;j<8;++j){ float v = xr[l + 64*j]; vals[j] = v; s += v; ss += v*v; }
    s = wsum(s); ss = wsum(ss);
    float m = s / (float)C_;
    float var = ss / (float)C_ - m*m;
    float inv = 1.0f / sqrtf(var + EPS_);
#pragma unroll
    for(int j=0;j<8;++j){
      int c = l + 64*j;
      xc[cls][c] = (vals[j]-m)*inv*ncw[c] + ncb[c];
    }
  }
  __syncthreads();
  int o = ochunk*128 + (t & 127);
  int cls0 = (t >> 7) * 10;
  float acc[10] = {};
  const float* wrow = pkvw + (long)o * C_;
  for(int k4 = 0; k4 < C_; k4 += 4){
    float4 w4 = *(const float4*)&wrow[k4];
#pragma unroll
    for(int i=0;i<10;++i){
      acc[i] += w4.x*xc[cls0+i][k4] + w4.y*xc[cls0+i][k4+1] + w4.z*xc[cls0+i][k4+2] + w4.w*xc[cls0+i][k4+3];
    }
  }
  float bo = pkvb[o];
#pragma unroll
  for(int i=0;i<10;++i) kv[((long)b*CLS_ + cls0+i)*1024 + o] = acc[i] + bo;
}

// K6: fc1+bn1 -> xf ; normalize -> xub(bf16, K-padded 96), sq. one wave per row
__global__ __launch_bounds__(256) void k_fc1(const float* __restrict__ amapT, const float* __restrict__ w,
                                             const float* __restrict__ bias, const float* __restrict__ g1,
                                             const float* __restrict__ b1,
                                             float* __restrict__ xf, unsigned short* __restrict__ xub,
                                             float* __restrict__ sq){
  int t = threadIdx.x, wv = t >> 6, l = t & 63;
  long r = (long)blockIdx.x*4 + wv;
  __shared__ float arow[4][G_];
  const float* ap = amapT + r*G_;
  arow[wv][l] = ap[l];
  if(l < 16) arow[wv][64+l] = ap[64+l];
  __syncthreads();
  int o2 = (l < 16) ? (64 + l) : 0;
  const float* w0 = w + (long)l*G_;
  const float* w1 = w + (long)o2*G_;
  float acc0 = 0.f, acc1 = 0.f;
#pragma unroll 8
  for(int g=0; g<G_; ++g){
    float a = arow[wv][g];
    acc0 += w0[g]*a;
    acc1 += w1[g]*a;
  }
  float v0 = (acc0 + bias[l])  * (g1[l]*BNS_)  + b1[l];
  float v1 = (acc1 + bias[o2]) * (g1[o2]*BNS_) + b1[o2];
  xf[r*G_ + l] = v0;
  if(l < 16) xf[r*G_ + 64 + l] = v1;
  float ssq = v0*v0 + ((l<16) ? v1*v1 : 0.f);
  ssq = wsum(ssq);
  float nrm = sqrtf(ssq);
  float invn = 1.0f / fmaxf(nrm, 1e-12f);
  float u0 = v0*invn, u1 = v1*invn;
  float s2 = u0*u0 + ((l<16) ? u1*u1 : 0.f);
  s2 = wsum(s2);
  xub[r*96 + l] = f2b(u0);
  if(l < 16) xub[r*96 + 64 + l] = f2b(u1);
  else if(l < 32) xub[r*96 + 64 + l] = 0;    // zero K-pad cols 80..95
  if(l == 0) sq[r] = s2;
}

// K8: neg_d via bf16 MFMA: 128x128 tile, K=96 (padded)
__global__ __launch_bounds__(256) void k_negd_mfma(const unsigned short* __restrict__ xub,
                                                   const float* __restrict__ sq,
                                                   float* __restrict__ negd){
  __shared__ unsigned short Al[128*96];
  __shared__ unsigned short Bl[128*96];
  int b = blockIdx.z;
  int n0 = blockIdx.y*128, m0 = blockIdx.x*128;
  int t = threadIdx.x, w = t >> 6, l = t & 63;
  int wr = w >> 1, wc = w & 1;
  const unsigned short* gA = xub + ((long)b*N_ + n0)*96;
  const unsigned short* gB = xub + ((long)b*N_ + m0)*96;
#pragma unroll
  for(int rd=0; rd<6; ++rd){
    int chunk = rd*4 + w;
    GLOAD16(gA + chunk*512 + l*8, &Al[chunk*512]);
    GLOAD16(gB + chunk*512 + l*8, &Bl[chunk*512]);
  }
  __syncthreads();
  f32x4 acc[4][4] = {};
  int ra = wr*64 + (l & 15);
  int rb = wc*64 + (l & 15);
#pragma unroll
  for(int ks=0; ks<3; ++ks){
    int kq = ks*32 + (l >> 4)*8;
    bf16x8 af[4], bfr[4];
#pragma unroll
    for(int i=0;i<4;++i){
      af[i]  = *(const bf16x8*)&Al[(ra + i*16)*96 + kq];
      bfr[i] = *(const bf16x8*)&Bl[(rb + i*16)*96 + kq];
    }
#pragma unroll
    for(int mi=0; mi<4; ++mi)
#pragma unroll
      for(int ni=0; ni<4; ++ni)
        acc[mi][ni] = __builtin_amdgcn_mfma_f32_16x16x32_bf16(af[mi], bfr[ni], acc[mi][ni], 0, 0, 0);
  }
  int r0 = (l >> 4)*4;
  const float* sqb = sq + (long)b*N_;
#pragma unroll
  for(int mi=0; mi<4; ++mi){
#pragma unroll
    for(int r=0; r<4; ++r){
      int n = n0 + wr*64 + mi*16 + r0 + r;
      float sn = sqb[n];
      long row = ((long)b*N_ + n)*N_;
#pragma unroll
      for(int ni=0; ni<4; ++ni){
        int m = m0 + wc*64 + ni*16 + (l & 15);
        negd[row + m] = 2.f*acc[mi][ni][r] - sn - sqb[m];
      }
    }
  }
}

// K9: top-9 per row
__global__ __launch_bounds__(256) void k_topk(const float* __restrict__ negd, int* __restrict__ idx){
  int t = threadIdx.x, wv = t >> 6, l = t & 63;
  long r = (long)blockIdx.x*4 + wv;
  const float* row = negd + r*N_;
  float vals[16];
#pragma unroll
  for(int j=0;j<16;++j) vals[j] = row[l + 64*j];
#pragma unroll
  for(int p=0; p<K_; ++p){
    float bv = vals[0]; int bj = 0;
#pragma unroll
    for(int j=1;j<16;++j) if(vals[j] > bv){ bv = vals[j]; bj = j; }
    int bm = l + 64*bj;
#pragma unroll
    for(int d=1; d<64; d<<=1){
      float ov = __shfl_xor(bv, d);
      int   om = __shfl_xor(bm, d);
      if(ov > bv || (ov == bv && om < bm)){ bv = ov; bm = om; }
    }
#pragma unroll
    for(int j=0;j<16;++j) if(bm == l + 64*j) vals[j] = -INFINITY;
    if(l == 0) idx[r*K_ + p] = bm;
  }
}

// K10a: gather -> y[b][n][160] bf16. one wave/row
__global__ __launch_bounds__(256) void k_y(const float* __restrict__ xf, const int* __restrict__ idx,
                                           unsigned short* __restrict__ y){
  int t = threadIdx.x, wv = t >> 6, l = t & 63;
  long r = (long)blockIdx.x*4 + wv;
  long b = r >> 10;
  const float* frow = xf + r*G_;
  int o2s = (l < 16) ? (64 + l) : 0;
  float f0 = frow[l];
  float f1 = frow[o2s];
  const int* ixp = idx + r*K_;
  float m0 = -INFINITY, m1 = -INFINITY;
#pragma unroll
  for(int k=0;k<K_;++k){
    const float* nr = xf + ((long)b*N_ + ixp[k])*G_;
    m0 = fmaxf(m0, nr[l]);
    m1 = fmaxf(m1, nr[o2s]);
  }
  unsigned short* yr = y + r*G2_;
  ushort2 u0; u0.x = f2b(f0); u0.y = f2b(m0 - f0);
  *(ushort2*)&yr[2*l] = u0;
  if(l < 16){
    ushort2 u1; u1.x = f2b(f1); u1.y = f2b(m1 - f1);
    *(ushort2*)&yr[128 + 2*l] = u1;
  }
}

// K10b: MFMA mixer + bn2 + gelu + fc2 + bn3 + amap -> goutT
__global__ __launch_bounds__(256) void k_mixer_mfma(const unsigned short* __restrict__ y,
                                                    const unsigned short* __restrict__ w1bd,
                                                    const float* __restrict__ mrb,
                                                    const float* __restrict__ g2, const float* __restrict__ b2,
                                                    const unsigned short* __restrict__ fc2b16,
                                                    const float* __restrict__ fc2bias,
                                                    const float* __restrict__ g3, const float* __restrict__ b3,
                                                    const float* __restrict__ amapT, float* __restrict__ goutT){
  __shared__ unsigned short zl[4][16][G2_];
  int t = threadIdx.x, w = t >> 6, l = t & 63;
  long row0 = ((long)blockIdx.x*4 + w)*16;
  int lr = l & 15, lk = l >> 4;
  bf16x8 ay[5];
  const unsigned short* yrow = y + (row0 + lr)*G2_ + lk*8;
#pragma unroll
  for(int ks=0; ks<5; ++ks) ay[ks] = *(const bf16x8*)&yrow[ks*32];
  f32x4 accz[10] = {};
  const unsigned short* wb = w1bd + (long)lr*G2_ + lk*8;
#pragma unroll
  for(int ks=0; ks<5; ++ks){
#pragma unroll
    for(int ct=0; ct<10; ++ct){
      bf16x8 bw = *(const bf16x8*)&wb[ct*16*G2_ + ks*32];
      accz[ct] = __builtin_amdgcn_mfma_f32_16x16x32_bf16(ay[ks], bw, accz[ct], 0, 0, 0);
    }
  }
#pragma unroll
  for(int ct=0; ct<10; ++ct){
    int o = ct*16 + lr;
    float bi = mrb[o], ga = g2[o]*BNS_, bb = b2[o];
#pragma unroll
    for(int i=0;i<4;++i){
      float v = (accz[ct][i] + bi)*ga + bb;
      float zz = v * 0.5f * (1.0f + erff(v * INVSQRT2_));
      zl[w][lk*4 + i][o] = f2b(zz);
    }
  }
  __syncthreads();
  bf16x8 az[5];
#pragma unroll
  for(int ks=0; ks<5; ++ks) az[ks] = *(const bf16x8*)&zl[w][lr][ks*32 + lk*8];
  f32x4 acc2[5] = {};
  const unsigned short* fb = fc2b16 + (long)lr*G2_ + lk*8;
#pragma unroll
  for(int ks=0; ks<5; ++ks){
#pragma unroll
    for(int ct=0; ct<5; ++ct){
      bf16x8 bw = *(const bf16x8*)&fb[ct*16*G2_ + ks*32];
      acc2[ct] = __builtin_amdgcn_mfma_f32_16x16x32_bf16(az[ks], bw, acc2[ct], 0, 0, 0);
    }
  }
#pragma unroll
  for(int ct=0; ct<5; ++ct){
    int o = ct*16 + lr;
    float bi = fc2bias[o], ga = g3[o]*BNS_, bb = b3[o];
#pragma unroll
    for(int i=0;i<4;++i){
      long row = row0 + lk*4 + i;
      float v = (acc2[ct][i] + bi)*ga + bb + amapT[row*G_ + o];
      goutT[row*G_ + o] = v;
    }
  }
}

// K12 v2: per-thread softmax + MFMA PV -> bf16 aob[b][n][c]
__global__ __launch_bounds__(256) void k_softmax_pv(const float* __restrict__ goutT, const float* __restrict__ kv,
                                                    unsigned short* __restrict__ aob){
  int bh = blockIdx.x; int b = bh >> 2, h = bh & 3;
  int n0 = blockIdx.y * 64;
  __shared__ unsigned short Vt[128*32];   // [d][cls-pad32]
  __shared__ unsigned short Pl[64*40];    // [n][cls-pad32, stride 40]
  __shared__ unsigned short Os[64*132];   // [n][d, stride 132]
  int t = threadIdx.x, w = t >> 6, l = t & 63;
  if(t < 128){
    int d = t;
    const float* vb = kv + ((long)b*CLS_)*1024 + C_ + h*HD_ + d;
#pragma unroll
    for(int cls=0; cls<CLS_; ++cls) Vt[d*32+cls] = f2b(vb[(long)cls*1024]);
#pragma unroll
    for(int cls=CLS_; cls<32; ++cls) Vt[d*32+cls] = 0;
  }
  if(t < 64){
    int n = n0 + t;
    const float* gr = goutT + ((long)b*N_ + n)*G_ + h*CLS_;
    float x[CLS_];
    float mx = -INFINITY;
#pragma unroll
    for(int cls=0; cls<CLS_; ++cls){ x[cls] = gr[cls]; mx = fmaxf(mx, x[cls]); }
    float s = 0.f;
#pragma unroll
    for(int cls=0; cls<CLS_; ++cls){ x[cls] = expf(x[cls]-mx); s += x[cls]; }
    float inv = 1.0f / s;
#pragma unroll
    for(int cls=0; cls<CLS_; ++cls) Pl[t*40+cls] = f2b(x[cls]*inv);
#pragma unroll
    for(int cls=CLS_; cls<32; ++cls) Pl[t*40+cls] = 0;
  }
  __syncthreads();
  int lr = l & 15, kq = (l >> 4)*8;
  f32x4 acc[4][2] = {};
  bf16x8 af[4], bf2[2];
#pragma unroll
  for(int rt=0; rt<4; ++rt) af[rt] = *(const bf16x8*)&Pl[(rt*16+lr)*40 + kq];
#pragma unroll
  for(int ci=0; ci<2; ++ci) bf2[ci] = *(const bf16x8*)&Vt[((2*w+ci)*16+lr)*32 + kq];
#pragma unroll
  for(int rt=0; rt<4; ++rt)
#pragma unroll
    for(int ci=0; ci<2; ++ci)
      acc[rt][ci] = __builtin_amdgcn_mfma_f32_16x16x32_bf16(af[rt], bf2[ci], acc[rt][ci], 0, 0, 0);
  int r0 = (l >> 4)*4;
#pragma unroll
  for(int rt=0; rt<4; ++rt)
#pragma unroll
    for(int ci=0; ci<2; ++ci)
#pragma unroll
      for(int i=0; i<4; ++i)
        Os[(rt*16 + r0 + i)*132 + (2*w+ci)*16 + lr] = f2b(acc[rt][ci][i]);
  __syncthreads();
  unsigned short* ob = aob + ((long)b*N_ + n0)*C_ + h*HD_;
#pragma unroll
  for(int j=0; j<8; ++j){
    int idx = t + 256*j;            // 2048 chunks of 4 shorts -> full 64x128 tile
    int row = idx >> 5, ch = idx & 31;
    *(ushort4*)&ob[(long)row*C_ + ch*4] =
        *(const ushort4*)&Os[row*132 + ch*4];
  }
}

extern "C" void kernel_launch(void* const* d_in, const int* in_sizes, int n_in,
                              void* d_out, int out_size, void* d_ws, size_t ws_size,
                              hipStream_t stream){
  const float* x_cls   = (const float*)d_in[0];
  const float* x_patch = (const float*)d_in[1];
  const float* norm_x_w = (const float*)d_in[2];
  const float* norm_x_b = (const float*)d_in[3];
  const float* pq_w  = (const float*)d_in[4];
  const float* pq_b  = (const float*)d_in[5];
  const float* ncls_w = (const float*)d_in[6];
  const float* ncls_b = (const float*)d_in[7];
  const float* pkv_w = (const float*)d_in[8];
  const float* pkv_b = (const float*)d_in[9];
  const float* fc1_w = (const float*)d_in[10];
  const float* fc1_b = (const float*)d_in[11];
  const float* bn1_g = (const float*)d_in[12];
  const float* bn1_b = (const float*)d_in[13];
  const float* mr_w  = (const float*)d_in[14];
  const float* mr_b  = (const float*)d_in[15];
  const float* bn2_g = (const float*)d_in[16];
  const float* bn2_b = (const float*)d_in[17];
  const float* fc2_w = (const float*)d_in[18];
  const float* fc2_b = (const float*)d_in[19];
  const float* bn3_g = (const float*)d_in[20];
  const float* bn3_b = (const float*)d_in[21];
  const float* proj_w = (const float*)d_in[22];
  const float* proj_b = (const float*)d_in[23];

  float* ws = (float*)d_ws;
  float* part   = ws + OFF_PART;
  float* stats  = ws + OFF_STATS;
  float* ebb    = ws + OFF_EBB;
  float* kvbuf  = ws + OFF_KV;
  float* amapT  = ws + OFF_AMAPT;
  float* xf     = ws + OFF_XF;
  float* sqbuf  = ws + OFF_SQ;
  float* negd   = ws + OFF_NEGD;
  int*   idxbuf = (int*)(ws + OFF_IDX);
  float* goutT  = ws + OFF_GOUTT;
  unsigned short* Eb     = (unsigned short*)(ws + OFF_EB);
  unsigned short* xub    = (unsigned short*)(ws + OFF_XUB);
  unsigned short* w1bd   = (unsigned short*)(ws + OFF_W1BD);
  unsigned short* fc2b16 = (unsigned short*)(ws + OFF_FC2B);
  unsigned short* ybuf   = (unsigned short*)(ws + OFF_Y);
  unsigned short* xnb = (unsigned short*)(ws + OFF_NEGD);   // overlay: dead before negd written
  unsigned short* aob = (unsigned short*)(ws + OFF_NEGD);   // overlay: negd dead after topk
  unsigned short* wpb = (unsigned short*)(ws + OFF_WPB);
  float* out = (float*)d_out;

  k_stats_partial<<<1024, 256, 0, stream>>>(x_patch, part);
  k_stats_final<<<16, 64, 0, stream>>>(part, stats);
  k_xn_t<<<dim3(16,8,16), 256, 0, stream>>>(x_patch, stats, norm_x_w, norm_x_b, xnb);
  k_cls_kv<<<dim3(16,8), 256, 0, stream>>>(x_cls, ncls_w, ncls_b, pkv_w, pkv_b, kvbuf);
  k_eprep<<<dim3(16,5,8), 256, 0, stream>>>(kvbuf, pq_w, pq_b, Eb, ebb);
  k_wconv<<<256, 256, 0, stream>>>(proj_w, wpb);
  k_wsmall<<<240, 256, 0, stream>>>(mr_w, fc2_w, w1bd, fc2b16);
  k_amap_gemm<<<dim3(16,16), 256, 0, stream>>>(Eb, xnb, ebb, amapT);
  k_fc1<<<4096, 256, 0, stream>>>(amapT, fc1_w, fc1_b, bn1_g, bn1_b, xf, xub, sqbuf);
  k_negd_mfma<<<dim3(8,8,16), 256, 0, stream>>>(xub, sqbuf, negd);
  k_topk<<<4096, 256, 0, stream>>>(negd, idxbuf);
  k_y<<<4096, 256, 0, stream>>>(xf, idxbuf, ybuf);
  k_mixer_mfma<<<256, 256, 0, stream>>>(ybuf, w1bd, mr_b, bn2_g, bn2_b,
                                        fc2b16, fc2_b, bn3_g, bn3_b, amapT, goutT);
  k_softmax_pv<<<dim3(64,16), 256, 0, stream>>>(goutT, kvbuf, aob);
  k_gemm_mfma<true><<<dim3(8,4,16), 256, 0, stream>>>(wpb, aob, proj_b, x_patch, out);
}

// Round 7
// 194.714 us; speedup vs baseline: 2.9778x; 1.1428x over previous
//
#include <hip/hip_runtime.h>
#include <math.h>

#define DI __device__ __forceinline__

constexpr int B_ = 16, CLS_ = 20, C_ = 512, H_ = 4, HD_ = 128, N_ = 1024, G_ = 80, G2_ = 160, K_ = 9;
constexpr float EPS_ = 1e-5f;
constexpr float BNS_ = 0.9999950000374997f;     // 1/sqrt(1+1e-5)
constexpr float SCALE_ = 0.08838834764831845f;  // 128^-0.5
constexpr float INVSQRT2_ = 0.7071067811865475f;

typedef __attribute__((ext_vector_type(8))) short bf16x8;
typedef __attribute__((ext_vector_type(4))) float f32x4;

// ---- workspace layout (float slots) ----
constexpr long OFF_PART  = 0;                      // 2048
constexpr long OFF_STATS = 2048;                   // 32
constexpr long OFF_EB    = 4096;                   // E bf16 [16][128][512] = 524288 slots
constexpr long OFF_EBB   = OFF_EB    + 524288;     // 1280 fp32
constexpr long OFF_KV    = OFF_EBB   + 2048;       // 16*20*1024
constexpr long OFF_AMAPT = OFF_KV    + 327680;     // 16*1024*80 fp32
constexpr long OFF_XF    = OFF_AMAPT + 1310720;
constexpr long OFF_XUB   = OFF_XF    + 1310720;    // bf16 16*1024*96 = 786432 slots
constexpr long OFF_W1BD  = OFF_XUB   + 786432;     // 16384
constexpr long OFF_FC2B  = OFF_W1BD  + 16384;      // 8192
constexpr long OFF_SQ    = OFF_FC2B  + 8192;       // 16384
constexpr long OFF_NEGD  = OFF_SQ    + 16384;      // 16*1024*1024 fp32; overlays xnb (early) / aob (late)
constexpr long OFF_IDX   = OFF_NEGD  + 16777216;   // 147456 ints
constexpr long OFF_GOUTT = OFF_IDX   + 147456;     // 1310720
constexpr long OFF_WPB   = OFF_GOUTT + 1310720;    // 131072 (proj_w bf16)
constexpr long OFF_Y     = OFF_WPB   + 131072;     // 1310720
constexpr long OFF_AMAPB = OFF_Y     + 1310720;    // amap bf16 K-pad96: 786432 slots
constexpr long OFF_FC1B  = OFF_AMAPB + 786432;     // fc1_w bf16 [80][96] -> 4096 slots

DI float wsum(float v){
#pragma unroll
  for(int d=1; d<64; d<<=1) v += __shfl_xor(v, d);
  return v;
}
DI unsigned short f2b(float f){
  unsigned u = __float_as_uint(f);
  unsigned r = (u + 0x7FFFu + ((u >> 16) & 1u)) >> 16;
  return (unsigned short)r;
}

#define GLOAD16(g, s) __builtin_amdgcn_global_load_lds((const __attribute__((address_space(1))) void*)(g), \
                        (__attribute__((address_space(3))) void*)(s), 16, 0, 0)

// K1a: per-segment partial sums of x_patch
__global__ __launch_bounds__(256) void k_stats_partial(const float* __restrict__ x, float* __restrict__ part){
  int blk = blockIdx.x;                 // b*64+seg
  const float4* xp = (const float4*)x;
  long base4 = (long)blk * 2048;
  int t = threadIdx.x;
  float s = 0.f, ss = 0.f;
#pragma unroll
  for(int j=0;j<8;++j){
    float4 v = xp[base4 + t + 256*j];
    s  += v.x + v.y + v.z + v.w;
    ss += v.x*v.x + v.y*v.y + v.z*v.z + v.w*v.w;
  }
  s = wsum(s); ss = wsum(ss);
  __shared__ float rs[4], rss[4];
  int wv = t >> 6;
  if((t & 63) == 0){ rs[wv] = s; rss[wv] = ss; }
  __syncthreads();
  if(t == 0){
    part[blk*2]   = rs[0]+rs[1]+rs[2]+rs[3];
    part[blk*2+1] = rss[0]+rss[1]+rss[2]+rss[3];
  }
}

__global__ __launch_bounds__(64) void k_stats_final(const float* __restrict__ part, float* __restrict__ stats){
  int b = blockIdx.x, t = threadIdx.x;
  float s  = part[(b*64+t)*2];
  float ss = part[(b*64+t)*2+1];
  s = wsum(s); ss = wsum(ss);
  if(t == 0){
    const float cnt = (float)(C_ * N_);
    float m = s / cnt;
    float var = ss / cnt - m*m;
    stats[b*2]   = m;
    stats[b*2+1] = 1.0f / sqrtf(var + EPS_);
  }
}

// K2: norm + transpose + bf16: xnb[b][n][c]
__global__ __launch_bounds__(256) void k_xn_t(const float* __restrict__ x, const float* __restrict__ stats,
                                              const float* __restrict__ nw, const float* __restrict__ nb,
                                              unsigned short* __restrict__ xnb){
  __shared__ float tile[64][65];
  int b = blockIdx.z, c0 = blockIdx.y*64, n0 = blockIdx.x*64;
  float m = stats[b*2], inv = stats[b*2+1];
  int t = threadIdx.x;
  const float* xb = x + ((long)b*C_ + c0)*N_ + n0;
#pragma unroll
  for(int j=0;j<4;++j){
    int idx = t + 256*j;
    int r = idx >> 4, c4 = (idx & 15)*4;
    float a = inv * nw[c0+r];
    float bb = nb[c0+r] - m*a;
    float4 v = *(const float4*)&xb[(long)r*N_ + c4];
    tile[r][c4]   = v.x*a + bb;
    tile[r][c4+1] = v.y*a + bb;
    tile[r][c4+2] = v.z*a + bb;
    tile[r][c4+3] = v.w*a + bb;
  }
  __syncthreads();
  unsigned short* ob = xnb + ((long)b*N_ + n0)*C_ + c0;
#pragma unroll
  for(int j=0;j<8;++j){
    int idx = t + 256*j;
    int n = idx >> 5, cc = (idx & 31)*2;
    ushort2 u;
    u.x = f2b(tile[cc][n]);
    u.y = f2b(tile[cc+1][n]);
    *(ushort2*)&ob[(long)n*C_ + cc] = u;
  }
}

// proj weight fp32 -> bf16
__global__ __launch_bounds__(256) void k_wconv(const float* __restrict__ a, unsigned short* __restrict__ oa){
  long i = (long)blockIdx.x*256 + threadIdx.x;
  float4 v = ((const float4*)a)[i];
  uint2 o;
  o.x = (unsigned)f2b(v.x) | ((unsigned)f2b(v.y) << 16);
  o.y = (unsigned)f2b(v.z) | ((unsigned)f2b(v.w) << 16);
  ((uint2*)oa)[i] = o;
}

// small-weight prep: block-diag mixer (160x160), fc2 (80x160), fc1 (80x96 pad) in bf16
__global__ __launch_bounds__(256) void k_wsmall(const float* __restrict__ mrw, const float* __restrict__ fc2w,
                                                const float* __restrict__ fc1w,
                                                unsigned short* __restrict__ w1bd, unsigned short* __restrict__ fc2b16,
                                                unsigned short* __restrict__ fc1b16){
  int row = blockIdx.x, t = threadIdx.x;
  if(row < 160){
    if(t < 160){
      unsigned short v = 0;
      if(t/40 == row/40) v = f2b(mrw[row*40 + (t % 40)]);
      w1bd[row*160 + t] = v;
    }
  } else if(row < 240){
    if(t < 160) fc2b16[(row-160)*160 + t] = f2b(fc2w[(long)(row-160)*160 + t]);
  } else {
    int r = row - 240;
    if(t < 96) fc1b16[r*96 + t] = (t < G_) ? f2b(fc1w[(long)r*G_ + t]) : (unsigned short)0;
  }
}

// E prep v2: grid (B, 5, 8)
__global__ __launch_bounds__(256) void k_eprep(const float* __restrict__ kv, const float* __restrict__ pqw,
                                               const float* __restrict__ pqb,
                                               unsigned short* __restrict__ Eb, float* __restrict__ ebb){
  int b = blockIdx.x, hh = blockIdx.y, cch = blockIdx.z, t = threadIdx.x;
  if(hh == 4){
    if(cch == 0){
      unsigned* z = (unsigned*)(Eb + ((long)b*128 + 80)*512);
      for(int i=t; i<12288; i+=256) z[i] = 0;
    }
    return;
  }
  int h = hh, c0 = cch*64;
  __shared__ float key[CLS_][HD_];      // 10 KB
  __shared__ float part[4][CLS_][64];   // 20 KB
  for(int i=t; i<CLS_*HD_; i+=256){
    int cls = i >> 7, d = i & 127;
    key[cls][d] = kv[((long)b*CLS_+cls)*1024 + h*HD_ + d];
  }
  __syncthreads();
  int c = t & 63, ds = t >> 6;
  float acc[CLS_] = {};
  const float* wp = pqw + ((long)(h*HD_ + ds*32))*C_ + c0 + c;
#pragma unroll 8
  for(int di=0; di<32; ++di){
    float wv = wp[(long)di*C_];
#pragma unroll
    for(int cls=0; cls<CLS_; ++cls) acc[cls] += key[cls][ds*32+di]*wv;
  }
#pragma unroll
  for(int cls=0; cls<CLS_; ++cls) part[ds][cls][c] = acc[cls];
  __syncthreads();
  for(int i=t; i<CLS_*64; i+=256){
    int cls = i >> 6, cc = i & 63;
    float v = part[0][cls][cc]+part[1][cls][cc]+part[2][cls][cc]+part[3][cls][cc];
    Eb[((long)b*128 + h*CLS_ + cls)*512 + c0 + cc] = f2b(v*SCALE_);
  }
  if(cch == 0 && t < CLS_){
    float bacc = 0.f;
    for(int d=0; d<HD_; ++d) bacc += key[t][d]*pqb[h*HD_+d];
    ebb[b*G_ + h*CLS_ + t] = bacc*SCALE_;
  }
}

// amap GEMM: amapT fp32 + amapb bf16(K-pad 96)
__global__ __launch_bounds__(256) void k_amap_gemm(const unsigned short* __restrict__ Eb,
                                                   const unsigned short* __restrict__ Xb,
                                                   const float* __restrict__ ebb,
                                                   float* __restrict__ amapT,
                                                   unsigned short* __restrict__ amapb){
  __shared__ unsigned short Anl[2048];   // 64 n rows x 32 k
  __shared__ unsigned short Bgl[4096];   // 128 g rows x 32 k
  int b = blockIdx.y, n0 = blockIdx.x*64;
  int t = threadIdx.x, w = t >> 6, l = t & 63;
  int wr = w >> 1, wc = w & 1;
  f32x4 acc[2][4] = {};
  const unsigned short* At = Xb + ((long)b*N_ + n0 + w*16 + (l>>2))*512 + (l&3)*8;
  const unsigned short* Bt = Eb + ((long)b*128 + w*16 + (l>>2))*512 + (l&3)*8;
  int ra = wr*32 + (l & 15);
  int rb = wc*64 + (l & 15);
  int kq = (l >> 4) * 8;
  for(int k0 = 0; k0 < 512; k0 += 32){
    if(k0) __syncthreads();
    GLOAD16(At + k0,          &Anl[w*512]);
    GLOAD16(Bt + k0,          &Bgl[w*512]);
    GLOAD16(Bt + 64*512 + k0, &Bgl[2048 + w*512]);
    __syncthreads();
    bf16x8 af[2], bfr[4];
#pragma unroll
    for(int rt=0; rt<2; ++rt) af[rt]  = *(const bf16x8*)&Anl[(ra + rt*16)*32 + kq];
#pragma unroll
    for(int ct=0; ct<4; ++ct) bfr[ct] = *(const bf16x8*)&Bgl[(rb + ct*16)*32 + kq];
#pragma unroll
    for(int rt=0; rt<2; ++rt)
#pragma unroll
      for(int ct=0; ct<4; ++ct)
        acc[rt][ct] = __builtin_amdgcn_mfma_f32_16x16x32_bf16(af[rt], bfr[ct], acc[rt][ct], 0, 0, 0);
  }
  int r0 = (l >> 4)*4;
#pragma unroll
  for(int rt=0; rt<2; ++rt){
#pragma unroll
    for(int r=0; r<4; ++r){
      int n = n0 + wr*32 + rt*16 + r0 + r;
      long rowb  = ((long)b*N_ + n)*G_;
      long rowb9 = ((long)b*N_ + n)*96;
#pragma unroll
      for(int ct=0; ct<4; ++ct){
        int g = wc*64 + ct*16 + (l & 15);
        if(g < G_){
          float val = acc[rt][ct][r] + ebb[b*G_ + g];
          amapT[rowb + g] = val;
          amapb[rowb9 + g] = f2b(val);
        } else if(g < 96){
          amapb[rowb9 + g] = 0;
        }
      }
    }
  }
}

// MFMA GEMM: Out[b][o][n] = sum_c Wb[o][c]*Xb[b][n][c] + bias[o] (+Res)
template<bool RES>
__global__ __launch_bounds__(256) void k_gemm_mfma(const unsigned short* __restrict__ Wb,
                                                   const unsigned short* __restrict__ Xb,
                                                   const float* __restrict__ bias,
                                                   const float* __restrict__ Res,
                                                   float* __restrict__ Out){
  __shared__ unsigned short Al[4096];   // [128 rows(o)][32 k]
  __shared__ unsigned short Bl[4096];   // [128 rows(n)][32 k]
  int b = blockIdx.z;
  int o0 = blockIdx.y*128, n0 = blockIdx.x*128;
  int t = threadIdx.x, w = t >> 6, l = t & 63;
  int wr = w >> 1, wc = w & 1;
  f32x4 acc[4][4] = {};
  const unsigned short* Wt = Wb + (long)(o0 + w*16 + (l>>2))*512 + (l&3)*8;
  const unsigned short* Xt = Xb + ((long)b*N_ + n0 + w*16 + (l>>2))*512 + (l&3)*8;
  int ra = wr*64 + (l & 15);
  int rb = wc*64 + (l & 15);
  int kq = (l >> 4) * 8;
  for(int k0 = 0; k0 < 512; k0 += 32){
    if(k0) __syncthreads();
    GLOAD16(Wt + k0,            &Al[w*512]);
    GLOAD16(Wt + 64*512 + k0,   &Al[2048 + w*512]);
    GLOAD16(Xt + k0,            &Bl[w*512]);
    GLOAD16(Xt + 64*512 + k0,   &Bl[2048 + w*512]);
    __syncthreads();
    bf16x8 af[4], bfr[4];
#pragma unroll
    for(int i=0;i<4;++i){
      af[i]  = *(const bf16x8*)&Al[(ra + i*16)*32 + kq];
      bfr[i] = *(const bf16x8*)&Bl[(rb + i*16)*32 + kq];
    }
#pragma unroll
    for(int mi=0; mi<4; ++mi)
#pragma unroll
      for(int ni=0; ni<4; ++ni)
        acc[mi][ni] = __builtin_amdgcn_mfma_f32_16x16x32_bf16(af[mi], bfr[ni], acc[mi][ni], 0, 0, 0);
  }
  long obase = ((long)b*C_ + o0 + wr*64)*N_ + n0 + wc*64 + (l & 15);
  int r0 = (l >> 4) * 4;
#pragma unroll
  for(int mi=0; mi<4; ++mi){
#pragma unroll
    for(int r=0; r<4; ++r){
      int row = mi*16 + r0 + r;
      float bi = bias[o0 + wr*64 + row];
#pragma unroll
      for(int ni=0; ni<4; ++ni){
        long oi = obase + (long)row*N_ + ni*16;
        float v = acc[mi][ni][r] + bi;
        if(RES) v += Res[oi];
        Out[oi] = v;
      }
    }
  }
}

// K4: cls layernorm + kv projection
__global__ __launch_bounds__(256) void k_cls_kv(const float* __restrict__ xcls,
                                                const float* __restrict__ ncw, const float* __restrict__ ncb,
                                                const float* __restrict__ pkvw, const float* __restrict__ pkvb,
                                                float* __restrict__ kv){
  int b = blockIdx.x;
  int ochunk = blockIdx.y;
  __shared__ float xc[CLS_][C_];
  int t = threadIdx.x, wv = t >> 6, l = t & 63;
  for(int cls = wv; cls < CLS_; cls += 4){
    const float* xr = xcls + ((long)b*CLS_ + cls) * C_;
    float vals[8];
    float s = 0.f, ss = 0.f;
#pragma unroll
    for(int j=0;j<8;++j){ float v = xr[l + 64*j]; vals[j] = v; s += v; ss += v*v; }
    s = wsum(s); ss = wsum(ss);
    float m = s / (float)C_;
    float var = ss / (float)C_ - m*m;
    float inv = 1.0f / sqrtf(var + EPS_);
#pragma unroll
    for(int j=0;j<8;++j){
      int c = l + 64*j;
      xc[cls][c] = (vals[j]-m)*inv*ncw[c] + ncb[c];
    }
  }
  __syncthreads();
  int o = ochunk*128 + (t & 127);
  int cls0 = (t >> 7) * 10;
  float acc[10] = {};
  const float* wrow = pkvw + (long)o * C_;
  for(int k4 = 0; k4 < C_; k4 += 4){
    float4 w4 = *(const float4*)&wrow[k4];
#pragma unroll
    for(int i=0;i<10;++i){
      acc[i] += w4.x*xc[cls0+i][k4] + w4.y*xc[cls0+i][k4+1] + w4.z*xc[cls0+i][k4+2] + w4.w*xc[cls0+i][k4+3];
    }
  }
  float bo = pkvb[o];
#pragma unroll
  for(int i=0;i<10;++i) kv[((long)b*CLS_ + cls0+i)*1024 + o] = acc[i] + bo;
}

// K6 v3: fc1 via MFMA + bn1 + row-normalize. one wave = 16 rows. grid 256
__global__ __launch_bounds__(256) void k_fc1_mfma(const unsigned short* __restrict__ amapb,
                                                  const unsigned short* __restrict__ w1b,
                                                  const float* __restrict__ bias,
                                                  const float* __restrict__ g1, const float* __restrict__ b1,
                                                  float* __restrict__ xf, unsigned short* __restrict__ xub,
                                                  float* __restrict__ sq){
  int t = threadIdx.x, w = t >> 6, l = t & 63;
  long row0 = ((long)blockIdx.x*4 + w)*16;
  int lr = l & 15, lk = l >> 4;
  bf16x8 ay[3];
  const unsigned short* arow = amapb + (row0 + lr)*96 + lk*8;
#pragma unroll
  for(int ks=0; ks<3; ++ks) ay[ks] = *(const bf16x8*)&arow[ks*32];
  f32x4 acc[5] = {};
  const unsigned short* wrow = w1b + (long)lr*96 + lk*8;
#pragma unroll
  for(int ks=0; ks<3; ++ks){
#pragma unroll
    for(int ct=0; ct<5; ++ct){
      bf16x8 bw = *(const bf16x8*)&wrow[ct*16*96 + ks*32];
      acc[ct] = __builtin_amdgcn_mfma_f32_16x16x32_bf16(ay[ks], bw, acc[ct], 0, 0, 0);
    }
  }
  float v[5][4];
  float ssq[4] = {0.f,0.f,0.f,0.f};
#pragma unroll
  for(int ct=0; ct<5; ++ct){
    int o = ct*16 + lr;
    float bi = bias[o], ga = g1[o]*BNS_, bb = b1[o];
#pragma unroll
    for(int i=0;i<4;++i){
      float vv = (acc[ct][i] + bi)*ga + bb;
      v[ct][i] = vv;
      ssq[i] += vv*vv;
    }
  }
#pragma unroll
  for(int d=1; d<16; d<<=1){
#pragma unroll
    for(int i=0;i<4;++i) ssq[i] += __shfl_xor(ssq[i], d);
  }
#pragma unroll
  for(int i=0;i<4;++i){
    long row = row0 + lk*4 + i;
    float invn = 1.0f / fmaxf(sqrtf(ssq[i]), 1e-12f);
#pragma unroll
    for(int ct=0; ct<5; ++ct){
      int o = ct*16 + lr;
      xf[row*G_ + o] = v[ct][i];
      xub[row*96 + o] = f2b(v[ct][i]*invn);
    }
    xub[row*96 + 80 + lr] = 0;
    if(lr == 0) sq[row] = ssq[i]*invn*invn;
  }
}

// K8: neg_d via bf16 MFMA: 128x128 tile, K=96 (padded)
__global__ __launch_bounds__(256) void k_negd_mfma(const unsigned short* __restrict__ xub,
                                                   const float* __restrict__ sq,
                                                   float* __restrict__ negd){
  __shared__ unsigned short Al[128*96];
  __shared__ unsigned short Bl[128*96];
  int b = blockIdx.z;
  int n0 = blockIdx.y*128, m0 = blockIdx.x*128;
  int t = threadIdx.x, w = t >> 6, l = t & 63;
  int wr = w >> 1, wc = w & 1;
  const unsigned short* gA = xub + ((long)b*N_ + n0)*96;
  const unsigned short* gB = xub + ((long)b*N_ + m0)*96;
#pragma unroll
  for(int rd=0; rd<6; ++rd){
    int chunk = rd*4 + w;
    GLOAD16(gA + chunk*512 + l*8, &Al[chunk*512]);
    GLOAD16(gB + chunk*512 + l*8, &Bl[chunk*512]);
  }
  __syncthreads();
  f32x4 acc[4][4] = {};
  int ra = wr*64 + (l & 15);
  int rb = wc*64 + (l & 15);
#pragma unroll
  for(int ks=0; ks<3; ++ks){
    int kq = ks*32 + (l >> 4)*8;
    bf16x8 af[4], bfr[4];
#pragma unroll
    for(int i=0;i<4;++i){
      af[i]  = *(const bf16x8*)&Al[(ra + i*16)*96 + kq];
      bfr[i] = *(const bf16x8*)&Bl[(rb + i*16)*96 + kq];
    }
#pragma unroll
    for(int mi=0; mi<4; ++mi)
#pragma unroll
      for(int ni=0; ni<4; ++ni)
        acc[mi][ni] = __builtin_amdgcn_mfma_f32_16x16x32_bf16(af[mi], bfr[ni], acc[mi][ni], 0, 0, 0);
  }
  int r0 = (l >> 4)*4;
  const float* sqb = sq + (long)b*N_;
#pragma unroll
  for(int mi=0; mi<4; ++mi){
#pragma unroll
    for(int r=0; r<4; ++r){
      int n = n0 + wr*64 + mi*16 + r0 + r;
      float sn = sqb[n];
      long row = ((long)b*N_ + n)*N_;
#pragma unroll
      for(int ni=0; ni<4; ++ni){
        int m = m0 + wc*64 + ni*16 + (l & 15);
        negd[row + m] = 2.f*acc[mi][ni][r] - sn - sqb[m];
      }
    }
  }
}

// K9: top-9 per row
__global__ __launch_bounds__(256) void k_topk(const float* __restrict__ negd, int* __restrict__ idx){
  int t = threadIdx.x, wv = t >> 6, l = t & 63;
  long r = (long)blockIdx.x*4 + wv;
  const float* row = negd + r*N_;
  float vals[16];
#pragma unroll
  for(int j=0;j<16;++j) vals[j] = row[l + 64*j];
#pragma unroll
  for(int p=0; p<K_; ++p){
    float bv = vals[0]; int bj = 0;
#pragma unroll
    for(int j=1;j<16;++j) if(vals[j] > bv){ bv = vals[j]; bj = j; }
    int bm = l + 64*bj;
#pragma unroll
    for(int d=1; d<64; d<<=1){
      float ov = __shfl_xor(bv, d);
      int   om = __shfl_xor(bm, d);
      if(ov > bv || (ov == bv && om < bm)){ bv = ov; bm = om; }
    }
#pragma unroll
    for(int j=0;j<16;++j) if(bm == l + 64*j) vals[j] = -INFINITY;
    if(l == 0) idx[r*K_ + p] = bm;
  }
}

// K10a: gather -> y[b][n][160] bf16. one wave/row
__global__ __launch_bounds__(256) void k_y(const float* __restrict__ xf, const int* __restrict__ idx,
                                           unsigned short* __restrict__ y){
  int t = threadIdx.x, wv = t >> 6, l = t & 63;
  long r = (long)blockIdx.x*4 + wv;
  long b = r >> 10;
  const float* frow = xf + r*G_;
  int o2s = (l < 16) ? (64 + l) : 0;
  float f0 = frow[l];
  float f1 = frow[o2s];
  const int* ixp = idx + r*K_;
  float m0 = -INFINITY, m1 = -INFINITY;
#pragma unroll
  for(int k=0;k<K_;++k){
    const float* nr = xf + ((long)b*N_ + ixp[k])*G_;
    m0 = fmaxf(m0, nr[l]);
    m1 = fmaxf(m1, nr[o2s]);
  }
  unsigned short* yr = y + r*G2_;
  ushort2 u0; u0.x = f2b(f0); u0.y = f2b(m0 - f0);
  *(ushort2*)&yr[2*l] = u0;
  if(l < 16){
    ushort2 u1; u1.x = f2b(f1); u1.y = f2b(m1 - f1);
    *(ushort2*)&yr[128 + 2*l] = u1;
  }
}

// K10b: MFMA mixer + bn2 + gelu + fc2 + bn3 + amap -> goutT
__global__ __launch_bounds__(256) void k_mixer_mfma(const unsigned short* __restrict__ y,
                                                    const unsigned short* __restrict__ w1bd,
                                                    const float* __restrict__ mrb,
                                                    const float* __restrict__ g2, const float* __restrict__ b2,
                                                    const unsigned short* __restrict__ fc2b16,
                                                    const float* __restrict__ fc2bias,
                                                    const float* __restrict__ g3, const float* __restrict__ b3,
                                                    const float* __restrict__ amapT, float* __restrict__ goutT){
  __shared__ unsigned short zl[4][16][G2_];
  int t = threadIdx.x, w = t >> 6, l = t & 63;
  long row0 = ((long)blockIdx.x*4 + w)*16;
  int lr = l & 15, lk = l >> 4;
  bf16x8 ay[5];
  const unsigned short* yrow = y + (row0 + lr)*G2_ + lk*8;
#pragma unroll
  for(int ks=0; ks<5; ++ks) ay[ks] = *(const bf16x8*)&yrow[ks*32];
  f32x4 accz[10] = {};
  const unsigned short* wb = w1bd + (long)lr*G2_ + lk*8;
#pragma unroll
  for(int ks=0; ks<5; ++ks){
#pragma unroll
    for(int ct=0; ct<10; ++ct){
      bf16x8 bw = *(const bf16x8*)&wb[ct*16*G2_ + ks*32];
      accz[ct] = __builtin_amdgcn_mfma_f32_16x16x32_bf16(ay[ks], bw, accz[ct], 0, 0, 0);
    }
  }
#pragma unroll
  for(int ct=0; ct<10; ++ct){
    int o = ct*16 + lr;
    float bi = mrb[o], ga = g2[o]*BNS_, bb = b2[o];
#pragma unroll
    for(int i=0;i<4;++i){
      float v = (accz[ct][i] + bi)*ga + bb;
      float zz = v * 0.5f * (1.0f + erff(v * INVSQRT2_));
      zl[w][lk*4 + i][o] = f2b(zz);
    }
  }
  __syncthreads();
  bf16x8 az[5];
#pragma unroll
  for(int ks=0; ks<5; ++ks) az[ks] = *(const bf16x8*)&zl[w][lr][ks*32 + lk*8];
  f32x4 acc2[5] = {};
  const unsigned short* fb = fc2b16 + (long)lr*G2_ + lk*8;
#pragma unroll
  for(int ks=0; ks<5; ++ks){
#pragma unroll
    for(int ct=0; ct<5; ++ct){
      bf16x8 bw = *(const bf16x8*)&fb[ct*16*G2_ + ks*32];
      acc2[ct] = __builtin_amdgcn_mfma_f32_16x16x32_bf16(az[ks], bw, acc2[ct], 0, 0, 0);
    }
  }
#pragma unroll
  for(int ct=0; ct<5; ++ct){
    int o = ct*16 + lr;
    float bi = fc2bias[o], ga = g3[o]*BNS_, bb = b3[o];
#pragma unroll
    for(int i=0;i<4;++i){
      long row = row0 + lk*4 + i;
      float v = (acc2[ct][i] + bi)*ga + bb + amapT[row*G_ + o];
      goutT[row*G_ + o] = v;
    }
  }
}

// K12 v2: per-thread softmax + MFMA PV -> bf16 aob[b][n][c]
__global__ __launch_bounds__(256) void k_softmax_pv(const float* __restrict__ goutT, const float* __restrict__ kv,
                                                    unsigned short* __restrict__ aob){
  int bh = blockIdx.x; int b = bh >> 2, h = bh & 3;
  int n0 = blockIdx.y * 64;
  __shared__ unsigned short Vt[128*32];   // [d][cls-pad32]
  __shared__ unsigned short Pl[64*40];    // [n][cls-pad32, stride 40]
  __shared__ unsigned short Os[64*132];   // [n][d, stride 132]
  int t = threadIdx.x, w = t >> 6, l = t & 63;
  if(t < 128){
    int d = t;
    const float* vb = kv + ((long)b*CLS_)*1024 + C_ + h*HD_ + d;
#pragma unroll
    for(int cls=0; cls<CLS_; ++cls) Vt[d*32+cls] = f2b(vb[(long)cls*1024]);
#pragma unroll
    for(int cls=CLS_; cls<32; ++cls) Vt[d*32+cls] = 0;
  }
  if(t < 64){
    int n = n0 + t;
    const float* gr = goutT + ((long)b*N_ + n)*G_ + h*CLS_;
    float x[CLS_];
    float mx = -INFINITY;
#pragma unroll
    for(int cls=0; cls<CLS_; ++cls){ x[cls] = gr[cls]; mx = fmaxf(mx, x[cls]); }
    float s = 0.f;
#pragma unroll
    for(int cls=0; cls<CLS_; ++cls){ x[cls] = expf(x[cls]-mx); s += x[cls]; }
    float inv = 1.0f / s;
#pragma unroll
    for(int cls=0; cls<CLS_; ++cls) Pl[t*40+cls] = f2b(x[cls]*inv);
#pragma unroll
    for(int cls=CLS_; cls<32; ++cls) Pl[t*40+cls] = 0;
  }
  __syncthreads();
  int lr = l & 15, kq = (l >> 4)*8;
  f32x4 acc[4][2] = {};
  bf16x8 af[4], bf2[2];
#pragma unroll
  for(int rt=0; rt<4; ++rt) af[rt] = *(const bf16x8*)&Pl[(rt*16+lr)*40 + kq];
#pragma unroll
  for(int ci=0; ci<2; ++ci) bf2[ci] = *(const bf16x8*)&Vt[((2*w+ci)*16+lr)*32 + kq];
#pragma unroll
  for(int rt=0; rt<4; ++rt)
#pragma unroll
    for(int ci=0; ci<2; ++ci)
      acc[rt][ci] = __builtin_amdgcn_mfma_f32_16x16x32_bf16(af[rt], bf2[ci], acc[rt][ci], 0, 0, 0);
  int r0 = (l >> 4)*4;
#pragma unroll
  for(int rt=0; rt<4; ++rt)
#pragma unroll
    for(int ci=0; ci<2; ++ci)
#pragma unroll
      for(int i=0; i<4; ++i)
        Os[(rt*16 + r0 + i)*132 + (2*w+ci)*16 + lr] = f2b(acc[rt][ci][i]);
  __syncthreads();
  unsigned short* ob = aob + ((long)b*N_ + n0)*C_ + h*HD_;
#pragma unroll
  for(int j=0; j<8; ++j){
    int idx = t + 256*j;            // 2048 chunks of 4 shorts -> full 64x128 tile
    int row = idx >> 5, ch = idx & 31;
    *(ushort4*)&ob[(long)row*C_ + ch*4] =
        *(const ushort4*)&Os[row*132 + ch*4];
  }
}

extern "C" void kernel_launch(void* const* d_in, const int* in_sizes, int n_in,
                              void* d_out, int out_size, void* d_ws, size_t ws_size,
                              hipStream_t stream){
  const float* x_cls   = (const float*)d_in[0];
  const float* x_patch = (const float*)d_in[1];
  const float* norm_x_w = (const float*)d_in[2];
  const float* norm_x_b = (const float*)d_in[3];
  const float* pq_w  = (const float*)d_in[4];
  const float* pq_b  = (const float*)d_in[5];
  const float* ncls_w = (const float*)d_in[6];
  const float* ncls_b = (const float*)d_in[7];
  const float* pkv_w = (const float*)d_in[8];
  const float* pkv_b = (const float*)d_in[9];
  const float* fc1_w = (const float*)d_in[10];
  const float* fc1_b = (const float*)d_in[11];
  const float* bn1_g = (const float*)d_in[12];
  const float* bn1_b = (const float*)d_in[13];
  const float* mr_w  = (const float*)d_in[14];
  const float* mr_b  = (const float*)d_in[15];
  const float* bn2_g = (const float*)d_in[16];
  const float* bn2_b = (const float*)d_in[17];
  const float* fc2_w = (const float*)d_in[18];
  const float* fc2_b = (const float*)d_in[19];
  const float* bn3_g = (const float*)d_in[20];
  const float* bn3_b = (const float*)d_in[21];
  const float* proj_w = (const float*)d_in[22];
  const float* proj_b = (const float*)d_in[23];

  float* ws = (float*)d_ws;
  float* part   = ws + OFF_PART;
  float* stats  = ws + OFF_STATS;
  float* ebb    = ws + OFF_EBB;
  float* kvbuf  = ws + OFF_KV;
  float* amapT  = ws + OFF_AMAPT;
  float* xf     = ws + OFF_XF;
  float* sqbuf  = ws + OFF_SQ;
  float* negd   = ws + OFF_NEGD;
  int*   idxbuf = (int*)(ws + OFF_IDX);
  float* goutT  = ws + OFF_GOUTT;
  unsigned short* Eb     = (unsigned short*)(ws + OFF_EB);
  unsigned short* xub    = (unsigned short*)(ws + OFF_XUB);
  unsigned short* w1bd   = (unsigned short*)(ws + OFF_W1BD);
  unsigned short* fc2b16 = (unsigned short*)(ws + OFF_FC2B);
  unsigned short* ybuf   = (unsigned short*)(ws + OFF_Y);
  unsigned short* amapb  = (unsigned short*)(ws + OFF_AMAPB);
  unsigned short* fc1b16 = (unsigned short*)(ws + OFF_FC1B);
  unsigned short* xnb = (unsigned short*)(ws + OFF_NEGD);   // overlay: dead before negd written
  unsigned short* aob = (unsigned short*)(ws + OFF_NEGD);   // overlay: negd dead after topk
  unsigned short* wpb = (unsigned short*)(ws + OFF_WPB);
  float* out = (float*)d_out;

  k_stats_partial<<<1024, 256, 0, stream>>>(x_patch, part);
  k_stats_final<<<16, 64, 0, stream>>>(part, stats);
  k_xn_t<<<dim3(16,8,16), 256, 0, stream>>>(x_patch, stats, norm_x_w, norm_x_b, xnb);
  k_cls_kv<<<dim3(16,8), 256, 0, stream>>>(x_cls, ncls_w, ncls_b, pkv_w, pkv_b, kvbuf);
  k_eprep<<<dim3(16,5,8), 256, 0, stream>>>(kvbuf, pq_w, pq_b, Eb, ebb);
  k_wconv<<<256, 256, 0, stream>>>(proj_w, wpb);
  k_wsmall<<<320, 256, 0, stream>>>(mr_w, fc2_w, fc1_w, w1bd, fc2b16, fc1b16);
  k_amap_gemm<<<dim3(16,16), 256, 0, stream>>>(Eb, xnb, ebb, amapT, amapb);
  k_fc1_mfma<<<256, 256, 0, stream>>>(amapb, fc1b16, fc1_b, bn1_g, bn1_b, xf, xub, sqbuf);
  k_negd_mfma<<<dim3(8,8,16), 256, 0, stream>>>(xub, sqbuf, negd);
  k_topk<<<4096, 256, 0, stream>>>(negd, idxbuf);
  k_y<<<4096, 256, 0, stream>>>(xf, idxbuf, ybuf);
  k_mixer_mfma<<<256, 256, 0, stream>>>(ybuf, w1bd, mr_b, bn2_g, bn2_b,
                                        fc2b16, fc2_b, bn3_g, bn3_b, amapT, goutT);
  k_softmax_pv<<<dim3(64,16), 256, 0, stream>>>(goutT, kvbuf, aob);
  k_gemm_mfma<true><<<dim3(8,4,16), 256, 0, stream>>>(wpb, aob, proj_b, x_patch, out);
}

// Round 8
// 181.393 us; speedup vs baseline: 3.1965x; 1.0734x over previous
//
#include <hip/hip_runtime.h>
#include <math.h>

#define DI __device__ __forceinline__

constexpr int B_ = 16, CLS_ = 20, C_ = 512, H_ = 4, HD_ = 128, N_ = 1024, G_ = 80, G2_ = 160, K_ = 9;
constexpr float EPS_ = 1e-5f;
constexpr float BNS_ = 0.9999950000374997f;     // 1/sqrt(1+1e-5)
constexpr float SCALE_ = 0.08838834764831845f;  // 128^-0.5
constexpr float INVSQRT2_ = 0.7071067811865475f;

typedef __attribute__((ext_vector_type(8))) short bf16x8;
typedef __attribute__((ext_vector_type(4))) float f32x4;

// ---- workspace layout (float slots) ----
constexpr long OFF_PART  = 0;                      // 2048
constexpr long OFF_STATS = 2048;                   // 32
constexpr long OFF_EB    = 4096;                   // E bf16 [16][128][512] = 524288 slots
constexpr long OFF_EBB   = OFF_EB    + 524288;     // 1280 fp32
constexpr long OFF_KV    = OFF_EBB   + 2048;       // 16*20*1024
constexpr long OFF_AMAPT = OFF_KV    + 327680;     // 16*1024*80 fp32
constexpr long OFF_XF    = OFF_AMAPT + 1310720;
constexpr long OFF_XUB   = OFF_XF    + 1310720;    // bf16 16*1024*96 = 786432 slots
constexpr long OFF_W1BD  = OFF_XUB   + 786432;     // 16384
constexpr long OFF_FC2B  = OFF_W1BD  + 16384;      // 8192
constexpr long OFF_SQ    = OFF_FC2B  + 8192;       // 16384
constexpr long OFF_NEGD  = OFF_SQ    + 16384;      // 16*1024*1024 fp32; overlays aob (late)
constexpr long OFF_GOUTT = OFF_NEGD  + 16777216 + 147456;  // 1310720
constexpr long OFF_WPB   = OFF_GOUTT + 1310720;    // 131072 (proj_w bf16)
constexpr long OFF_Y     = OFF_WPB   + 131072;     // 1310720
constexpr long OFF_AMAPB = OFF_Y     + 1310720;    // amap bf16 K-pad96: 786432 slots
constexpr long OFF_FC1B  = OFF_AMAPB + 786432;     // fc1_w bf16 [80][96] -> 4096 slots
constexpr long OFF_PB    = OFF_FC1B  + 4096;       // bias partials [16][8][80] -> 10240

DI float wsum(float v){
#pragma unroll
  for(int d=1; d<64; d<<=1) v += __shfl_xor(v, d);
  return v;
}
DI unsigned short f2b(float f){
  unsigned u = __float_as_uint(f);
  unsigned r = (u + 0x7FFFu + ((u >> 16) & 1u)) >> 16;
  return (unsigned short)r;
}

#define GLOAD16(g, s) __builtin_amdgcn_global_load_lds((const __attribute__((address_space(1))) void*)(g), \
                        (__attribute__((address_space(3))) void*)(s), 16, 0, 0)

// K1a: per-segment partial sums of x_patch
__global__ __launch_bounds__(256) void k_stats_partial(const float* __restrict__ x, float* __restrict__ part){
  int blk = blockIdx.x;                 // b*64+seg
  const float4* xp = (const float4*)x;
  long base4 = (long)blk * 2048;
  int t = threadIdx.x;
  float s = 0.f, ss = 0.f;
#pragma unroll
  for(int j=0;j<8;++j){
    float4 v = xp[base4 + t + 256*j];
    s  += v.x + v.y + v.z + v.w;
    ss += v.x*v.x + v.y*v.y + v.z*v.z + v.w*v.w;
  }
  s = wsum(s); ss = wsum(ss);
  __shared__ float rs[4], rss[4];
  int wv = t >> 6;
  if((t & 63) == 0){ rs[wv] = s; rss[wv] = ss; }
  __syncthreads();
  if(t == 0){
    part[blk*2]   = rs[0]+rs[1]+rs[2]+rs[3];
    part[blk*2+1] = rss[0]+rss[1]+rss[2]+rss[3];
  }
}

__global__ __launch_bounds__(64) void k_stats_final(const float* __restrict__ part, float* __restrict__ stats){
  int b = blockIdx.x, t = threadIdx.x;
  float s  = part[(b*64+t)*2];
  float ss = part[(b*64+t)*2+1];
  s = wsum(s); ss = wsum(ss);
  if(t == 0){
    const float cnt = (float)(C_ * N_);
    float m = s / cnt;
    float var = ss / cnt - m*m;
    stats[b*2]   = m;
    stats[b*2+1] = 1.0f / sqrtf(var + EPS_);
  }
}

// merged weight prep: blocks 0..255 -> proj_w fp32->bf16 ; 256..575 -> small weights
__global__ __launch_bounds__(256) void k_wprep(const float* __restrict__ projw, unsigned short* __restrict__ wpb,
                                               const float* __restrict__ mrw, const float* __restrict__ fc2w,
                                               const float* __restrict__ fc1w,
                                               unsigned short* __restrict__ w1bd, unsigned short* __restrict__ fc2b16,
                                               unsigned short* __restrict__ fc1b16){
  int blk = blockIdx.x, t = threadIdx.x;
  if(blk < 256){
    long i = (long)blk*256 + t;
    float4 v = ((const float4*)projw)[i];
    uint2 o;
    o.x = (unsigned)f2b(v.x) | ((unsigned)f2b(v.y) << 16);
    o.y = (unsigned)f2b(v.z) | ((unsigned)f2b(v.w) << 16);
    ((uint2*)wpb)[i] = o;
    return;
  }
  int row = blk - 256;
  if(row < 160){
    if(t < 160){
      unsigned short v = 0;
      if(t/40 == row/40) v = f2b(mrw[row*40 + (t % 40)]);
      w1bd[row*160 + t] = v;
    }
  } else if(row < 240){
    if(t < 160) fc2b16[(row-160)*160 + t] = f2b(fc2w[(long)(row-160)*160 + t]);
  } else {
    int r = row - 240;
    if(t < 96) fc1b16[r*96 + t] = (t < G_) ? f2b(fc1w[(long)r*G_ + t]) : (unsigned short)0;
  }
}

// E prep v3: folds patch-norm affine into E and bias partials.
// E'[b][g][c] = SCALE * (sum_d key*pqw) * a_c  ;  pb[b][cch][g] = sum_{c in chunk} SCALE*E*(nb_c - m*a_c)
__global__ __launch_bounds__(256) void k_eprep(const float* __restrict__ kv, const float* __restrict__ pqw,
                                               const float* __restrict__ pqb, const float* __restrict__ stats,
                                               const float* __restrict__ nw, const float* __restrict__ nbv,
                                               unsigned short* __restrict__ Eb, float* __restrict__ ebb,
                                               float* __restrict__ pb){
  int b = blockIdx.x, hh = blockIdx.y, cch = blockIdx.z, t = threadIdx.x;
  if(hh == 4){
    if(cch == 0){
      unsigned* z = (unsigned*)(Eb + ((long)b*128 + 80)*512);
      for(int i=t; i<12288; i+=256) z[i] = 0;
    }
    return;
  }
  int h = hh, c0 = cch*64;
  float m = stats[b*2], inv = stats[b*2+1];
  __shared__ float key[CLS_][HD_];      // 10 KB
  __shared__ float part[4][CLS_][64];   // 20 KB
  for(int i=t; i<CLS_*HD_; i+=256){
    int cls = i >> 7, d = i & 127;
    key[cls][d] = kv[((long)b*CLS_+cls)*1024 + h*HD_ + d];
  }
  __syncthreads();
  int c = t & 63, ds = t >> 6;
  float acc[CLS_] = {};
  const float* wp = pqw + ((long)(h*HD_ + ds*32))*C_ + c0 + c;
#pragma unroll 8
  for(int di=0; di<32; ++di){
    float wv = wp[(long)di*C_];
#pragma unroll
    for(int cls=0; cls<CLS_; ++cls) acc[cls] += key[cls][ds*32+di]*wv;
  }
#pragma unroll
  for(int cls=0; cls<CLS_; ++cls) part[ds][cls][c] = acc[cls];
  __syncthreads();
  for(int i=t; i<CLS_*64; i+=256){
    int cls = i >> 6, cc = i & 63;
    float v = (part[0][cls][cc]+part[1][cls][cc]+part[2][cls][cc]+part[3][cls][cc]) * SCALE_;
    int cg = c0 + cc;
    float a = inv * nw[cg];
    float bbv = nbv[cg] - m*a;
    Eb[((long)b*128 + h*CLS_ + cls)*512 + cg] = f2b(v*a);
    part[0][cls][cc] = v*bbv;           // exclusive slot: safe read-then-write
  }
  __syncthreads();
  if(t < CLS_){
    float s = 0.f;
    for(int cc=0; cc<64; ++cc) s += part[0][t][cc];
    pb[((long)b*8 + cch)*G_ + h*CLS_ + t] = s;
  }
  if(cch == 0 && t >= 64 && t < 64 + CLS_){
    int tt = t - 64;
    float bacc = 0.f;
    for(int d=0; d<HD_; ++d) bacc += key[tt][d]*pqb[h*HD_+d];
    ebb[b*G_ + h*CLS_ + tt] = bacc*SCALE_;
  }
}

// amap GEMM v2: reads x_patch directly (in-kernel bf16 transpose staging), E' pre-scaled.
// amapT[b][n][g] (fp32) + amapb bf16(K-pad 96)
__global__ __launch_bounds__(256) void k_amap_gemm(const unsigned short* __restrict__ Eb,
                                                   const float* __restrict__ xp,
                                                   const float* __restrict__ ebb,
                                                   const float* __restrict__ pb,
                                                   float* __restrict__ amapT,
                                                   unsigned short* __restrict__ amapb){
  __shared__ unsigned short Xl[64*520];   // [64 n][512 k, stride 520]
  __shared__ unsigned short Bgl[4096];    // 128 g x 32 k
  int b = blockIdx.y, n0 = blockIdx.x*64;
  int t = threadIdx.x, w = t >> 6, l = t & 63;
  int wr = w >> 1, wc = w & 1;
  // stage X strip: 16 passes x (32 c x 64 n), coalesced fp32 reads, transposed bf16 LDS writes
  {
    int nb = t & 7, cl = t >> 3;
    const float* xb = xp + (long)b*C_*N_ + n0 + nb*8;
#pragma unroll 4
    for(int pass=0; pass<16; ++pass){
      int c = pass*32 + cl;
      const float* src = xb + (long)c*N_;
      float4 v0 = *(const float4*)src;
      float4 v1 = *(const float4*)(src+4);
      int base = (nb*8)*520 + c;
      Xl[base         ] = f2b(v0.x);
      Xl[base + 520   ] = f2b(v0.y);
      Xl[base + 520*2 ] = f2b(v0.z);
      Xl[base + 520*3 ] = f2b(v0.w);
      Xl[base + 520*4 ] = f2b(v1.x);
      Xl[base + 520*5 ] = f2b(v1.y);
      Xl[base + 520*6 ] = f2b(v1.z);
      Xl[base + 520*7 ] = f2b(v1.w);
    }
  }
  __syncthreads();
  f32x4 acc[2][4] = {};
  const unsigned short* Bt = Eb + ((long)b*128 + w*16 + (l>>2))*512 + (l&3)*8;
  int ra = wr*32 + (l & 15);
  int rb = wc*64 + (l & 15);
  int kq = (l >> 4) * 8;
  for(int k0 = 0; k0 < 512; k0 += 32){
    if(k0) __syncthreads();
    GLOAD16(Bt + k0,          &Bgl[w*512]);
    GLOAD16(Bt + 64*512 + k0, &Bgl[2048 + w*512]);
    __syncthreads();
    bf16x8 af[2], bfr[4];
#pragma unroll
    for(int rt=0; rt<2; ++rt) af[rt]  = *(const bf16x8*)&Xl[(ra + rt*16)*520 + k0 + kq];
#pragma unroll
    for(int ct=0; ct<4; ++ct) bfr[ct] = *(const bf16x8*)&Bgl[(rb + ct*16)*32 + kq];
#pragma unroll
    for(int rt=0; rt<2; ++rt)
#pragma unroll
      for(int ct=0; ct<4; ++ct)
        acc[rt][ct] = __builtin_amdgcn_mfma_f32_16x16x32_bf16(af[rt], bfr[ct], acc[rt][ct], 0, 0, 0);
  }
  // bias per ct (g depends only on ct + lane)
  float bias4[4];
#pragma unroll
  for(int ct=0; ct<4; ++ct){
    int g = wc*64 + ct*16 + (l & 15);
    float bi = 0.f;
    if(g < G_){
      bi = ebb[b*G_ + g];
#pragma unroll
      for(int cc=0; cc<8; ++cc) bi += pb[((long)b*8 + cc)*G_ + g];
    }
    bias4[ct] = bi;
  }
  int r0 = (l >> 4)*4;
#pragma unroll
  for(int rt=0; rt<2; ++rt){
#pragma unroll
    for(int r=0; r<4; ++r){
      int n = n0 + wr*32 + rt*16 + r0 + r;
      long rowb  = ((long)b*N_ + n)*G_;
      long rowb9 = ((long)b*N_ + n)*96;
#pragma unroll
      for(int ct=0; ct<4; ++ct){
        int g = wc*64 + ct*16 + (l & 15);
        if(g < G_){
          float val = acc[rt][ct][r] + bias4[ct];
          amapT[rowb + g] = val;
          amapb[rowb9 + g] = f2b(val);
        } else if(g < 96){
          amapb[rowb9 + g] = 0;
        }
      }
    }
  }
}

// MFMA GEMM: Out[b][o][n] = sum_c Wb[o][c]*Xb[b][n][c] + bias[o] (+Res)
template<bool RES>
__global__ __launch_bounds__(256) void k_gemm_mfma(const unsigned short* __restrict__ Wb,
                                                   const unsigned short* __restrict__ Xb,
                                                   const float* __restrict__ bias,
                                                   const float* __restrict__ Res,
                                                   float* __restrict__ Out){
  __shared__ unsigned short Al[4096];   // [128 rows(o)][32 k]
  __shared__ unsigned short Bl[4096];   // [128 rows(n)][32 k]
  int b = blockIdx.z;
  int o0 = blockIdx.y*128, n0 = blockIdx.x*128;
  int t = threadIdx.x, w = t >> 6, l = t & 63;
  int wr = w >> 1, wc = w & 1;
  f32x4 acc[4][4] = {};
  const unsigned short* Wt = Wb + (long)(o0 + w*16 + (l>>2))*512 + (l&3)*8;
  const unsigned short* Xt = Xb + ((long)b*N_ + n0 + w*16 + (l>>2))*512 + (l&3)*8;
  int ra = wr*64 + (l & 15);
  int rb = wc*64 + (l & 15);
  int kq = (l >> 4) * 8;
  for(int k0 = 0; k0 < 512; k0 += 32){
    if(k0) __syncthreads();
    GLOAD16(Wt + k0,            &Al[w*512]);
    GLOAD16(Wt + 64*512 + k0,   &Al[2048 + w*512]);
    GLOAD16(Xt + k0,            &Bl[w*512]);
    GLOAD16(Xt + 64*512 + k0,   &Bl[2048 + w*512]);
    __syncthreads();
    bf16x8 af[4], bfr[4];
#pragma unroll
    for(int i=0;i<4;++i){
      af[i]  = *(const bf16x8*)&Al[(ra + i*16)*32 + kq];
      bfr[i] = *(const bf16x8*)&Bl[(rb + i*16)*32 + kq];
    }
#pragma unroll
    for(int mi=0; mi<4; ++mi)
#pragma unroll
      for(int ni=0; ni<4; ++ni)
        acc[mi][ni] = __builtin_amdgcn_mfma_f32_16x16x32_bf16(af[mi], bfr[ni], acc[mi][ni], 0, 0, 0);
  }
  long obase = ((long)b*C_ + o0 + wr*64)*N_ + n0 + wc*64 + (l & 15);
  int r0 = (l >> 4) * 4;
#pragma unroll
  for(int mi=0; mi<4; ++mi){
#pragma unroll
    for(int r=0; r<4; ++r){
      int row = mi*16 + r0 + r;
      float bi = bias[o0 + wr*64 + row];
#pragma unroll
      for(int ni=0; ni<4; ++ni){
        long oi = obase + (long)row*N_ + ni*16;
        float v = acc[mi][ni][r] + bi;
        if(RES) v += Res[oi];
        Out[oi] = v;
      }
    }
  }
}

// K4: cls layernorm + kv projection
__global__ __launch_bounds__(256) void k_cls_kv(const float* __restrict__ xcls,
                                                const float* __restrict__ ncw, const float* __restrict__ ncb,
                                                const float* __restrict__ pkvw, const float* __restrict__ pkvb,
                                                float* __restrict__ kv){
  int b = blockIdx.x;
  int ochunk = blockIdx.y;
  __shared__ float xc[CLS_][C_];
  int t = threadIdx.x, wv = t >> 6, l = t & 63;
  for(int cls = wv; cls < CLS_; cls += 4){
    const float* xr = xcls + ((long)b*CLS_ + cls) * C_;
    float vals[8];
    float s = 0.f, ss = 0.f;
#pragma unroll
    for(int j=0;j<8;++j){ float v = xr[l + 64*j]; vals[j] = v; s += v; ss += v*v; }
    s = wsum(s); ss = wsum(ss);
    float m = s / (float)C_;
    float var = ss / (float)C_ - m*m;
    float inv = 1.0f / sqrtf(var + EPS_);
#pragma unroll
    for(int j=0;j<8;++j){
      int c = l + 64*j;
      xc[cls][c] = (vals[j]-m)*inv*ncw[c] + ncb[c];
    }
  }
  __syncthreads();
  int o = ochunk*128 + (t & 127);
  int cls0 = (t >> 7) * 10;
  float acc[10] = {};
  const float* wrow = pkvw + (long)o * C_;
  for(int k4 = 0; k4 < C_; k4 += 4){
    float4 w4 = *(const float4*)&wrow[k4];
#pragma unroll
    for(int i=0;i<10;++i){
      acc[i] += w4.x*xc[cls0+i][k4] + w4.y*xc[cls0+i][k4+1] + w4.z*xc[cls0+i][k4+2] + w4.w*xc[cls0+i][k4+3];
    }
  }
  float bo = pkvb[o];
#pragma unroll
  for(int i=0;i<10;++i) kv[((long)b*CLS_ + cls0+i)*1024 + o] = acc[i] + bo;
}

// K6: fc1 via MFMA + bn1 + row-normalize. one wave = 16 rows. grid 256
__global__ __launch_bounds__(256) void k_fc1_mfma(const unsigned short* __restrict__ amapb,
                                                  const unsigned short* __restrict__ w1b,
                                                  const float* __restrict__ bias,
                                                  const float* __restrict__ g1, const float* __restrict__ b1,
                                                  float* __restrict__ xf, unsigned short* __restrict__ xub,
                                                  float* __restrict__ sq){
  int t = threadIdx.x, w = t >> 6, l = t & 63;
  long row0 = ((long)blockIdx.x*4 + w)*16;
  int lr = l & 15, lk = l >> 4;
  bf16x8 ay[3];
  const unsigned short* arow = amapb + (row0 + lr)*96 + lk*8;
#pragma unroll
  for(int ks=0; ks<3; ++ks) ay[ks] = *(const bf16x8*)&arow[ks*32];
  f32x4 acc[5] = {};
  const unsigned short* wrow = w1b + (long)lr*96 + lk*8;
#pragma unroll
  for(int ks=0; ks<3; ++ks){
#pragma unroll
    for(int ct=0; ct<5; ++ct){
      bf16x8 bw = *(const bf16x8*)&wrow[ct*16*96 + ks*32];
      acc[ct] = __builtin_amdgcn_mfma_f32_16x16x32_bf16(ay[ks], bw, acc[ct], 0, 0, 0);
    }
  }
  float v[5][4];
  float ssq[4] = {0.f,0.f,0.f,0.f};
#pragma unroll
  for(int ct=0; ct<5; ++ct){
    int o = ct*16 + lr;
    float bi = bias[o], ga = g1[o]*BNS_, bb = b1[o];
#pragma unroll
    for(int i=0;i<4;++i){
      float vv = (acc[ct][i] + bi)*ga + bb;
      v[ct][i] = vv;
      ssq[i] += vv*vv;
    }
  }
#pragma unroll
  for(int d=1; d<16; d<<=1){
#pragma unroll
    for(int i=0;i<4;++i) ssq[i] += __shfl_xor(ssq[i], d);
  }
#pragma unroll
  for(int i=0;i<4;++i){
    long row = row0 + lk*4 + i;
    float invn = 1.0f / fmaxf(sqrtf(ssq[i]), 1e-12f);
#pragma unroll
    for(int ct=0; ct<5; ++ct){
      int o = ct*16 + lr;
      xf[row*G_ + o] = v[ct][i];
      xub[row*96 + o] = f2b(v[ct][i]*invn);
    }
    xub[row*96 + 80 + lr] = 0;
    if(lr == 0) sq[row] = ssq[i]*invn*invn;
  }
}

// K8: neg_d via bf16 MFMA: 128x128 tile, K=96 (padded)
__global__ __launch_bounds__(256) void k_negd_mfma(const unsigned short* __restrict__ xub,
                                                   const float* __restrict__ sq,
                                                   float* __restrict__ negd){
  __shared__ unsigned short Al[128*96];
  __shared__ unsigned short Bl[128*96];
  int b = blockIdx.z;
  int n0 = blockIdx.y*128, m0 = blockIdx.x*128;
  int t = threadIdx.x, w = t >> 6, l = t & 63;
  int wr = w >> 1, wc = w & 1;
  const unsigned short* gA = xub + ((long)b*N_ + n0)*96;
  const unsigned short* gB = xub + ((long)b*N_ + m0)*96;
#pragma unroll
  for(int rd=0; rd<6; ++rd){
    int chunk = rd*4 + w;
    GLOAD16(gA + chunk*512 + l*8, &Al[chunk*512]);
    GLOAD16(gB + chunk*512 + l*8, &Bl[chunk*512]);
  }
  __syncthreads();
  f32x4 acc[4][4] = {};
  int ra = wr*64 + (l & 15);
  int rb = wc*64 + (l & 15);
#pragma unroll
  for(int ks=0; ks<3; ++ks){
    int kq = ks*32 + (l >> 4)*8;
    bf16x8 af[4], bfr[4];
#pragma unroll
    for(int i=0;i<4;++i){
      af[i]  = *(const bf16x8*)&Al[(ra + i*16)*96 + kq];
      bfr[i] = *(const bf16x8*)&Bl[(rb + i*16)*96 + kq];
    }
#pragma unroll
    for(int mi=0; mi<4; ++mi)
#pragma unroll
      for(int ni=0; ni<4; ++ni)
        acc[mi][ni] = __builtin_amdgcn_mfma_f32_16x16x32_bf16(af[mi], bfr[ni], acc[mi][ni], 0, 0, 0);
  }
  int r0 = (l >> 4)*4;
  const float* sqb = sq + (long)b*N_;
#pragma unroll
  for(int mi=0; mi<4; ++mi){
#pragma unroll
    for(int r=0; r<4; ++r){
      int n = n0 + wr*64 + mi*16 + r0 + r;
      float sn = sqb[n];
      long row = ((long)b*N_ + n)*N_;
#pragma unroll
      for(int ni=0; ni<4; ++ni){
        int m = m0 + wc*64 + ni*16 + (l & 15);
        negd[row + m] = 2.f*acc[mi][ni][r] - sn - sqb[m];
      }
    }
  }
}

// K9+K10a merged: top-9 per row then gather neighbor-max -> y bf16. one wave per row.
__global__ __launch_bounds__(256) void k_topk_y(const float* __restrict__ negd, const float* __restrict__ xf,
                                                unsigned short* __restrict__ y){
  int t = threadIdx.x, wv = t >> 6, l = t & 63;
  long r = (long)blockIdx.x*4 + wv;
  long b = r >> 10;
  const float* row = negd + r*N_;
  float vals[16];
#pragma unroll
  for(int j=0;j<16;++j) vals[j] = row[l + 64*j];
  int nbs[K_];
#pragma unroll
  for(int p=0; p<K_; ++p){
    float bv = vals[0]; int bj = 0;
#pragma unroll
    for(int j=1;j<16;++j) if(vals[j] > bv){ bv = vals[j]; bj = j; }
    int bm = l + 64*bj;
#pragma unroll
    for(int d=1; d<64; d<<=1){
      float ov = __shfl_xor(bv, d);
      int   om = __shfl_xor(bm, d);
      if(ov > bv || (ov == bv && om < bm)){ bv = ov; bm = om; }
    }
    nbs[p] = bm;
#pragma unroll
    for(int j=0;j<16;++j) if(bm == l + 64*j) vals[j] = -INFINITY;
  }
  const float* frow = xf + r*G_;
  int o2s = (l < 16) ? (64 + l) : 0;
  float f0 = frow[l];
  float f1 = frow[o2s];
  float m0 = -INFINITY, m1 = -INFINITY;
#pragma unroll
  for(int k=0;k<K_;++k){
    const float* nr = xf + ((long)b*N_ + nbs[k])*G_;
    m0 = fmaxf(m0, nr[l]);
    m1 = fmaxf(m1, nr[o2s]);
  }
  unsigned short* yr = y + r*G2_;
  ushort2 u0; u0.x = f2b(f0); u0.y = f2b(m0 - f0);
  *(ushort2*)&yr[2*l] = u0;
  if(l < 16){
    ushort2 u1; u1.x = f2b(f1); u1.y = f2b(m1 - f1);
    *(ushort2*)&yr[128 + 2*l] = u1;
  }
}

// K10b: MFMA mixer + bn2 + gelu + fc2 + bn3 + amap -> goutT
__global__ __launch_bounds__(256) void k_mixer_mfma(const unsigned short* __restrict__ y,
                                                    const unsigned short* __restrict__ w1bd,
                                                    const float* __restrict__ mrb,
                                                    const float* __restrict__ g2, const float* __restrict__ b2,
                                                    const unsigned short* __restrict__ fc2b16,
                                                    const float* __restrict__ fc2bias,
                                                    const float* __restrict__ g3, const float* __restrict__ b3,
                                                    const float* __restrict__ amapT, float* __restrict__ goutT){
  __shared__ unsigned short zl[4][16][G2_];
  int t = threadIdx.x, w = t >> 6, l = t & 63;
  long row0 = ((long)blockIdx.x*4 + w)*16;
  int lr = l & 15, lk = l >> 4;
  bf16x8 ay[5];
  const unsigned short* yrow = y + (row0 + lr)*G2_ + lk*8;
#pragma unroll
  for(int ks=0; ks<5; ++ks) ay[ks] = *(const bf16x8*)&yrow[ks*32];
  f32x4 accz[10] = {};
  const unsigned short* wb = w1bd + (long)lr*G2_ + lk*8;
#pragma unroll
  for(int ks=0; ks<5; ++ks){
#pragma unroll
    for(int ct=0; ct<10; ++ct){
      bf16x8 bw = *(const bf16x8*)&wb[ct*16*G2_ + ks*32];
      accz[ct] = __builtin_amdgcn_mfma_f32_16x16x32_bf16(ay[ks], bw, accz[ct], 0, 0, 0);
    }
  }
#pragma unroll
  for(int ct=0; ct<10; ++ct){
    int o = ct*16 + lr;
    float bi = mrb[o], ga = g2[o]*BNS_, bb = b2[o];
#pragma unroll
    for(int i=0;i<4;++i){
      float v = (accz[ct][i] + bi)*ga + bb;
      float zz = v * 0.5f * (1.0f + erff(v * INVSQRT2_));
      zl[w][lk*4 + i][o] = f2b(zz);
    }
  }
  __syncthreads();
  bf16x8 az[5];
#pragma unroll
  for(int ks=0; ks<5; ++ks) az[ks] = *(const bf16x8*)&zl[w][lr][ks*32 + lk*8];
  f32x4 acc2[5] = {};
  const unsigned short* fb = fc2b16 + (long)lr*G2_ + lk*8;
#pragma unroll
  for(int ks=0; ks<5; ++ks){
#pragma unroll
    for(int ct=0; ct<5; ++ct){
      bf16x8 bw = *(const bf16x8*)&fb[ct*16*G2_ + ks*32];
      acc2[ct] = __builtin_amdgcn_mfma_f32_16x16x32_bf16(az[ks], bw, acc2[ct], 0, 0, 0);
    }
  }
#pragma unroll
  for(int ct=0; ct<5; ++ct){
    int o = ct*16 + lr;
    float bi = fc2bias[o], ga = g3[o]*BNS_, bb = b3[o];
#pragma unroll
    for(int i=0;i<4;++i){
      long row = row0 + lk*4 + i;
      float v = (acc2[ct][i] + bi)*ga + bb + amapT[row*G_ + o];
      goutT[row*G_ + o] = v;
    }
  }
}

// K12: per-thread softmax + MFMA PV -> bf16 aob[b][n][c]
__global__ __launch_bounds__(256) void k_softmax_pv(const float* __restrict__ goutT, const float* __restrict__ kv,
                                                    unsigned short* __restrict__ aob){
  int bh = blockIdx.x; int b = bh >> 2, h = bh & 3;
  int n0 = blockIdx.y * 64;
  __shared__ unsigned short Vt[128*32];   // [d][cls-pad32]
  __shared__ unsigned short Pl[64*40];    // [n][cls-pad32, stride 40]
  __shared__ unsigned short Os[64*132];   // [n][d, stride 132]
  int t = threadIdx.x, w = t >> 6, l = t & 63;
  if(t < 128){
    int d = t;
    const float* vb = kv + ((long)b*CLS_)*1024 + C_ + h*HD_ + d;
#pragma unroll
    for(int cls=0; cls<CLS_; ++cls) Vt[d*32+cls] = f2b(vb[(long)cls*1024]);
#pragma unroll
    for(int cls=CLS_; cls<32; ++cls) Vt[d*32+cls] = 0;
  }
  if(t < 64){
    int n = n0 + t;
    const float* gr = goutT + ((long)b*N_ + n)*G_ + h*CLS_;
    float x[CLS_];
    float mx = -INFINITY;
#pragma unroll
    for(int cls=0; cls<CLS_; ++cls){ x[cls] = gr[cls]; mx = fmaxf(mx, x[cls]); }
    float s = 0.f;
#pragma unroll
    for(int cls=0; cls<CLS_; ++cls){ x[cls] = expf(x[cls]-mx); s += x[cls]; }
    float inv = 1.0f / s;
#pragma unroll
    for(int cls=0; cls<CLS_; ++cls) Pl[t*40+cls] = f2b(x[cls]*inv);
#pragma unroll
    for(int cls=CLS_; cls<32; ++cls) Pl[t*40+cls] = 0;
  }
  __syncthreads();
  int lr = l & 15, kq = (l >> 4)*8;
  f32x4 acc[4][2] = {};
  bf16x8 af[4], bf2[2];
#pragma unroll
  for(int rt=0; rt<4; ++rt) af[rt] = *(const bf16x8*)&Pl[(rt*16+lr)*40 + kq];
#pragma unroll
  for(int ci=0; ci<2; ++ci) bf2[ci] = *(const bf16x8*)&Vt[((2*w+ci)*16+lr)*32 + kq];
#pragma unroll
  for(int rt=0; rt<4; ++rt)
#pragma unroll
    for(int ci=0; ci<2; ++ci)
      acc[rt][ci] = __builtin_amdgcn_mfma_f32_16x16x32_bf16(af[rt], bf2[ci], acc[rt][ci], 0, 0, 0);
  int r0 = (l >> 4)*4;
#pragma unroll
  for(int rt=0; rt<4; ++rt)
#pragma unroll
    for(int ci=0; ci<2; ++ci)
#pragma unroll
      for(int i=0; i<4; ++i)
        Os[(rt*16 + r0 + i)*132 + (2*w+ci)*16 + lr] = f2b(acc[rt][ci][i]);
  __syncthreads();
  unsigned short* ob = aob + ((long)b*N_ + n0)*C_ + h*HD_;
#pragma unroll
  for(int j=0; j<8; ++j){
    int idx = t + 256*j;
    int row = idx >> 5, ch = idx & 31;
    *(ushort4*)&ob[(long)row*C_ + ch*4] =
        *(const ushort4*)&Os[row*132 + ch*4];
  }
}

extern "C" void kernel_launch(void* const* d_in, const int* in_sizes, int n_in,
                              void* d_out, int out_size, void* d_ws, size_t ws_size,
                              hipStream_t stream){
  const float* x_cls   = (const float*)d_in[0];
  const float* x_patch = (const float*)d_in[1];
  const float* norm_x_w = (const float*)d_in[2];
  const float* norm_x_b = (const float*)d_in[3];
  const float* pq_w  = (const float*)d_in[4];
  const float* pq_b  = (const float*)d_in[5];
  const float* ncls_w = (const float*)d_in[6];
  const float* ncls_b = (const float*)d_in[7];
  const float* pkv_w = (const float*)d_in[8];
  const float* pkv_b = (const float*)d_in[9];
  const float* fc1_w = (const float*)d_in[10];
  const float* fc1_b = (const float*)d_in[11];
  const float* bn1_g = (const float*)d_in[12];
  const float* bn1_b = (const float*)d_in[13];
  const float* mr_w  = (const float*)d_in[14];
  const float* mr_b  = (const float*)d_in[15];
  const float* bn2_g = (const float*)d_in[16];
  const float* bn2_b = (const float*)d_in[17];
  const float* fc2_w = (const float*)d_in[18];
  const float* fc2_b = (const float*)d_in[19];
  const float* bn3_g = (const float*)d_in[20];
  const float* bn3_b = (const float*)d_in[21];
  const float* proj_w = (const float*)d_in[22];
  const float* proj_b = (const float*)d_in[23];

  float* ws = (float*)d_ws;
  float* part   = ws + OFF_PART;
  float* stats  = ws + OFF_STATS;
  float* ebb    = ws + OFF_EBB;
  float* kvbuf  = ws + OFF_KV;
  float* amapT  = ws + OFF_AMAPT;
  float* xf     = ws + OFF_XF;
  float* sqbuf  = ws + OFF_SQ;
  float* negd   = ws + OFF_NEGD;
  float* goutT  = ws + OFF_GOUTT;
  float* pbuf   = ws + OFF_PB;
  unsigned short* Eb     = (unsigned short*)(ws + OFF_EB);
  unsigned short* xub    = (unsigned short*)(ws + OFF_XUB);
  unsigned short* w1bd   = (unsigned short*)(ws + OFF_W1BD);
  unsigned short* fc2b16 = (unsigned short*)(ws + OFF_FC2B);
  unsigned short* ybuf   = (unsigned short*)(ws + OFF_Y);
  unsigned short* amapb  = (unsigned short*)(ws + OFF_AMAPB);
  unsigned short* fc1b16 = (unsigned short*)(ws + OFF_FC1B);
  unsigned short* aob = (unsigned short*)(ws + OFF_NEGD);   // overlay: negd dead after topk_y
  unsigned short* wpb = (unsigned short*)(ws + OFF_WPB);
  float* out = (float*)d_out;

  k_stats_partial<<<1024, 256, 0, stream>>>(x_patch, part);
  k_stats_final<<<16, 64, 0, stream>>>(part, stats);
  k_cls_kv<<<dim3(16,8), 256, 0, stream>>>(x_cls, ncls_w, ncls_b, pkv_w, pkv_b, kvbuf);
  k_eprep<<<dim3(16,5,8), 256, 0, stream>>>(kvbuf, pq_w, pq_b, stats, norm_x_w, norm_x_b, Eb, ebb, pbuf);
  k_wprep<<<576, 256, 0, stream>>>(proj_w, wpb, mr_w, fc2_w, fc1_w, w1bd, fc2b16, fc1b16);
  k_amap_gemm<<<dim3(16,16), 256, 0, stream>>>(Eb, x_patch, ebb, pbuf, amapT, amapb);
  k_fc1_mfma<<<256, 256, 0, stream>>>(amapb, fc1b16, fc1_b, bn1_g, bn1_b, xf, xub, sqbuf);
  k_negd_mfma<<<dim3(8,8,16), 256, 0, stream>>>(xub, sqbuf, negd);
  k_topk_y<<<4096, 256, 0, stream>>>(negd, xf, ybuf);
  k_mixer_mfma<<<256, 256, 0, stream>>>(ybuf, w1bd, mr_b, bn2_g, bn2_b,
                                        fc2b16, fc2_b, bn3_g, bn3_b, amapT, goutT);
  k_softmax_pv<<<dim3(64,16), 256, 0, stream>>>(goutT, kvbuf, aob);
  k_gemm_mfma<true><<<dim3(8,4,16), 256, 0, stream>>>(wpb, aob, proj_b, x_patch, out);
}

// Round 9
// 174.269 us; speedup vs baseline: 3.3272x; 1.0409x over previous
//
#include <hip/hip_runtime.h>
#include <math.h>

#define DI __device__ __forceinline__

constexpr int B_ = 16, CLS_ = 20, C_ = 512, H_ = 4, HD_ = 128, N_ = 1024, G_ = 80, G2_ = 160, K_ = 9;
constexpr float EPS_ = 1e-5f;
constexpr float BNS_ = 0.9999950000374997f;     // 1/sqrt(1+1e-5)
constexpr float SCALE_ = 0.08838834764831845f;  // 128^-0.5
constexpr float INVSQRT2_ = 0.7071067811865475f;

typedef __attribute__((ext_vector_type(8))) short bf16x8;
typedef __attribute__((ext_vector_type(4))) float f32x4;

// ---- workspace layout (float slots) ----
constexpr long OFF_PART  = 0;                      // 2048
constexpr long OFF_EB    = 4096;                   // E bf16 [16][128][512] = 524288 slots
constexpr long OFF_EBB   = OFF_EB    + 524288;     // 1280 fp32
constexpr long OFF_KV    = OFF_EBB   + 2048;       // 16*20*1024
constexpr long OFF_AMAPT = OFF_KV    + 327680;     // 16*1024*80 fp32
constexpr long OFF_XF    = OFF_AMAPT + 1310720;
constexpr long OFF_XUB   = OFF_XF    + 1310720;    // bf16 16*1024*96 = 786432 slots
constexpr long OFF_W1BD  = OFF_XUB   + 786432;     // 16384
constexpr long OFF_FC2B  = OFF_W1BD  + 16384;      // 8192
constexpr long OFF_SQ    = OFF_FC2B  + 8192;       // 16384
constexpr long OFF_NEGD  = OFF_SQ    + 16384;      // 16*1024*1024 fp32; overlays aob (late)
constexpr long OFF_GOUTT = OFF_NEGD  + 16777216 + 147456;  // 1310720
constexpr long OFF_WPB   = OFF_GOUTT + 1310720;    // 131072 (proj_w bf16)
constexpr long OFF_Y     = OFF_WPB   + 131072;     // 1310720
constexpr long OFF_FC1B  = OFF_Y     + 1310720;    // fc1_w bf16 [80][96] -> 4096 slots
constexpr long OFF_PB    = OFF_FC1B  + 4096;       // bias partials [16][8][80] -> 10240

DI float wsum(float v){
#pragma unroll
  for(int d=1; d<64; d<<=1) v += __shfl_xor(v, d);
  return v;
}
DI unsigned short f2b(float f){
  unsigned u = __float_as_uint(f);
  unsigned r = (u + 0x7FFFu + ((u >> 16) & 1u)) >> 16;
  return (unsigned short)r;
}

#define GLOAD16(g, s) __builtin_amdgcn_global_load_lds((const __attribute__((address_space(1))) void*)(g), \
                        (__attribute__((address_space(3))) void*)(s), 16, 0, 0)

// K_pre: fused independent prologue.
// blocks [0,1024): x_patch partial sums ; [1024,1152): cls LN + kv proj ; [1152,1728): weight conversions
__global__ __launch_bounds__(256) void k_pre(const float* __restrict__ x, float* __restrict__ part,
                                             const float* __restrict__ xcls,
                                             const float* __restrict__ ncw, const float* __restrict__ ncb,
                                             const float* __restrict__ pkvw, const float* __restrict__ pkvb,
                                             float* __restrict__ kv,
                                             const float* __restrict__ projw, unsigned short* __restrict__ wpb,
                                             const float* __restrict__ mrw, const float* __restrict__ fc2w,
                                             const float* __restrict__ fc1w,
                                             unsigned short* __restrict__ w1bd, unsigned short* __restrict__ fc2b16,
                                             unsigned short* __restrict__ fc1b16){
  __shared__ float sh[CLS_*C_];       // 40 KB, aliased per branch
  int blk = blockIdx.x, t = threadIdx.x;
  if(blk < 1024){
    const float4* xp = (const float4*)x;
    long base4 = (long)blk * 2048;
    float s = 0.f, ss = 0.f;
#pragma unroll
    for(int j=0;j<8;++j){
      float4 v = xp[base4 + t + 256*j];
      s  += v.x + v.y + v.z + v.w;
      ss += v.x*v.x + v.y*v.y + v.z*v.z + v.w*v.w;
    }
    s = wsum(s); ss = wsum(ss);
    int wv = t >> 6;
    if((t & 63) == 0){ sh[wv] = s; sh[4+wv] = ss; }
    __syncthreads();
    if(t == 0){
      part[blk*2]   = sh[0]+sh[1]+sh[2]+sh[3];
      part[blk*2+1] = sh[4]+sh[5]+sh[6]+sh[7];
    }
    return;
  }
  if(blk < 1152){
    int idx = blk - 1024;
    int b = idx >> 3, ochunk = idx & 7;
    float (*xc)[C_] = (float(*)[C_])sh;
    int wv = t >> 6, l = t & 63;
    for(int cls = wv; cls < CLS_; cls += 4){
      const float* xr = xcls + ((long)b*CLS_ + cls) * C_;
      float vals[8];
      float s = 0.f, ss = 0.f;
#pragma unroll
      for(int j=0;j<8;++j){ float v = xr[l + 64*j]; vals[j] = v; s += v; ss += v*v; }
      s = wsum(s); ss = wsum(ss);
      float m = s / (float)C_;
      float var = ss / (float)C_ - m*m;
      float inv = 1.0f / sqrtf(var + EPS_);
#pragma unroll
      for(int j=0;j<8;++j){
        int c = l + 64*j;
        xc[cls][c] = (vals[j]-m)*inv*ncw[c] + ncb[c];
      }
    }
    __syncthreads();
    int o = ochunk*128 + (t & 127);
    int cls0 = (t >> 7) * 10;
    float acc[10] = {};
    const float* wrow = pkvw + (long)o * C_;
    for(int k4 = 0; k4 < C_; k4 += 4){
      float4 w4 = *(const float4*)&wrow[k4];
#pragma unroll
      for(int i=0;i<10;++i){
        acc[i] += w4.x*xc[cls0+i][k4] + w4.y*xc[cls0+i][k4+1] + w4.z*xc[cls0+i][k4+2] + w4.w*xc[cls0+i][k4+3];
      }
    }
    float bo = pkvb[o];
#pragma unroll
    for(int i=0;i<10;++i) kv[((long)b*CLS_ + cls0+i)*1024 + o] = acc[i] + bo;
    return;
  }
  int blk2 = blk - 1152;
  if(blk2 < 256){
    long i = (long)blk2*256 + t;
    float4 v = ((const float4*)projw)[i];
    uint2 o;
    o.x = (unsigned)f2b(v.x) | ((unsigned)f2b(v.y) << 16);
    o.y = (unsigned)f2b(v.z) | ((unsigned)f2b(v.w) << 16);
    ((uint2*)wpb)[i] = o;
    return;
  }
  int row = blk2 - 256;
  if(row < 160){
    if(t < 160){
      unsigned short v = 0;
      if(t/40 == row/40) v = f2b(mrw[row*40 + (t % 40)]);
      w1bd[row*160 + t] = v;
    }
  } else if(row < 240){
    if(t < 160) fc2b16[(row-160)*160 + t] = f2b(fc2w[(long)(row-160)*160 + t]);
  } else if(row < 320){
    int r = row - 240;
    if(t < 96) fc1b16[r*96 + t] = (t < G_) ? f2b(fc1w[(long)r*G_ + t]) : (unsigned short)0;
  }
}

// E prep v4: inline batch stats from part; folds patch-norm affine into E' and bias partials.
__global__ __launch_bounds__(256) void k_eprep(const float* __restrict__ kv, const float* __restrict__ pqw,
                                               const float* __restrict__ pqb, const float* __restrict__ partbuf,
                                               const float* __restrict__ nw, const float* __restrict__ nbv,
                                               unsigned short* __restrict__ Eb, float* __restrict__ ebb,
                                               float* __restrict__ pb){
  int b = blockIdx.x, hh = blockIdx.y, cch = blockIdx.z, t = threadIdx.x;
  if(hh == 4){
    if(cch == 0){
      unsigned* z = (unsigned*)(Eb + ((long)b*128 + 80)*512);
      for(int i=t; i<12288; i+=256) z[i] = 0;
    }
    return;
  }
  __shared__ float sst[2];
  __shared__ float key[CLS_][HD_];      // 10 KB
  __shared__ float part[4][CLS_][64];   // 20 KB
  if(t < 64){
    float s  = partbuf[(b*64+t)*2];
    float ss = partbuf[(b*64+t)*2+1];
    s = wsum(s); ss = wsum(ss);
    if(t == 0){
      const float cnt = (float)(C_ * N_);
      float m = s / cnt;
      sst[0] = m;
      sst[1] = 1.0f / sqrtf(ss / cnt - m*m + EPS_);
    }
  }
  int h = hh, c0 = cch*64;
  for(int i=t; i<CLS_*HD_; i+=256){
    int cls = i >> 7, d = i & 127;
    key[cls][d] = kv[((long)b*CLS_+cls)*1024 + h*HD_ + d];
  }
  __syncthreads();
  float m = sst[0], inv = sst[1];
  int c = t & 63, ds = t >> 6;
  float acc[CLS_] = {};
  const float* wp = pqw + ((long)(h*HD_ + ds*32))*C_ + c0 + c;
#pragma unroll 8
  for(int di=0; di<32; ++di){
    float wv = wp[(long)di*C_];
#pragma unroll
    for(int cls=0; cls<CLS_; ++cls) acc[cls] += key[cls][ds*32+di]*wv;
  }
#pragma unroll
  for(int cls=0; cls<CLS_; ++cls) part[ds][cls][c] = acc[cls];
  __syncthreads();
  for(int i=t; i<CLS_*64; i+=256){
    int cls = i >> 6, cc = i & 63;
    float v = (part[0][cls][cc]+part[1][cls][cc]+part[2][cls][cc]+part[3][cls][cc]) * SCALE_;
    int cg = c0 + cc;
    float a = inv * nw[cg];
    float bbv = nbv[cg] - m*a;
    Eb[((long)b*128 + h*CLS_ + cls)*512 + cg] = f2b(v*a);
    part[0][cls][cc] = v*bbv;           // exclusive slot: safe read-then-write
  }
  __syncthreads();
  if(t < CLS_){
    float s = 0.f;
    for(int cc=0; cc<64; ++cc) s += part[0][t][cc];
    pb[((long)b*8 + cch)*G_ + t < 0 ? 0 : ((long)b*8 + cch)*G_ + h*CLS_ + t] = s;   // (see note: plain index below)
  }
  if(cch == 0 && t >= 64 && t < 64 + CLS_){
    int tt = t - 64;
    float bacc = 0.f;
    for(int d=0; d<HD_; ++d) bacc += key[tt][d]*pqb[h*HD_+d];
    ebb[b*G_ + h*CLS_ + tt] = bacc*SCALE_;
  }
}

// amap GEMM + fused fc1: reads x_patch directly; writes amapT fp32, xf, xub(bf16 K-pad 96), sq
__global__ __launch_bounds__(256) void k_amap_fc1(const unsigned short* __restrict__ Eb,
                                                  const float* __restrict__ xp,
                                                  const float* __restrict__ ebb,
                                                  const float* __restrict__ pb,
                                                  const unsigned short* __restrict__ w1b,
                                                  const float* __restrict__ f1bias,
                                                  const float* __restrict__ g1, const float* __restrict__ b1,
                                                  float* __restrict__ amapT,
                                                  float* __restrict__ xf, unsigned short* __restrict__ xub,
                                                  float* __restrict__ sq){
  __shared__ unsigned short Xl[64*520];   // X strip; later overlaid by A1[64][96]
  __shared__ unsigned short Bgl[4096];
  unsigned short* A1 = Xl;
  int b = blockIdx.y, n0 = blockIdx.x*64;
  int t = threadIdx.x, w = t >> 6, l = t & 63;
  int wr = w >> 1, wc = w & 1;
  {
    int nb = t & 7, cl = t >> 3;
    const float* xb = xp + (long)b*C_*N_ + n0 + nb*8;
#pragma unroll 4
    for(int pass=0; pass<16; ++pass){
      int c = pass*32 + cl;
      const float* src = xb + (long)c*N_;
      float4 v0 = *(const float4*)src;
      float4 v1 = *(const float4*)(src+4);
      int base = (nb*8)*520 + c;
      Xl[base         ] = f2b(v0.x);
      Xl[base + 520   ] = f2b(v0.y);
      Xl[base + 520*2 ] = f2b(v0.z);
      Xl[base + 520*3 ] = f2b(v0.w);
      Xl[base + 520*4 ] = f2b(v1.x);
      Xl[base + 520*5 ] = f2b(v1.y);
      Xl[base + 520*6 ] = f2b(v1.z);
      Xl[base + 520*7 ] = f2b(v1.w);
    }
  }
  __syncthreads();
  f32x4 acc[2][4] = {};
  const unsigned short* Bt = Eb + ((long)b*128 + w*16 + (l>>2))*512 + (l&3)*8;
  int ra = wr*32 + (l & 15);
  int rb = wc*64 + (l & 15);
  int kq = (l >> 4) * 8;
  for(int k0 = 0; k0 < 512; k0 += 32){
    if(k0) __syncthreads();
    GLOAD16(Bt + k0,          &Bgl[w*512]);
    GLOAD16(Bt + 64*512 + k0, &Bgl[2048 + w*512]);
    __syncthreads();
    bf16x8 af[2], bfr[4];
#pragma unroll
    for(int rt=0; rt<2; ++rt) af[rt]  = *(const bf16x8*)&Xl[(ra + rt*16)*520 + k0 + kq];
#pragma unroll
    for(int ct=0; ct<4; ++ct) bfr[ct] = *(const bf16x8*)&Bgl[(rb + ct*16)*32 + kq];
#pragma unroll
    for(int rt=0; rt<2; ++rt)
#pragma unroll
      for(int ct=0; ct<4; ++ct)
        acc[rt][ct] = __builtin_amdgcn_mfma_f32_16x16x32_bf16(af[rt], bfr[ct], acc[rt][ct], 0, 0, 0);
  }
  float bias4[4];
#pragma unroll
  for(int ct=0; ct<4; ++ct){
    int g = wc*64 + ct*16 + (l & 15);
    float bi = 0.f;
    if(g < G_){
      bi = ebb[b*G_ + g];
#pragma unroll
      for(int cc=0; cc<8; ++cc) bi += pb[((long)b*8 + cc)*G_ + g];
    }
    bias4[ct] = bi;
  }
  __syncthreads();                        // all Xl fragment reads done before A1 overlay
  int r0 = (l >> 4)*4;
#pragma unroll
  for(int rt=0; rt<2; ++rt){
#pragma unroll
    for(int r=0; r<4; ++r){
      int lrow = wr*32 + rt*16 + r0 + r;
      long rowb = ((long)b*N_ + n0 + lrow)*G_;
#pragma unroll
      for(int ct=0; ct<4; ++ct){
        int g = wc*64 + ct*16 + (l & 15);
        if(g < G_){
          float val = acc[rt][ct][r] + bias4[ct];
          amapT[rowb + g] = val;
          A1[lrow*96 + g] = f2b(val);
        } else if(g < 96){
          A1[lrow*96 + g] = 0;
        }
      }
    }
  }
  __syncthreads();
  // fused fc1: wave w owns local rows w*16 .. w*16+15
  int lr = l & 15, lk = l >> 4;
  bf16x8 ay[3];
  const unsigned short* arow = &A1[(w*16 + lr)*96 + lk*8];
#pragma unroll
  for(int ks=0; ks<3; ++ks) ay[ks] = *(const bf16x8*)&arow[ks*32];
  f32x4 acc5[5] = {};
  const unsigned short* wrow = w1b + (long)lr*96 + lk*8;
#pragma unroll
  for(int ks=0; ks<3; ++ks){
#pragma unroll
    for(int ct=0; ct<5; ++ct){
      bf16x8 bw = *(const bf16x8*)&wrow[ct*16*96 + ks*32];
      acc5[ct] = __builtin_amdgcn_mfma_f32_16x16x32_bf16(ay[ks], bw, acc5[ct], 0, 0, 0);
    }
  }
  float v[5][4];
  float ssq[4] = {0.f,0.f,0.f,0.f};
#pragma unroll
  for(int ct=0; ct<5; ++ct){
    int o = ct*16 + lr;
    float bi = f1bias[o], ga = g1[o]*BNS_, bb = b1[o];
#pragma unroll
    for(int i=0;i<4;++i){
      float vv = (acc5[ct][i] + bi)*ga + bb;
      v[ct][i] = vv;
      ssq[i] += vv*vv;
    }
  }
#pragma unroll
  for(int d=1; d<16; d<<=1){
#pragma unroll
    for(int i=0;i<4;++i) ssq[i] += __shfl_xor(ssq[i], d);
  }
  long row0g = (long)b*N_ + n0 + w*16;
#pragma unroll
  for(int i=0;i<4;++i){
    long row = row0g + lk*4 + i;
    float invn = 1.0f / fmaxf(sqrtf(ssq[i]), 1e-12f);
#pragma unroll
    for(int ct=0; ct<5; ++ct){
      int o = ct*16 + lr;
      xf[row*G_ + o] = v[ct][i];
      xub[row*96 + o] = f2b(v[ct][i]*invn);
    }
    xub[row*96 + 80 + lr] = 0;
    if(lr == 0) sq[row] = ssq[i]*invn*invn;
  }
}

// MFMA GEMM: Out[b][o][n] = sum_c Wb[o][c]*Xb[b][n][c] + bias[o] (+Res)
template<bool RES>
__global__ __launch_bounds__(256) void k_gemm_mfma(const unsigned short* __restrict__ Wb,
                                                   const unsigned short* __restrict__ Xb,
                                                   const float* __restrict__ bias,
                                                   const float* __restrict__ Res,
                                                   float* __restrict__ Out){
  __shared__ unsigned short Al[4096];
  __shared__ unsigned short Bl[4096];
  int b = blockIdx.z;
  int o0 = blockIdx.y*128, n0 = blockIdx.x*128;
  int t = threadIdx.x, w = t >> 6, l = t & 63;
  int wr = w >> 1, wc = w & 1;
  f32x4 acc[4][4] = {};
  const unsigned short* Wt = Wb + (long)(o0 + w*16 + (l>>2))*512 + (l&3)*8;
  const unsigned short* Xt = Xb + ((long)b*N_ + n0 + w*16 + (l>>2))*512 + (l&3)*8;
  int ra = wr*64 + (l & 15);
  int rb = wc*64 + (l & 15);
  int kq = (l >> 4) * 8;
  for(int k0 = 0; k0 < 512; k0 += 32){
    if(k0) __syncthreads();
    GLOAD16(Wt + k0,            &Al[w*512]);
    GLOAD16(Wt + 64*512 + k0,   &Al[2048 + w*512]);
    GLOAD16(Xt + k0,            &Bl[w*512]);
    GLOAD16(Xt + 64*512 + k0,   &Bl[2048 + w*512]);
    __syncthreads();
    bf16x8 af[4], bfr[4];
#pragma unroll
    for(int i=0;i<4;++i){
      af[i]  = *(const bf16x8*)&Al[(ra + i*16)*32 + kq];
      bfr[i] = *(const bf16x8*)&Bl[(rb + i*16)*32 + kq];
    }
#pragma unroll
    for(int mi=0; mi<4; ++mi)
#pragma unroll
      for(int ni=0; ni<4; ++ni)
        acc[mi][ni] = __builtin_amdgcn_mfma_f32_16x16x32_bf16(af[mi], bfr[ni], acc[mi][ni], 0, 0, 0);
  }
  long obase = ((long)b*C_ + o0 + wr*64)*N_ + n0 + wc*64 + (l & 15);
  int r0 = (l >> 4) * 4;
#pragma unroll
  for(int mi=0; mi<4; ++mi){
#pragma unroll
    for(int r=0; r<4; ++r){
      int row = mi*16 + r0 + r;
      float bi = bias[o0 + wr*64 + row];
#pragma unroll
      for(int ni=0; ni<4; ++ni){
        long oi = obase + (long)row*N_ + ni*16;
        float v = acc[mi][ni][r] + bi;
        if(RES) v += Res[oi];
        Out[oi] = v;
      }
    }
  }
}

// K8: neg_d via bf16 MFMA: 128x128 tile, K=96 (padded)
__global__ __launch_bounds__(256) void k_negd_mfma(const unsigned short* __restrict__ xub,
                                                   const float* __restrict__ sq,
                                                   float* __restrict__ negd){
  __shared__ unsigned short Al[128*96];
  __shared__ unsigned short Bl[128*96];
  int b = blockIdx.z;
  int n0 = blockIdx.y*128, m0 = blockIdx.x*128;
  int t = threadIdx.x, w = t >> 6, l = t & 63;
  int wr = w >> 1, wc = w & 1;
  const unsigned short* gA = xub + ((long)b*N_ + n0)*96;
  const unsigned short* gB = xub + ((long)b*N_ + m0)*96;
#pragma unroll
  for(int rd=0; rd<6; ++rd){
    int chunk = rd*4 + w;
    GLOAD16(gA + chunk*512 + l*8, &Al[chunk*512]);
    GLOAD16(gB + chunk*512 + l*8, &Bl[chunk*512]);
  }
  __syncthreads();
  f32x4 acc[4][4] = {};
  int ra = wr*64 + (l & 15);
  int rb = wc*64 + (l & 15);
#pragma unroll
  for(int ks=0; ks<3; ++ks){
    int kq = ks*32 + (l >> 4)*8;
    bf16x8 af[4], bfr[4];
#pragma unroll
    for(int i=0;i<4;++i){
      af[i]  = *(const bf16x8*)&Al[(ra + i*16)*96 + kq];
      bfr[i] = *(const bf16x8*)&Bl[(rb + i*16)*96 + kq];
    }
#pragma unroll
    for(int mi=0; mi<4; ++mi)
#pragma unroll
      for(int ni=0; ni<4; ++ni)
        acc[mi][ni] = __builtin_amdgcn_mfma_f32_16x16x32_bf16(af[mi], bfr[ni], acc[mi][ni], 0, 0, 0);
  }
  int r0 = (l >> 4)*4;
  const float* sqb = sq + (long)b*N_;
#pragma unroll
  for(int mi=0; mi<4; ++mi){
#pragma unroll
    for(int r=0; r<4; ++r){
      int n = n0 + wr*64 + mi*16 + r0 + r;
      float sn = sqb[n];
      long row = ((long)b*N_ + n)*N_;
#pragma unroll
      for(int ni=0; ni<4; ++ni){
        int m = m0 + wc*64 + ni*16 + (l & 15);
        negd[row + m] = 2.f*acc[mi][ni][r] - sn - sqb[m];
      }
    }
  }
}

// K9: top-9 per row then gather neighbor-max -> y bf16. one wave per row.
__global__ __launch_bounds__(256) void k_topk_y(const float* __restrict__ negd, const float* __restrict__ xf,
                                                unsigned short* __restrict__ y){
  int t = threadIdx.x, wv = t >> 6, l = t & 63;
  long r = (long)blockIdx.x*4 + wv;
  long b = r >> 10;
  const float* row = negd + r*N_;
  float vals[16];
#pragma unroll
  for(int j=0;j<16;++j) vals[j] = row[l + 64*j];
  int nbs[K_];
#pragma unroll
  for(int p=0; p<K_; ++p){
    float bv = vals[0]; int bj = 0;
#pragma unroll
    for(int j=1;j<16;++j) if(vals[j] > bv){ bv = vals[j]; bj = j; }
    int bm = l + 64*bj;
#pragma unroll
    for(int d=1; d<64; d<<=1){
      float ov = __shfl_xor(bv, d);
      int   om = __shfl_xor(bm, d);
      if(ov > bv || (ov == bv && om < bm)){ bv = ov; bm = om; }
    }
    nbs[p] = bm;
#pragma unroll
    for(int j=0;j<16;++j) if(bm == l + 64*j) vals[j] = -INFINITY;
  }
  const float* frow = xf + r*G_;
  int o2s = (l < 16) ? (64 + l) : 0;
  float f0 = frow[l];
  float f1 = frow[o2s];
  float m0 = -INFINITY, m1 = -INFINITY;
#pragma unroll
  for(int k=0;k<K_;++k){
    const float* nr = xf + ((long)b*N_ + nbs[k])*G_;
    m0 = fmaxf(m0, nr[l]);
    m1 = fmaxf(m1, nr[o2s]);
  }
  unsigned short* yr = y + r*G2_;
  ushort2 u0; u0.x = f2b(f0); u0.y = f2b(m0 - f0);
  *(ushort2*)&yr[2*l] = u0;
  if(l < 16){
    ushort2 u1; u1.x = f2b(f1); u1.y = f2b(m1 - f1);
    *(ushort2*)&yr[128 + 2*l] = u1;
  }
}

// K10: MFMA mixer + bn2 + gelu + fc2 + bn3 + amap -> goutT
__global__ __launch_bounds__(256) void k_mixer_mfma(const unsigned short* __restrict__ y,
                                                    const unsigned short* __restrict__ w1bd,
                                                    const float* __restrict__ mrb,
                                                    const float* __restrict__ g2, const float* __restrict__ b2,
                                                    const unsigned short* __restrict__ fc2b16,
                                                    const float* __restrict__ fc2bias,
                                                    const float* __restrict__ g3, const float* __restrict__ b3,
                                                    const float* __restrict__ amapT, float* __restrict__ goutT){
  __shared__ unsigned short zl[4][16][G2_];
  int t = threadIdx.x, w = t >> 6, l = t & 63;
  long row0 = ((long)blockIdx.x*4 + w)*16;
  int lr = l & 15, lk = l >> 4;
  bf16x8 ay[5];
  const unsigned short* yrow = y + (row0 + lr)*G2_ + lk*8;
#pragma unroll
  for(int ks=0; ks<5; ++ks) ay[ks] = *(const bf16x8*)&yrow[ks*32];
  f32x4 accz[10] = {};
  const unsigned short* wb = w1bd + (long)lr*G2_ + lk*8;
#pragma unroll
  for(int ks=0; ks<5; ++ks){
#pragma unroll
    for(int ct=0; ct<10; ++ct){
      bf16x8 bw = *(const bf16x8*)&wb[ct*16*G2_ + ks*32];
      accz[ct] = __builtin_amdgcn_mfma_f32_16x16x32_bf16(ay[ks], bw, accz[ct], 0, 0, 0);
    }
  }
#pragma unroll
  for(int ct=0; ct<10; ++ct){
    int o = ct*16 + lr;
    float bi = mrb[o], ga = g2[o]*BNS_, bb = b2[o];
#pragma unroll
    for(int i=0;i<4;++i){
      float v = (accz[ct][i] + bi)*ga + bb;
      float zz = v * 0.5f * (1.0f + erff(v * INVSQRT2_));
      zl[w][lk*4 + i][o] = f2b(zz);
    }
  }
  __syncthreads();
  bf16x8 az[5];
#pragma unroll
  for(int ks=0; ks<5; ++ks) az[ks] = *(const bf16x8*)&zl[w][lr][ks*32 + lk*8];
  f32x4 acc2[5] = {};
  const unsigned short* fb = fc2b16 + (long)lr*G2_ + lk*8;
#pragma unroll
  for(int ks=0; ks<5; ++ks){
#pragma unroll
    for(int ct=0; ct<5; ++ct){
      bf16x8 bw = *(const bf16x8*)&fb[ct*16*G2_ + ks*32];
      acc2[ct] = __builtin_amdgcn_mfma_f32_16x16x32_bf16(az[ks], bw, acc2[ct], 0, 0, 0);
    }
  }
#pragma unroll
  for(int ct=0; ct<5; ++ct){
    int o = ct*16 + lr;
    float bi = fc2bias[o], ga = g3[o]*BNS_, bb = b3[o];
#pragma unroll
    for(int i=0;i<4;++i){
      long row = row0 + lk*4 + i;
      float v = (acc2[ct][i] + bi)*ga + bb + amapT[row*G_ + o];
      goutT[row*G_ + o] = v;
    }
  }
}

// K12: per-thread softmax + MFMA PV -> bf16 aob[b][n][c]
__global__ __launch_bounds__(256) void k_softmax_pv(const float* __restrict__ goutT, const float* __restrict__ kv,
                                                    unsigned short* __restrict__ aob){
  int bh = blockIdx.x; int b = bh >> 2, h = bh & 3;
  int n0 = blockIdx.y * 64;
  __shared__ unsigned short Vt[128*32];
  __shared__ unsigned short Pl[64*40];
  __shared__ unsigned short Os[64*132];
  int t = threadIdx.x, w = t >> 6, l = t & 63;
  if(t < 128){
    int d = t;
    const float* vb = kv + ((long)b*CLS_)*1024 + C_ + h*HD_ + d;
#pragma unroll
    for(int cls=0; cls<CLS_; ++cls) Vt[d*32+cls] = f2b(vb[(long)cls*1024]);
#pragma unroll
    for(int cls=CLS_; cls<32; ++cls) Vt[d*32+cls] = 0;
  }
  if(t < 64){
    int n = n0 + t;
    const float* gr = goutT + ((long)b*N_ + n)*G_ + h*CLS_;
    float x[CLS_];
    float mx = -INFINITY;
#pragma unroll
    for(int cls=0; cls<CLS_; ++cls){ x[cls] = gr[cls]; mx = fmaxf(mx, x[cls]); }
    float s = 0.f;
#pragma unroll
    for(int cls=0; cls<CLS_; ++cls){ x[cls] = expf(x[cls]-mx); s += x[cls]; }
    float inv = 1.0f / s;
#pragma unroll
    for(int cls=0; cls<CLS_; ++cls) Pl[t*40+cls] = f2b(x[cls]*inv);
#pragma unroll
    for(int cls=CLS_; cls<32; ++cls) Pl[t*40+cls] = 0;
  }
  __syncthreads();
  int lr = l & 15, kq = (l >> 4)*8;
  f32x4 acc[4][2] = {};
  bf16x8 af[4], bf2[2];
#pragma unroll
  for(int rt=0; rt<4; ++rt) af[rt] = *(const bf16x8*)&Pl[(rt*16+lr)*40 + kq];
#pragma unroll
  for(int ci=0; ci<2; ++ci) bf2[ci] = *(const bf16x8*)&Vt[((2*w+ci)*16+lr)*32 + kq];
#pragma unroll
  for(int rt=0; rt<4; ++rt)
#pragma unroll
    for(int ci=0; ci<2; ++ci)
      acc[rt][ci] = __builtin_amdgcn_mfma_f32_16x16x32_bf16(af[rt], bf2[ci], acc[rt][ci], 0, 0, 0);
  int r0 = (l >> 4)*4;
#pragma unroll
  for(int rt=0; rt<4; ++rt)
#pragma unroll
    for(int ci=0; ci<2; ++ci)
#pragma unroll
      for(int i=0; i<4; ++i)
        Os[(rt*16 + r0 + i)*132 + (2*w+ci)*16 + lr] = f2b(acc[rt][ci][i]);
  __syncthreads();
  unsigned short* ob = aob + ((long)b*N_ + n0)*C_ + h*HD_;
#pragma unroll
  for(int j=0; j<8; ++j){
    int idx = t + 256*j;
    int row = idx >> 5, ch = idx & 31;
    *(ushort4*)&ob[(long)row*C_ + ch*4] =
        *(const ushort4*)&Os[row*132 + ch*4];
  }
}

extern "C" void kernel_launch(void* const* d_in, const int* in_sizes, int n_in,
                              void* d_out, int out_size, void* d_ws, size_t ws_size,
                              hipStream_t stream){
  const float* x_cls   = (const float*)d_in[0];
  const float* x_patch = (const float*)d_in[1];
  const float* norm_x_w = (const float*)d_in[2];
  const float* norm_x_b = (const float*)d_in[3];
  const float* pq_w  = (const float*)d_in[4];
  const float* pq_b  = (const float*)d_in[5];
  const float* ncls_w = (const float*)d_in[6];
  const float* ncls_b = (const float*)d_in[7];
  const float* pkv_w = (const float*)d_in[8];
  const float* pkv_b = (const float*)d_in[9];
  const float* fc1_w = (const float*)d_in[10];
  const float* fc1_b = (const float*)d_in[11];
  const float* bn1_g = (const float*)d_in[12];
  const float* bn1_b = (const float*)d_in[13];
  const float* mr_w  = (const float*)d_in[14];
  const float* mr_b  = (const float*)d_in[15];
  const float* bn2_g = (const float*)d_in[16];
  const float* bn2_b = (const float*)d_in[17];
  const float* fc2_w = (const float*)d_in[18];
  const float* fc2_b = (const float*)d_in[19];
  const float* bn3_g = (const float*)d_in[20];
  const float* bn3_b = (const float*)d_in[21];
  const float* proj_w = (const float*)d_in[22];
  const float* proj_b = (const float*)d_in[23];

  float* ws = (float*)d_ws;
  float* part   = ws + OFF_PART;
  float* ebb    = ws + OFF_EBB;
  float* kvbuf  = ws + OFF_KV;
  float* amapT  = ws + OFF_AMAPT;
  float* xf     = ws + OFF_XF;
  float* sqbuf  = ws + OFF_SQ;
  float* negd   = ws + OFF_NEGD;
  float* goutT  = ws + OFF_GOUTT;
  float* pbuf   = ws + OFF_PB;
  unsigned short* Eb     = (unsigned short*)(ws + OFF_EB);
  unsigned short* xub    = (unsigned short*)(ws + OFF_XUB);
  unsigned short* w1bd   = (unsigned short*)(ws + OFF_W1BD);
  unsigned short* fc2b16 = (unsigned short*)(ws + OFF_FC2B);
  unsigned short* ybuf   = (unsigned short*)(ws + OFF_Y);
  unsigned short* fc1b16 = (unsigned short*)(ws + OFF_FC1B);
  unsigned short* aob = (unsigned short*)(ws + OFF_NEGD);   // overlay: negd dead after topk_y
  unsigned short* wpb = (unsigned short*)(ws + OFF_WPB);
  float* out = (float*)d_out;

  k_pre<<<1728, 256, 0, stream>>>(x_patch, part, x_cls, ncls_w, ncls_b, pkv_w, pkv_b, kvbuf,
                                  proj_w, wpb, mr_w, fc2_w, fc1_w, w1bd, fc2b16, fc1b16);
  k_eprep<<<dim3(16,5,8), 256, 0, stream>>>(kvbuf, pq_w, pq_b, part, norm_x_w, norm_x_b, Eb, ebb, pbuf);
  k_amap_fc1<<<dim3(16,16), 256, 0, stream>>>(Eb, x_patch, ebb, pbuf, fc1b16, fc1_b, bn1_g, bn1_b,
                                              amapT, xf, xub, sqbuf);
  k_negd_mfma<<<dim3(8,8,16), 256, 0, stream>>>(xub, sqbuf, negd);
  k_topk_y<<<4096, 256, 0, stream>>>(negd, xf, ybuf);
  k_mixer_mfma<<<256, 256, 0, stream>>>(ybuf, w1bd, mr_b, bn2_g, bn2_b,
                                        fc2b16, fc2_b, bn3_g, bn3_b, amapT, goutT);
  k_softmax_pv<<<dim3(64,16), 256, 0, stream>>>(goutT, kvbuf, aob);
  k_gemm_mfma<true><<<dim3(8,4,16), 256, 0, stream>>>(wpb, aob, proj_b, x_patch, out);
}

// Round 10
// 162.285 us; speedup vs baseline: 3.5729x; 1.0738x over previous
//
#include <hip/hip_runtime.h>
#include <math.h>

#define DI __device__ __forceinline__

constexpr int B_ = 16, CLS_ = 20, C_ = 512, H_ = 4, HD_ = 128, N_ = 1024, G_ = 80, G2_ = 160, K_ = 9;
constexpr float EPS_ = 1e-5f;
constexpr float BNS_ = 0.9999950000374997f;     // 1/sqrt(1+1e-5)
constexpr float SCALE_ = 0.08838834764831845f;  // 128^-0.5
constexpr float INVSQRT2_ = 0.7071067811865475f;

typedef __attribute__((ext_vector_type(8))) short bf16x8;
typedef __attribute__((ext_vector_type(4))) float f32x4;

// ---- workspace layout (float slots) ----
constexpr long OFF_PART  = 0;                      // 2048
constexpr long OFF_EB    = 4096;                   // E bf16 [16][128][512] = 524288 slots
constexpr long OFF_EBB   = OFF_EB    + 524288;     // 1280 fp32
constexpr long OFF_KV    = OFF_EBB   + 2048;       // 16*20*1024 fp32
constexpr long OFF_AMAPT = OFF_KV    + 327680;     // 16*1024*80 fp32
constexpr long OFF_XF    = OFF_AMAPT + 1310720;
constexpr long OFF_XUB   = OFF_XF    + 1310720;    // bf16 16*1024*96 = 786432 slots
constexpr long OFF_W1BD  = OFF_XUB   + 786432;     // 16384
constexpr long OFF_FC2B  = OFF_W1BD  + 16384;      // 8192
constexpr long OFF_SQ    = OFF_FC2B  + 8192;       // 16384
constexpr long OFF_NEGD  = OFF_SQ    + 16384;      // 16*1024*1024 fp32; overlays aob (late)
constexpr long OFF_GOUTT = OFF_NEGD  + 16777216 + 147456;  // 1310720
constexpr long OFF_WPB   = OFF_GOUTT + 1310720;    // 131072 (proj_w bf16)
constexpr long OFF_Y     = OFF_WPB   + 131072;     // 1310720
constexpr long OFF_FC1B  = OFF_Y     + 1310720;    // fc1_w bf16 [80][96] -> 4096
constexpr long OFF_PB    = OFF_FC1B  + 4096;       // bias partials [16][8][80] -> 10240
constexpr long OFF_XCB   = OFF_PB    + 10240;      // cls-LN bf16 [16][32][512] -> 131072
constexpr long OFF_PKVB  = OFF_XCB   + 131072;     // pkv_w bf16 [1024][512] -> 262144

DI float wsum(float v){
#pragma unroll
  for(int d=1; d<64; d<<=1) v += __shfl_xor(v, d);
  return v;
}
DI unsigned short f2b(float f){
  unsigned u = __float_as_uint(f);
  unsigned r = (u + 0x7FFFu + ((u >> 16) & 1u)) >> 16;
  return (unsigned short)r;
}

#define GLOAD16(g, s) __builtin_amdgcn_global_load_lds((const __attribute__((address_space(1))) void*)(g), \
                        (__attribute__((address_space(3))) void*)(s), 16, 0, 0)

// K_pre v2: uniform short blocks, tiny LDS.
// [0,1024): x_patch partial sums ; [1024,1040): cls LN -> xcb bf16 ; [1040,1296): proj_w conv ;
// [1296,1808): pkv_w conv ; [1808,2128): small weights
__global__ __launch_bounds__(256) void k_pre(const float* __restrict__ x, float* __restrict__ part,
                                             const float* __restrict__ xcls,
                                             const float* __restrict__ ncw, const float* __restrict__ ncb,
                                             unsigned short* __restrict__ xcb,
                                             const float* __restrict__ pkvw, unsigned short* __restrict__ pkvb16,
                                             const float* __restrict__ projw, unsigned short* __restrict__ wpb,
                                             const float* __restrict__ mrw, const float* __restrict__ fc2w,
                                             const float* __restrict__ fc1w,
                                             unsigned short* __restrict__ w1bd, unsigned short* __restrict__ fc2b16,
                                             unsigned short* __restrict__ fc1b16){
  __shared__ float rs[4], rss[4];
  int blk = blockIdx.x, t = threadIdx.x;
  if(blk < 1024){
    const float4* xp = (const float4*)x;
    long base4 = (long)blk * 2048;
    float s = 0.f, ss = 0.f;
#pragma unroll
    for(int j=0;j<8;++j){
      float4 v = xp[base4 + t + 256*j];
      s  += v.x + v.y + v.z + v.w;
      ss += v.x*v.x + v.y*v.y + v.z*v.z + v.w*v.w;
    }
    s = wsum(s); ss = wsum(ss);
    int wv = t >> 6;
    if((t & 63) == 0){ rs[wv] = s; rss[wv] = ss; }
    __syncthreads();
    if(t == 0){
      part[blk*2]   = rs[0]+rs[1]+rs[2]+rs[3];
      part[blk*2+1] = rss[0]+rss[1]+rss[2]+rss[3];
    }
    return;
  }
  if(blk < 1040){
    int b = blk - 1024;
    int wv = t >> 6, l = t & 63;
    for(int cls = wv; cls < 32; cls += 4){
      unsigned short* orow = xcb + ((long)b*32 + cls)*512;
      if(cls < CLS_){
        const float* xr = xcls + ((long)b*CLS_ + cls) * C_;
        float vals[8];
        float s = 0.f, ss = 0.f;
#pragma unroll
        for(int j=0;j<8;++j){ float v = xr[l + 64*j]; vals[j] = v; s += v; ss += v*v; }
        s = wsum(s); ss = wsum(ss);
        float m = s / (float)C_;
        float var = ss / (float)C_ - m*m;
        float inv = 1.0f / sqrtf(var + EPS_);
#pragma unroll
        for(int j=0;j<8;++j){
          int c = l + 64*j;
          orow[c] = f2b((vals[j]-m)*inv*ncw[c] + ncb[c]);
        }
      } else {
#pragma unroll
        for(int j=0;j<8;++j) orow[l + 64*j] = 0;
      }
    }
    return;
  }
  if(blk < 1296){
    long i = (long)(blk - 1040)*256 + t;
    float4 v = ((const float4*)projw)[i];
    uint2 o;
    o.x = (unsigned)f2b(v.x) | ((unsigned)f2b(v.y) << 16);
    o.y = (unsigned)f2b(v.z) | ((unsigned)f2b(v.w) << 16);
    ((uint2*)wpb)[i] = o;
    return;
  }
  if(blk < 1808){
    long i = (long)(blk - 1296)*256 + t;      // 131072 float4 = 1024x512
    float4 v = ((const float4*)pkvw)[i];
    uint2 o;
    o.x = (unsigned)f2b(v.x) | ((unsigned)f2b(v.y) << 16);
    o.y = (unsigned)f2b(v.z) | ((unsigned)f2b(v.w) << 16);
    ((uint2*)pkvb16)[i] = o;
    return;
  }
  int row = blk - 1808;
  if(row < 160){
    if(t < 160){
      unsigned short v = 0;
      if(t/40 == row/40) v = f2b(mrw[row*40 + (t % 40)]);
      w1bd[row*160 + t] = v;
    }
  } else if(row < 240){
    if(t < 160) fc2b16[(row-160)*160 + t] = f2b(fc2w[(long)(row-160)*160 + t]);
  } else if(row < 320){
    int r = row - 240;
    if(t < 96) fc1b16[r*96 + t] = (t < G_) ? f2b(fc1w[(long)r*G_ + t]) : (unsigned short)0;
  }
}

// kv projection via MFMA: kv[b][cls][o] = sum_c xcb[b][cls][c]*pkvw[o][c] + pkvb[o]
// grid 128 = (b<<3)|otile ; block 256 = 4 waves, wave owns 32 o-rows x 32 cls
__global__ __launch_bounds__(256) void k_kv_mfma(const unsigned short* __restrict__ xcb,
                                                 const unsigned short* __restrict__ pkvb16,
                                                 const float* __restrict__ pkvb,
                                                 float* __restrict__ kv){
  __shared__ unsigned short Al[4096];   // 128 o-rows x 32 k
  __shared__ unsigned short Bl[1024];   // 32 cls-rows x 32 k
  int b = blockIdx.x >> 3, o0 = (blockIdx.x & 7)*128;
  int t = threadIdx.x, w = t >> 6, l = t & 63;
  f32x4 acc[2][2] = {};
  const unsigned short* At = pkvb16 + (long)(o0 + w*16 + (l>>2))*512 + (l&3)*8;
  const unsigned short* Bt = xcb + ((long)b*32 + w*16 + (l>>2))*512 + (l&3)*8;
  int kq = (l >> 4)*8;
  for(int k0 = 0; k0 < 512; k0 += 32){
    if(k0) __syncthreads();
    GLOAD16(At + k0,          &Al[w*512]);
    GLOAD16(At + 64*512 + k0, &Al[2048 + w*512]);
    if(w < 2) GLOAD16(Bt + k0, &Bl[w*512]);
    __syncthreads();
    bf16x8 af[2], bfr[2];
#pragma unroll
    for(int mi=0; mi<2; ++mi) af[mi]  = *(const bf16x8*)&Al[(w*32 + mi*16 + (l & 15))*32 + kq];
#pragma unroll
    for(int ni=0; ni<2; ++ni) bfr[ni] = *(const bf16x8*)&Bl[(ni*16 + (l & 15))*32 + kq];
#pragma unroll
    for(int mi=0; mi<2; ++mi)
#pragma unroll
      for(int ni=0; ni<2; ++ni)
        acc[mi][ni] = __builtin_amdgcn_mfma_f32_16x16x32_bf16(af[mi], bfr[ni], acc[mi][ni], 0, 0, 0);
  }
  int r0 = (l >> 4)*4;
#pragma unroll
  for(int mi=0; mi<2; ++mi){
#pragma unroll
    for(int r=0; r<4; ++r){
      int o = o0 + w*32 + mi*16 + r0 + r;
      float bi = pkvb[o];
#pragma unroll
      for(int ni=0; ni<2; ++ni){
        int cls = ni*16 + (l & 15);
        if(cls < CLS_) kv[((long)b*CLS_ + cls)*1024 + o] = acc[mi][ni][r] + bi;
      }
    }
  }
}

// E prep: inline batch stats from part; folds patch-norm affine into E' and bias partials.
__global__ __launch_bounds__(256) void k_eprep(const float* __restrict__ kv, const float* __restrict__ pqw,
                                               const float* __restrict__ pqb, const float* __restrict__ partbuf,
                                               const float* __restrict__ nw, const float* __restrict__ nbv,
                                               unsigned short* __restrict__ Eb, float* __restrict__ ebb,
                                               float* __restrict__ pb){
  int b = blockIdx.x, hh = blockIdx.y, cch = blockIdx.z, t = threadIdx.x;
  if(hh == 4){
    if(cch == 0){
      unsigned* z = (unsigned*)(Eb + ((long)b*128 + 80)*512);
      for(int i=t; i<12288; i+=256) z[i] = 0;
    }
    return;
  }
  __shared__ float sst[2];
  __shared__ float key[CLS_][HD_];      // 10 KB
  __shared__ float part[4][CLS_][64];   // 20 KB
  if(t < 64){
    float s  = partbuf[(b*64+t)*2];
    float ss = partbuf[(b*64+t)*2+1];
    s = wsum(s); ss = wsum(ss);
    if(t == 0){
      const float cnt = (float)(C_ * N_);
      float m = s / cnt;
      sst[0] = m;
      sst[1] = 1.0f / sqrtf(ss / cnt - m*m + EPS_);
    }
  }
  int h = hh, c0 = cch*64;
  for(int i=t; i<CLS_*HD_; i+=256){
    int cls = i >> 7, d = i & 127;
    key[cls][d] = kv[((long)b*CLS_+cls)*1024 + h*HD_ + d];
  }
  __syncthreads();
  float m = sst[0], inv = sst[1];
  int c = t & 63, ds = t >> 6;
  float acc[CLS_] = {};
  const float* wp = pqw + ((long)(h*HD_ + ds*32))*C_ + c0 + c;
#pragma unroll 8
  for(int di=0; di<32; ++di){
    float wv = wp[(long)di*C_];
#pragma unroll
    for(int cls=0; cls<CLS_; ++cls) acc[cls] += key[cls][ds*32+di]*wv;
  }
#pragma unroll
  for(int cls=0; cls<CLS_; ++cls) part[ds][cls][c] = acc[cls];
  __syncthreads();
  for(int i=t; i<CLS_*64; i+=256){
    int cls = i >> 6, cc = i & 63;
    float v = (part[0][cls][cc]+part[1][cls][cc]+part[2][cls][cc]+part[3][cls][cc]) * SCALE_;
    int cg = c0 + cc;
    float a = inv * nw[cg];
    float bbv = nbv[cg] - m*a;
    Eb[((long)b*128 + h*CLS_ + cls)*512 + cg] = f2b(v*a);
    part[0][cls][cc] = v*bbv;           // exclusive slot: safe read-then-write
  }
  __syncthreads();
  if(t < CLS_){
    float s = 0.f;
    for(int cc=0; cc<64; ++cc) s += part[0][t][cc];
    pb[((long)b*8 + cch)*G_ + h*CLS_ + t] = s;
  }
  if(cch == 0 && t >= 64 && t < 64 + CLS_){
    int tt = t - 64;
    float bacc = 0.f;
    for(int d=0; d<HD_; ++d) bacc += key[tt][d]*pqb[h*HD_+d];
    ebb[b*G_ + h*CLS_ + tt] = bacc*SCALE_;
  }
}

// amap GEMM + fused fc1
__global__ __launch_bounds__(256) void k_amap_fc1(const unsigned short* __restrict__ Eb,
                                                  const float* __restrict__ xp,
                                                  const float* __restrict__ ebb,
                                                  const float* __restrict__ pb,
                                                  const unsigned short* __restrict__ w1b,
                                                  const float* __restrict__ f1bias,
                                                  const float* __restrict__ g1, const float* __restrict__ b1,
                                                  float* __restrict__ amapT,
                                                  float* __restrict__ xf, unsigned short* __restrict__ xub,
                                                  float* __restrict__ sq){
  __shared__ unsigned short Xl[64*520];   // X strip; later overlaid by A1[64][96]
  __shared__ unsigned short Bgl[4096];
  unsigned short* A1 = Xl;
  int b = blockIdx.y, n0 = blockIdx.x*64;
  int t = threadIdx.x, w = t >> 6, l = t & 63;
  int wr = w >> 1, wc = w & 1;
  {
    int nb = t & 7, cl = t >> 3;
    const float* xb = xp + (long)b*C_*N_ + n0 + nb*8;
#pragma unroll 4
    for(int pass=0; pass<16; ++pass){
      int c = pass*32 + cl;
      const float* src = xb + (long)c*N_;
      float4 v0 = *(const float4*)src;
      float4 v1 = *(const float4*)(src+4);
      int base = (nb*8)*520 + c;
      Xl[base         ] = f2b(v0.x);
      Xl[base + 520   ] = f2b(v0.y);
      Xl[base + 520*2 ] = f2b(v0.z);
      Xl[base + 520*3 ] = f2b(v0.w);
      Xl[base + 520*4 ] = f2b(v1.x);
      Xl[base + 520*5 ] = f2b(v1.y);
      Xl[base + 520*6 ] = f2b(v1.z);
      Xl[base + 520*7 ] = f2b(v1.w);
    }
  }
  __syncthreads();
  f32x4 acc[2][4] = {};
  const unsigned short* Bt = Eb + ((long)b*128 + w*16 + (l>>2))*512 + (l&3)*8;
  int ra = wr*32 + (l & 15);
  int rb = wc*64 + (l & 15);
  int kq = (l >> 4) * 8;
  for(int k0 = 0; k0 < 512; k0 += 32){
    if(k0) __syncthreads();
    GLOAD16(Bt + k0,          &Bgl[w*512]);
    GLOAD16(Bt + 64*512 + k0, &Bgl[2048 + w*512]);
    __syncthreads();
    bf16x8 af[2], bfr[4];
#pragma unroll
    for(int rt=0; rt<2; ++rt) af[rt]  = *(const bf16x8*)&Xl[(ra + rt*16)*520 + k0 + kq];
#pragma unroll
    for(int ct=0; ct<4; ++ct) bfr[ct] = *(const bf16x8*)&Bgl[(rb + ct*16)*32 + kq];
#pragma unroll
    for(int rt=0; rt<2; ++rt)
#pragma unroll
      for(int ct=0; ct<4; ++ct)
        acc[rt][ct] = __builtin_amdgcn_mfma_f32_16x16x32_bf16(af[rt], bfr[ct], acc[rt][ct], 0, 0, 0);
  }
  float bias4[4];
#pragma unroll
  for(int ct=0; ct<4; ++ct){
    int g = wc*64 + ct*16 + (l & 15);
    float bi = 0.f;
    if(g < G_){
      bi = ebb[b*G_ + g];
#pragma unroll
      for(int cc=0; cc<8; ++cc) bi += pb[((long)b*8 + cc)*G_ + g];
    }
    bias4[ct] = bi;
  }
  __syncthreads();                        // all Xl fragment reads done before A1 overlay
  int r0 = (l >> 4)*4;
#pragma unroll
  for(int rt=0; rt<2; ++rt){
#pragma unroll
    for(int r=0; r<4; ++r){
      int lrow = wr*32 + rt*16 + r0 + r;
      long rowb = ((long)b*N_ + n0 + lrow)*G_;
#pragma unroll
      for(int ct=0; ct<4; ++ct){
        int g = wc*64 + ct*16 + (l & 15);
        if(g < G_){
          float val = acc[rt][ct][r] + bias4[ct];
          amapT[rowb + g] = val;
          A1[lrow*96 + g] = f2b(val);
        } else if(g < 96){
          A1[lrow*96 + g] = 0;
        }
      }
    }
  }
  __syncthreads();
  int lr = l & 15, lk = l >> 4;
  bf16x8 ay[3];
  const unsigned short* arow = &A1[(w*16 + lr)*96 + lk*8];
#pragma unroll
  for(int ks=0; ks<3; ++ks) ay[ks] = *(const bf16x8*)&arow[ks*32];
  f32x4 acc5[5] = {};
  const unsigned short* wrow = w1b + (long)lr*96 + lk*8;
#pragma unroll
  for(int ks=0; ks<3; ++ks){
#pragma unroll
    for(int ct=0; ct<5; ++ct){
      bf16x8 bw = *(const bf16x8*)&wrow[ct*16*96 + ks*32];
      acc5[ct] = __builtin_amdgcn_mfma_f32_16x16x32_bf16(ay[ks], bw, acc5[ct], 0, 0, 0);
    }
  }
  float v[5][4];
  float ssq[4] = {0.f,0.f,0.f,0.f};
#pragma unroll
  for(int ct=0; ct<5; ++ct){
    int o = ct*16 + lr;
    float bi = f1bias[o], ga = g1[o]*BNS_, bb = b1[o];
#pragma unroll
    for(int i=0;i<4;++i){
      float vv = (acc5[ct][i] + bi)*ga + bb;
      v[ct][i] = vv;
      ssq[i] += vv*vv;
    }
  }
#pragma unroll
  for(int d=1; d<16; d<<=1){
#pragma unroll
    for(int i=0;i<4;++i) ssq[i] += __shfl_xor(ssq[i], d);
  }
  long row0g = (long)b*N_ + n0 + w*16;
#pragma unroll
  for(int i=0;i<4;++i){
    long row = row0g + lk*4 + i;
    float invn = 1.0f / fmaxf(sqrtf(ssq[i]), 1e-12f);
#pragma unroll
    for(int ct=0; ct<5; ++ct){
      int o = ct*16 + lr;
      xf[row*G_ + o] = v[ct][i];
      xub[row*96 + o] = f2b(v[ct][i]*invn);
    }
    xub[row*96 + 80 + lr] = 0;
    if(lr == 0) sq[row] = ssq[i]*invn*invn;
  }
}

// MFMA GEMM: Out[b][o][n] = sum_c Wb[o][c]*Xb[b][n][c] + bias[o] (+Res)
template<bool RES>
__global__ __launch_bounds__(256) void k_gemm_mfma(const unsigned short* __restrict__ Wb,
                                                   const unsigned short* __restrict__ Xb,
                                                   const float* __restrict__ bias,
                                                   const float* __restrict__ Res,
                                                   float* __restrict__ Out){
  __shared__ unsigned short Al[4096];
  __shared__ unsigned short Bl[4096];
  int b = blockIdx.z;
  int o0 = blockIdx.y*128, n0 = blockIdx.x*128;
  int t = threadIdx.x, w = t >> 6, l = t & 63;
  int wr = w >> 1, wc = w & 1;
  f32x4 acc[4][4] = {};
  const unsigned short* Wt = Wb + (long)(o0 + w*16 + (l>>2))*512 + (l&3)*8;
  const unsigned short* Xt = Xb + ((long)b*N_ + n0 + w*16 + (l>>2))*512 + (l&3)*8;
  int ra = wr*64 + (l & 15);
  int rb = wc*64 + (l & 15);
  int kq = (l >> 4) * 8;
  for(int k0 = 0; k0 < 512; k0 += 32){
    if(k0) __syncthreads();
    GLOAD16(Wt + k0,            &Al[w*512]);
    GLOAD16(Wt + 64*512 + k0,   &Al[2048 + w*512]);
    GLOAD16(Xt + k0,            &Bl[w*512]);
    GLOAD16(Xt + 64*512 + k0,   &Bl[2048 + w*512]);
    __syncthreads();
    bf16x8 af[4], bfr[4];
#pragma unroll
    for(int i=0;i<4;++i){
      af[i]  = *(const bf16x8*)&Al[(ra + i*16)*32 + kq];
      bfr[i] = *(const bf16x8*)&Bl[(rb + i*16)*32 + kq];
    }
#pragma unroll
    for(int mi=0; mi<4; ++mi)
#pragma unroll
      for(int ni=0; ni<4; ++ni)
        acc[mi][ni] = __builtin_amdgcn_mfma_f32_16x16x32_bf16(af[mi], bfr[ni], acc[mi][ni], 0, 0, 0);
  }
  long obase = ((long)b*C_ + o0 + wr*64)*N_ + n0 + wc*64 + (l & 15);
  int r0 = (l >> 4) * 4;
#pragma unroll
  for(int mi=0; mi<4; ++mi){
#pragma unroll
    for(int r=0; r<4; ++r){
      int row = mi*16 + r0 + r;
      float bi = bias[o0 + wr*64 + row];
#pragma unroll
      for(int ni=0; ni<4; ++ni){
        long oi = obase + (long)row*N_ + ni*16;
        float v = acc[mi][ni][r] + bi;
        if(RES) v += Res[oi];
        Out[oi] = v;
      }
    }
  }
}

// neg_d via bf16 MFMA: 128x128 tile, K=96 (padded)
__global__ __launch_bounds__(256) void k_negd_mfma(const unsigned short* __restrict__ xub,
                                                   const float* __restrict__ sq,
                                                   float* __restrict__ negd){
  __shared__ unsigned short Al[128*96];
  __shared__ unsigned short Bl[128*96];
  int b = blockIdx.z;
  int n0 = blockIdx.y*128, m0 = blockIdx.x*128;
  int t = threadIdx.x, w = t >> 6, l = t & 63;
  int wr = w >> 1, wc = w & 1;
  const unsigned short* gA = xub + ((long)b*N_ + n0)*96;
  const unsigned short* gB = xub + ((long)b*N_ + m0)*96;
#pragma unroll
  for(int rd=0; rd<6; ++rd){
    int chunk = rd*4 + w;
    GLOAD16(gA + chunk*512 + l*8, &Al[chunk*512]);
    GLOAD16(gB + chunk*512 + l*8, &Bl[chunk*512]);
  }
  __syncthreads();
  f32x4 acc[4][4] = {};
  int ra = wr*64 + (l & 15);
  int rb = wc*64 + (l & 15);
#pragma unroll
  for(int ks=0; ks<3; ++ks){
    int kq = ks*32 + (l >> 4)*8;
    bf16x8 af[4], bfr[4];
#pragma unroll
    for(int i=0;i<4;++i){
      af[i]  = *(const bf16x8*)&Al[(ra + i*16)*96 + kq];
      bfr[i] = *(const bf16x8*)&Bl[(rb + i*16)*96 + kq];
    }
#pragma unroll
    for(int mi=0; mi<4; ++mi)
#pragma unroll
      for(int ni=0; ni<4; ++ni)
        acc[mi][ni] = __builtin_amdgcn_mfma_f32_16x16x32_bf16(af[mi], bfr[ni], acc[mi][ni], 0, 0, 0);
  }
  int r0 = (l >> 4)*4;
  const float* sqb = sq + (long)b*N_;
#pragma unroll
  for(int mi=0; mi<4; ++mi){
#pragma unroll
    for(int r=0; r<4; ++r){
      int n = n0 + wr*64 + mi*16 + r0 + r;
      float sn = sqb[n];
      long row = ((long)b*N_ + n)*N_;
#pragma unroll
      for(int ni=0; ni<4; ++ni){
        int m = m0 + wc*64 + ni*16 + (l & 15);
        negd[row + m] = 2.f*acc[mi][ni][r] - sn - sqb[m];
      }
    }
  }
}

// top-9 per row then gather neighbor-max -> y bf16. one wave per row.
__global__ __launch_bounds__(256) void k_topk_y(const float* __restrict__ negd, const float* __restrict__ xf,
                                                unsigned short* __restrict__ y){
  int t = threadIdx.x, wv = t >> 6, l = t & 63;
  long r = (long)blockIdx.x*4 + wv;
  long b = r >> 10;
  const float* row = negd + r*N_;
  float vals[16];
#pragma unroll
  for(int j=0;j<16;++j) vals[j] = row[l + 64*j];
  int nbs[K_];
#pragma unroll
  for(int p=0; p<K_; ++p){
    float bv = vals[0]; int bj = 0;
#pragma unroll
    for(int j=1;j<16;++j) if(vals[j] > bv){ bv = vals[j]; bj = j; }
    int bm = l + 64*bj;
#pragma unroll
    for(int d=1; d<64; d<<=1){
      float ov = __shfl_xor(bv, d);
      int   om = __shfl_xor(bm, d);
      if(ov > bv || (ov == bv && om < bm)){ bv = ov; bm = om; }
    }
    nbs[p] = bm;
#pragma unroll
    for(int j=0;j<16;++j) if(bm == l + 64*j) vals[j] = -INFINITY;
  }
  const float* frow = xf + r*G_;
  int o2s = (l < 16) ? (64 + l) : 0;
  float f0 = frow[l];
  float f1 = frow[o2s];
  float m0 = -INFINITY, m1 = -INFINITY;
#pragma unroll
  for(int k=0;k<K_;++k){
    const float* nr = xf + ((long)b*N_ + nbs[k])*G_;
    m0 = fmaxf(m0, nr[l]);
    m1 = fmaxf(m1, nr[o2s]);
  }
  unsigned short* yr = y + r*G2_;
  ushort2 u0; u0.x = f2b(f0); u0.y = f2b(m0 - f0);
  *(ushort2*)&yr[2*l] = u0;
  if(l < 16){
    ushort2 u1; u1.x = f2b(f1); u1.y = f2b(m1 - f1);
    *(ushort2*)&yr[128 + 2*l] = u1;
  }
}

// MFMA mixer + bn2 + gelu + fc2 + bn3 + amap -> goutT
__global__ __launch_bounds__(256) void k_mixer_mfma(const unsigned short* __restrict__ y,
                                                    const unsigned short* __restrict__ w1bd,
                                                    const float* __restrict__ mrb,
                                                    const float* __restrict__ g2, const float* __restrict__ b2,
                                                    const unsigned short* __restrict__ fc2b16,
                                                    const float* __restrict__ fc2bias,
                                                    const float* __restrict__ g3, const float* __restrict__ b3,
                                                    const float* __restrict__ amapT, float* __restrict__ goutT){
  __shared__ unsigned short zl[4][16][G2_];
  int t = threadIdx.x, w = t >> 6, l = t & 63;
  long row0 = ((long)blockIdx.x*4 + w)*16;
  int lr = l & 15, lk = l >> 4;
  bf16x8 ay[5];
  const unsigned short* yrow = y + (row0 + lr)*G2_ + lk*8;
#pragma unroll
  for(int ks=0; ks<5; ++ks) ay[ks] = *(const bf16x8*)&yrow[ks*32];
  f32x4 accz[10] = {};
  const unsigned short* wb = w1bd + (long)lr*G2_ + lk*8;
#pragma unroll
  for(int ks=0; ks<5; ++ks){
#pragma unroll
    for(int ct=0; ct<10; ++ct){
      bf16x8 bw = *(const bf16x8*)&wb[ct*16*G2_ + ks*32];
      accz[ct] = __builtin_amdgcn_mfma_f32_16x16x32_bf16(ay[ks], bw, accz[ct], 0, 0, 0);
    }
  }
#pragma unroll
  for(int ct=0; ct<10; ++ct){
    int o = ct*16 + lr;
    float bi = mrb[o], ga = g2[o]*BNS_, bb = b2[o];
#pragma unroll
    for(int i=0;i<4;++i){
      float v = (accz[ct][i] + bi)*ga + bb;
      float zz = v * 0.5f * (1.0f + erff(v * INVSQRT2_));
      zl[w][lk*4 + i][o] = f2b(zz);
    }
  }
  __syncthreads();
  bf16x8 az[5];
#pragma unroll
  for(int ks=0; ks<5; ++ks) az[ks] = *(const bf16x8*)&zl[w][lr][ks*32 + lk*8];
  f32x4 acc2[5] = {};
  const unsigned short* fb = fc2b16 + (long)lr*G2_ + lk*8;
#pragma unroll
  for(int ks=0; ks<5; ++ks){
#pragma unroll
    for(int ct=0; ct<5; ++ct){
      bf16x8 bw = *(const bf16x8*)&fb[ct*16*G2_ + ks*32];
      acc2[ct] = __builtin_amdgcn_mfma_f32_16x16x32_bf16(az[ks], bw, acc2[ct], 0, 0, 0);
    }
  }
#pragma unroll
  for(int ct=0; ct<5; ++ct){
    int o = ct*16 + lr;
    float bi = fc2bias[o], ga = g3[o]*BNS_, bb = b3[o];
#pragma unroll
    for(int i=0;i<4;++i){
      long row = row0 + lk*4 + i;
      float v = (acc2[ct][i] + bi)*ga + bb + amapT[row*G_ + o];
      goutT[row*G_ + o] = v;
    }
  }
}

// per-thread softmax + MFMA PV -> bf16 aob[b][n][c]
__global__ __launch_bounds__(256) void k_softmax_pv(const float* __restrict__ goutT, const float* __restrict__ kv,
                                                    unsigned short* __restrict__ aob){
  int bh = blockIdx.x; int b = bh >> 2, h = bh & 3;
  int n0 = blockIdx.y * 64;
  __shared__ unsigned short Vt[128*32];
  __shared__ unsigned short Pl[64*40];
  __shared__ unsigned short Os[64*132];
  int t = threadIdx.x, w = t >> 6, l = t & 63;
  if(t < 128){
    int d = t;
    const float* vb = kv + ((long)b*CLS_)*1024 + C_ + h*HD_ + d;
#pragma unroll
    for(int cls=0; cls<CLS_; ++cls) Vt[d*32+cls] = f2b(vb[(long)cls*1024]);
#pragma unroll
    for(int cls=CLS_; cls<32; ++cls) Vt[d*32+cls] = 0;
  }
  if(t < 64){
    int n = n0 + t;
    const float* gr = goutT + ((long)b*N_ + n)*G_ + h*CLS_;
    float x[CLS_];
    float mx = -INFINITY;
#pragma unroll
    for(int cls=0; cls<CLS_; ++cls){ x[cls] = gr[cls]; mx = fmaxf(mx, x[cls]); }
    float s = 0.f;
#pragma unroll
    for(int cls=0; cls<CLS_; ++cls){ x[cls] = expf(x[cls]-mx); s += x[cls]; }
    float inv = 1.0f / s;
#pragma unroll
    for(int cls=0; cls<CLS_; ++cls) Pl[t*40+cls] = f2b(x[cls]*inv);
#pragma unroll
    for(int cls=CLS_; cls<32; ++cls) Pl[t*40+cls] = 0;
  }
  __syncthreads();
  int lr = l & 15, kq = (l >> 4)*8;
  f32x4 acc[4][2] = {};
  bf16x8 af[4], bf2[2];
#pragma unroll
  for(int rt=0; rt<4; ++rt) af[rt] = *(const bf16x8*)&Pl[(rt*16+lr)*40 + kq];
#pragma unroll
  for(int ci=0; ci<2; ++ci) bf2[ci] = *(const bf16x8*)&Vt[((2*w+ci)*16+lr)*32 + kq];
#pragma unroll
  for(int rt=0; rt<4; ++rt)
#pragma unroll
    for(int ci=0; ci<2; ++ci)
      acc[rt][ci] = __builtin_amdgcn_mfma_f32_16x16x32_bf16(af[rt], bf2[ci], acc[rt][ci], 0, 0, 0);
  int r0 = (l >> 4)*4;
#pragma unroll
  for(int rt=0; rt<4; ++rt)
#pragma unroll
    for(int ci=0; ci<2; ++ci)
#pragma unroll
      for(int i=0; i<4; ++i)
        Os[(rt*16 + r0 + i)*132 + (2*w+ci)*16 + lr] = f2b(acc[rt][ci][i]);
  __syncthreads();
  unsigned short* ob = aob + ((long)b*N_ + n0)*C_ + h*HD_;
#pragma unroll
  for(int j=0; j<8; ++j){
    int idx = t + 256*j;
    int row = idx >> 5, ch = idx & 31;
    *(ushort4*)&ob[(long)row*C_ + ch*4] =
        *(const ushort4*)&Os[row*132 + ch*4];
  }
}

extern "C" void kernel_launch(void* const* d_in, const int* in_sizes, int n_in,
                              void* d_out, int out_size, void* d_ws, size_t ws_size,
                              hipStream_t stream){
  const float* x_cls   = (const float*)d_in[0];
  const float* x_patch = (const float*)d_in[1];
  const float* norm_x_w = (const float*)d_in[2];
  const float* norm_x_b = (const float*)d_in[3];
  const float* pq_w  = (const float*)d_in[4];
  const float* pq_b  = (const float*)d_in[5];
  const float* ncls_w = (const float*)d_in[6];
  const float* ncls_b = (const float*)d_in[7];
  const float* pkv_w = (const float*)d_in[8];
  const float* pkv_b = (const float*)d_in[9];
  const float* fc1_w = (const float*)d_in[10];
  const float* fc1_b = (const float*)d_in[11];
  const float* bn1_g = (const float*)d_in[12];
  const float* bn1_b = (const float*)d_in[13];
  const float* mr_w  = (const float*)d_in[14];
  const float* mr_b  = (const float*)d_in[15];
  const float* bn2_g = (const float*)d_in[16];
  const float* bn2_b = (const float*)d_in[17];
  const float* fc2_w = (const float*)d_in[18];
  const float* fc2_b = (const float*)d_in[19];
  const float* bn3_g = (const float*)d_in[20];
  const float* bn3_b = (const float*)d_in[21];
  const float* proj_w = (const float*)d_in[22];
  const float* proj_b = (const float*)d_in[23];

  float* ws = (float*)d_ws;
  float* part   = ws + OFF_PART;
  float* ebb    = ws + OFF_EBB;
  float* kvbuf  = ws + OFF_KV;
  float* amapT  = ws + OFF_AMAPT;
  float* xf     = ws + OFF_XF;
  float* sqbuf  = ws + OFF_SQ;
  float* negd   = ws + OFF_NEGD;
  float* goutT  = ws + OFF_GOUTT;
  float* pbuf   = ws + OFF_PB;
  unsigned short* Eb     = (unsigned short*)(ws + OFF_EB);
  unsigned short* xub    = (unsigned short*)(ws + OFF_XUB);
  unsigned short* w1bd   = (unsigned short*)(ws + OFF_W1BD);
  unsigned short* fc2b16 = (unsigned short*)(ws + OFF_FC2B);
  unsigned short* ybuf   = (unsigned short*)(ws + OFF_Y);
  unsigned short* fc1b16 = (unsigned short*)(ws + OFF_FC1B);
  unsigned short* xcb    = (unsigned short*)(ws + OFF_XCB);
  unsigned short* pkvb16 = (unsigned short*)(ws + OFF_PKVB);
  unsigned short* aob = (unsigned short*)(ws + OFF_NEGD);   // overlay: negd dead after topk_y
  unsigned short* wpb = (unsigned short*)(ws + OFF_WPB);
  float* out = (float*)d_out;

  k_pre<<<2128, 256, 0, stream>>>(x_patch, part, x_cls, ncls_w, ncls_b, xcb,
                                  pkv_w, pkvb16, proj_w, wpb,
                                  mr_w, fc2_w, fc1_w, w1bd, fc2b16, fc1b16);
  k_kv_mfma<<<128, 256, 0, stream>>>(xcb, pkvb16, pkv_b, kvbuf);
  k_eprep<<<dim3(16,5,8), 256, 0, stream>>>(kvbuf, pq_w, pq_b, part, norm_x_w, norm_x_b, Eb, ebb, pbuf);
  k_amap_fc1<<<dim3(16,16), 256, 0, stream>>>(Eb, x_patch, ebb, pbuf, fc1b16, fc1_b, bn1_g, bn1_b,
                                              amapT, xf, xub, sqbuf);
  k_negd_mfma<<<dim3(8,8,16), 256, 0, stream>>>(xub, sqbuf, negd);
  k_topk_y<<<4096, 256, 0, stream>>>(negd, xf, ybuf);
  k_mixer_mfma<<<256, 256, 0, stream>>>(ybuf, w1bd, mr_b, bn2_g, bn2_b,
                                        fc2b16, fc2_b, bn3_g, bn3_b, amapT, goutT);
  k_softmax_pv<<<dim3(64,16), 256, 0, stream>>>(goutT, kvbuf, aob);
  k_gemm_mfma<true><<<dim3(8,4,16), 256, 0, stream>>>(wpb, aob, proj_b, x_patch, out);
}